// Round 1
// baseline (2379.597 us; speedup 1.0000x reference)
//
#include <hip/hip_runtime.h>
#include <cstddef>

// Shapes (hard-coded to the bench problem):
// B=2, L=4096 (64x64), C=256, H=8, D=32, K=9, scale=8, NL=4, layers: self,cross,self,cross
// X layout: rows 0..8191 = feat0 (b0,b1), rows 8192..16383 = feat1. 16384 x 256.

#define NROWS 16384

__device__ __forceinline__ float elu1(float x) {
    return x > 0.f ? x + 1.f : expm1f(x) + 1.f;
}

__device__ __forceinline__ float blockReduceSum256(float v, float* sbuf) {
    #pragma unroll
    for (int off = 32; off; off >>= 1) v += __shfl_xor(v, off, 64);
    int lane = threadIdx.x & 63;
    int w = threadIdx.x >> 6;
    __syncthreads();               // protect sbuf reuse across calls
    if (lane == 0) sbuf[w] = v;
    __syncthreads();
    return sbuf[0] + sbuf[1] + sbuf[2] + sbuf[3];
}

// ---------------------------------------------------------------------------
// Tiled fp32 GEMM: C[M,N] = act(A[M,K] @ W[K,N]); A can be split column-wise
// across two sources (for the concat([x,msg]) @ W1 case). 128x128x8 tile,
// 256 threads, 8x8 micro-tile per thread. M%128==0, N%128==0, K%8==0.
// ---------------------------------------------------------------------------
__global__ __launch_bounds__(256) void sgemm_kernel(
    const float* __restrict__ A0, const float* __restrict__ A1, int ksplit,
    int lda0, int lda1,
    const float* __restrict__ W, float* __restrict__ C,
    int Kd, int N, int act)
{
    __shared__ float As[8][128];
    __shared__ float Bs[8][128];

    int tid = threadIdx.x;
    int m0 = blockIdx.y * 128;
    int n0 = blockIdx.x * 128;

    int arow = tid >> 1;           // 0..127
    int acol = (tid & 1) * 4;      // 0 or 4
    int brow = tid >> 5;           // 0..7
    int bcol = (tid & 31) * 4;     // 0..124

    int ty = tid >> 4;             // 0..15
    int tx = tid & 15;             // 0..15

    float acc[8][8];
    #pragma unroll
    for (int i = 0; i < 8; i++)
        #pragma unroll
        for (int j = 0; j < 8; j++) acc[i][j] = 0.f;

    for (int kb = 0; kb < Kd; kb += 8) {
        const float* Ap;
        int lda, kcol;
        if (kb < ksplit) { Ap = A0; lda = lda0; kcol = kb; }
        else             { Ap = A1; lda = lda1; kcol = kb - ksplit; }

        float4 av = *(const float4*)&Ap[(size_t)(m0 + arow) * lda + kcol + acol];
        float4 bv = *(const float4*)&W[(size_t)(kb + brow) * N + n0 + bcol];

        As[acol + 0][arow] = av.x;
        As[acol + 1][arow] = av.y;
        As[acol + 2][arow] = av.z;
        As[acol + 3][arow] = av.w;
        *(float4*)&Bs[brow][bcol] = bv;
        __syncthreads();

        #pragma unroll
        for (int kk = 0; kk < 8; kk++) {
            float a[8], b[8];
            *(float4*)&a[0] = *(const float4*)&As[kk][ty * 8];
            *(float4*)&a[4] = *(const float4*)&As[kk][ty * 8 + 4];
            *(float4*)&b[0] = *(const float4*)&Bs[kk][tx * 8];
            *(float4*)&b[4] = *(const float4*)&Bs[kk][tx * 8 + 4];
            #pragma unroll
            for (int i = 0; i < 8; i++)
                #pragma unroll
                for (int j = 0; j < 8; j++)
                    acc[i][j] += a[i] * b[j];
        }
        __syncthreads();
    }

    #pragma unroll
    for (int i = 0; i < 8; i++) {
        int row = m0 + ty * 8 + i;
        float o[8];
        #pragma unroll
        for (int j = 0; j < 8; j++) {
            float v = acc[i][j];
            if (act == 1) v = tanhf(v);
            o[j] = v;
        }
        *(float4*)&C[(size_t)row * N + n0 + tx * 8]     = *(float4*)&o[0];
        *(float4*)&C[(size_t)row * N + n0 + tx * 8 + 4] = *(float4*)&o[4];
    }
}

// ---------------------------------------------------------------------------
// Self-attention: KV[g,32,32] and Ksum[g,32] reduction over S=4096.
// g = (tensor*2 + b)*8 + h, 32 groups. grid = (8 chunks, 32 groups).
// Kf = (elu(k)+1)*mask, Vf = v*mask  (the /S ... *S cancels and is skipped).
// ---------------------------------------------------------------------------
__global__ __launch_bounds__(256) void kv_reduce_kernel(
    const float* __restrict__ Kb, const float* __restrict__ Vb,
    const int* __restrict__ mask0, const int* __restrict__ mask1,
    float* __restrict__ KV, float* __restrict__ Ksum)
{
    int g = blockIdx.y;
    int t = g >> 4, b = (g >> 3) & 1, h = g & 7;
    const int* mask = t ? mask1 : mask0;
    int rowbase = t * 8192 + b * 4096;
    int s_begin = blockIdx.x * 512;

    __shared__ float sK[4][32];
    __shared__ float sV[4][32];

    int tid = threadIdx.x;
    int s4 = tid >> 6;             // 0..3
    int i  = tid & 63;
    int e  = tid & 31;
    int dq = tid >> 5;             // 0..7

    float acc[4] = {0.f, 0.f, 0.f, 0.f};
    float ks[4]  = {0.f, 0.f, 0.f, 0.f};

    for (int s0 = s_begin; s0 < s_begin + 512; s0 += 4) {
        int s = s0 + s4;
        int row = rowbase + s;
        float m = mask[b * 4096 + s] ? 1.f : 0.f;
        if (i < 32) sK[s4][i]      = elu1(Kb[(size_t)row * 256 + h * 32 + i]) * m;
        else        sV[s4][i - 32] = Vb[(size_t)row * 256 + h * 32 + (i - 32)] * m;
        __syncthreads();
        #pragma unroll
        for (int j = 0; j < 4; j++) {
            int d = dq * 4 + j;
            #pragma unroll
            for (int ss = 0; ss < 4; ss++)
                acc[j] += sK[ss][d] * sV[ss][e];
        }
        if (e == 0) {
            #pragma unroll
            for (int j = 0; j < 4; j++) {
                int d = dq * 4 + j;
                #pragma unroll
                for (int ss = 0; ss < 4; ss++) ks[j] += sK[ss][d];
            }
        }
        __syncthreads();
    }

    #pragma unroll
    for (int j = 0; j < 4; j++)
        atomicAdd(&KV[(size_t)g * 1024 + (dq * 4 + j) * 32 + e], acc[j]);
    if (e == 0) {
        #pragma unroll
        for (int j = 0; j < 4; j++)
            atomicAdd(&Ksum[g * 32 + dq * 4 + j], ks[j]);
    }
}

// msg[row, h*32+e] = Z_h * sum_d Qf[h*32+d] * KV[g,d,e],  Z_h = 1/(Qf.Ksum + 1e-6)
__global__ __launch_bounds__(256) void attn_apply_kernel(
    const float* __restrict__ Qb, const float* __restrict__ KV,
    const float* __restrict__ Ksum, float* __restrict__ MSG)
{
    int row = blockIdx.x;
    int t = row >> 13, bb = (row >> 12) & 1;
    int gb = (t * 2 + bb) * 8;
    int c = threadIdx.x, h = c >> 5, e = c & 31;
    int g = gb + h;

    __shared__ float sQ[256];
    float qf = elu1(Qb[(size_t)row * 256 + c]);
    sQ[c] = qf;
    __syncthreads();

    float p = qf * Ksum[g * 32 + e];
    #pragma unroll
    for (int off = 16; off; off >>= 1) p += __shfl_xor(p, off, 32);
    float Z = 1.f / (p + 1e-6f);

    float acc = 0.f;
    #pragma unroll
    for (int d = 0; d < 32; d++)
        acc += sQ[h * 32 + d] * KV[(size_t)g * 1024 + d * 32 + e];

    MSG[(size_t)row * 256 + c] = acc * Z;
}

// ---------------------------------------------------------------------------
// Cross sampling pre-pass: per sample (ts, b, l, k9) compute the 4 bilinear
// source rows (as X-row indices) and weights with 1/(||desc||+1e-8) folded in.
// 147456 samples, 1 wave each (4 samples / block).
// ---------------------------------------------------------------------------
__global__ __launch_bounds__(256) void sample_kernel(
    const float* __restrict__ X, const float* __restrict__ kp0,
    const float* __restrict__ kp1, int* __restrict__ SIDX,
    float* __restrict__ SWGT)
{
    int samp = blockIdx.x * 4 + (threadIdx.x >> 6);
    int lane = threadIdx.x & 63;
    int ts = samp / 73728;
    int r = samp - ts * 73728;           // (b*4096+l)*9 + s9
    const float* kp = ts ? kp1 : kp0;

    float xx = kp[(size_t)r * 2 + 0];
    float yy = kp[(size_t)r * 2 + 1];
    // k = kp - s/2 + 0.5 ; normalize by (W*s - s/2 - 0.5) ; align_corners grid
    float kx = xx - 3.5f, ky = yy - 3.5f;
    float knx = (kx / 507.5f) * 2.f - 1.f;
    float kny = (ky / 507.5f) * 2.f - 1.f;
    float px = (knx + 1.f) * 0.5f * 63.f;
    float py = (kny + 1.f) * 0.5f * 63.f;
    float x0 = floorf(px), y0 = floorf(py);
    float wx = px - x0, wy = py - y0;
    int x0i = (int)fminf(fmaxf(x0, 0.f), 63.f);
    int x1i = (int)fminf(fmaxf(x0 + 1.f, 0.f), 63.f);
    int y0i = (int)fminf(fmaxf(y0, 0.f), 63.f);
    int y1i = (int)fminf(fmaxf(y0 + 1.f, 0.f), 63.f);

    int bl = r / 9;
    int b = bl >> 12;
    int rb = ts * 8192 + b * 4096;
    int r00 = rb + y0i * 64 + x0i;
    int r01 = rb + y0i * 64 + x1i;
    int r10 = rb + y1i * 64 + x0i;
    int r11 = rb + y1i * 64 + x1i;
    float w00 = (1.f - wy) * (1.f - wx);
    float w01 = (1.f - wy) * wx;
    float w10 = wy * (1.f - wx);
    float w11 = wy * wx;

    int c4 = lane * 4;
    float4 a = *(const float4*)&X[(size_t)r00 * 256 + c4];
    float4 bq = *(const float4*)&X[(size_t)r01 * 256 + c4];
    float4 cq = *(const float4*)&X[(size_t)r10 * 256 + c4];
    float4 dq = *(const float4*)&X[(size_t)r11 * 256 + c4];
    float g0 = w00 * a.x + w01 * bq.x + w10 * cq.x + w11 * dq.x;
    float g1 = w00 * a.y + w01 * bq.y + w10 * cq.y + w11 * dq.y;
    float g2 = w00 * a.z + w01 * bq.z + w10 * cq.z + w11 * dq.z;
    float g3 = w00 * a.w + w01 * bq.w + w10 * cq.w + w11 * dq.w;
    float ss = g0 * g0 + g1 * g1 + g2 * g2 + g3 * g3;
    #pragma unroll
    for (int off = 32; off; off >>= 1) ss += __shfl_xor(ss, off, 64);

    if (lane == 0) {
        float inv = 1.f / (sqrtf(ss) + 1e-8f);
        SIDX[(size_t)samp * 4 + 0] = r00;
        SIDX[(size_t)samp * 4 + 1] = r01;
        SIDX[(size_t)samp * 4 + 2] = r10;
        SIDX[(size_t)samp * 4 + 3] = r11;
        SWGT[(size_t)samp * 4 + 0] = w00 * inv;
        SWGT[(size_t)samp * 4 + 1] = w01 * inv;
        SWGT[(size_t)samp * 4 + 2] = w10 * inv;
        SWGT[(size_t)samp * 4 + 3] = w11 * inv;
    }
}

// ---------------------------------------------------------------------------
// Cross attention (S=9): kproj = bilin(Gk)*invnorm (weights pre-folded),
// Kf = mask ? elu(kproj)+1 : 0; score_h = <Qf_h, Kf_h>; out = Z*sum_s score*Vf.
// One block per query row; thread c owns channel c = h*32+e.
// ---------------------------------------------------------------------------
__global__ __launch_bounds__(256) void cross_attn_kernel(
    const float* __restrict__ Qb, const float* __restrict__ Gk,
    const float* __restrict__ Gv, const int* __restrict__ SIDX,
    const float* __restrict__ SWGT, const int* __restrict__ maskc0,
    const int* __restrict__ maskc1, float* __restrict__ MSG)
{
    int row = blockIdx.x;
    int t = row >> 13;
    int bl = row & 8191;               // b*4096 + l
    int ts = 1 - t;
    const int* mask = (t == 0) ? maskc1 : maskc0;
    int sampBase = ts * 73728 + bl * 9;

    int c = threadIdx.x;
    float qf = elu1(Qb[(size_t)row * 256 + c]);

    float zsum = 0.f, acc = 0.f;
    #pragma unroll
    for (int s9 = 0; s9 < 9; s9++) {
        int samp = sampBase + s9;
        int4 id = ((const int4*)SIDX)[samp];
        float4 w = ((const float4*)SWGT)[samp];
        float kc = w.x * Gk[(size_t)id.x * 256 + c] + w.y * Gk[(size_t)id.y * 256 + c]
                 + w.z * Gk[(size_t)id.z * 256 + c] + w.w * Gk[(size_t)id.w * 256 + c];
        float vc = w.x * Gv[(size_t)id.x * 256 + c] + w.y * Gv[(size_t)id.y * 256 + c]
                 + w.z * Gv[(size_t)id.z * 256 + c] + w.w * Gv[(size_t)id.w * 256 + c];
        float kf = mask[bl * 9 + s9] ? elu1(kc) : 0.f;
        float p = qf * kf;
        #pragma unroll
        for (int off = 16; off; off >>= 1) p += __shfl_xor(p, off, 32);
        zsum += p;
        acc += p * vc;
    }
    float Z = 1.f / (zsum + 1e-6f);
    MSG[(size_t)row * 256 + c] = acc * Z;
}

// ---------------------------------------------------------------------------
// LayerNorm over C=256 (+ optional residual add): out = resid + ln(in)*g+b
// ---------------------------------------------------------------------------
__global__ __launch_bounds__(256) void ln_kernel(
    const float* __restrict__ in, const float* __restrict__ g,
    const float* __restrict__ bp, const float* __restrict__ resid,
    float* __restrict__ out)
{
    __shared__ float sbuf[4];
    int row = blockIdx.x, c = threadIdx.x;
    float x = in[(size_t)row * 256 + c];
    float m = blockReduceSum256(x, sbuf) * (1.f / 256.f);
    float d = x - m;
    float v = blockReduceSum256(d * d, sbuf) * (1.f / 256.f);
    float y = d * rsqrtf(v + 1e-5f) * g[c] + bp[c];
    if (resid) y += resid[(size_t)row * 256 + c];
    out[(size_t)row * 256 + c] = y;
}

// ---------------------------------------------------------------------------

extern "C" void kernel_launch(void* const* d_in, const int* in_sizes, int n_in,
                              void* d_out, int out_size, void* d_ws, size_t ws_size,
                              hipStream_t stream)
{
    const float* feat0 = (const float*)d_in[0];
    const float* feat1 = (const float*)d_in[1];
    const float* kp0 = (const float*)d_in[2];
    const float* kp1 = (const float*)d_in[3];
    const int* ms0 = (const int*)d_in[4];
    const int* ms1 = (const int*)d_in[5];
    const int* mc0 = (const int*)d_in[6];
    const int* mc1 = (const int*)d_in[7];
    const float* Wq = (const float*)d_in[8];
    const float* Wk = (const float*)d_in[9];
    const float* Wv = (const float*)d_in[10];
    const float* Wm = (const float*)d_in[11];
    const float* W1 = (const float*)d_in[12];
    const float* W2 = (const float*)d_in[13];
    const float* g1 = (const float*)d_in[14];
    const float* b1 = (const float*)d_in[15];
    const float* g2 = (const float*)d_in[16];
    const float* b2 = (const float*)d_in[17];

    // workspace layout (floats); total ~26.4M elements (~105.5 MB)
    float* X   = (float*)d_ws;                 // 16384 x 256
    float* Qb  = X   + 4194304;                // q (raw); later reused as M2
    float* Kb  = Qb  + 4194304;                // k / Gk; later reused as M1
    float* Vb  = Kb  + 4194304;                // v / Gv
    float* MSG = Vb  + 4194304;                // attention out; Tb aliases it
    float* Tb  = MSG;                          // 16384 x 512 (MSG dead when written)
    float* KVb = Tb  + 8388608;                // 32 x 1024
    float* KSb = KVb + 32768;                  // 32 x 32
    int*   SIDX = (int*)(KSb + 1024);          // 147456 x 4
    float* SWGT = (float*)(SIDX + 589824);     // 147456 x 4

    hipMemcpyAsync(X, feat0, 8388608ull, hipMemcpyDeviceToDevice, stream);
    hipMemcpyAsync(X + 2097152, feat1, 8388608ull, hipMemcpyDeviceToDevice, stream);

    auto gemm = [&](const float* A0, const float* A1, int ksplit, int lda0, int lda1,
                    const float* Wp, float* Cp, int Kd, int N, int act) {
        dim3 grid(N / 128, NROWS / 128);
        sgemm_kernel<<<grid, 256, 0, stream>>>(A0, A1, ksplit, lda0, lda1, Wp, Cp, Kd, N, act);
    };

    for (int i = 0; i < 4; i++) {
        const float* Wq_l = Wq + (size_t)i * 65536;
        const float* Wk_l = Wk + (size_t)i * 65536;
        const float* Wv_l = Wv + (size_t)i * 65536;
        const float* Wm_l = Wm + (size_t)i * 65536;
        const float* W1_l = W1 + (size_t)i * 262144;
        const float* W2_l = W2 + (size_t)i * 131072;
        const float* g1_l = g1 + (size_t)i * 256;
        const float* b1_l = b1 + (size_t)i * 256;
        const float* g2_l = g2 + (size_t)i * 256;
        const float* b2_l = b2 + (size_t)i * 256;
        bool is_self = (i == 0 || i == 2);

        gemm(X, nullptr, 256, 256, 0, Wq_l, Qb, 256, 256, 0);
        gemm(X, nullptr, 256, 256, 0, Wk_l, Kb, 256, 256, 0);
        gemm(X, nullptr, 256, 256, 0, Wv_l, Vb, 256, 256, 0);

        if (is_self) {
            hipMemsetAsync(KVb, 0, 33792 * 4, stream);
            kv_reduce_kernel<<<dim3(8, 32), 256, 0, stream>>>(Kb, Vb, ms0, ms1, KVb, KSb);
            attn_apply_kernel<<<NROWS, 256, 0, stream>>>(Qb, KVb, KSb, MSG);
        } else {
            sample_kernel<<<36864, 256, 0, stream>>>(X, kp0, kp1, SIDX, SWGT);
            cross_attn_kernel<<<NROWS, 256, 0, stream>>>(Qb, Kb, Vb, SIDX, SWGT, mc0, mc1, MSG);
        }

        gemm(MSG, nullptr, 256, 256, 0, Wm_l, Kb, 256, 256, 0);          // M1 -> Kb
        ln_kernel<<<NROWS, 256, 0, stream>>>(Kb, g1_l, b1_l, nullptr, Kb);
        gemm(X, Kb, 256, 256, 256, W1_l, Tb, 512, 512, 1);               // tanh(cat @ W1)
        gemm(Tb, nullptr, 512, 512, 0, W2_l, Qb, 512, 256, 0);           // M2 -> Qb
        ln_kernel<<<NROWS, 256, 0, stream>>>(Qb, g2_l, b2_l, X, X);      // X += ln(M2)
    }

    hipMemcpyAsync(d_out, X, 16777216ull, hipMemcpyDeviceToDevice, stream);
}

// Round 2
// 1016.803 us; speedup vs baseline: 2.3403x; 2.3403x over previous
//
#include <hip/hip_runtime.h>
#include <cstddef>

// Shapes (hard-coded): B=2, L=4096 (64x64), C=256, H=8, D=32, K=9, scale=8,
// layers: self,cross,self,cross. X rows: 0..8191 feat0 (b0,b1), 8192..16383 feat1.

#define NROWS 16384

typedef unsigned short ushort_t;
typedef __attribute__((ext_vector_type(8))) short short8;
typedef __attribute__((ext_vector_type(4))) float f32x4;
typedef __attribute__((ext_vector_type(4))) unsigned short ushort4_t;

__device__ __forceinline__ float b2f(unsigned short u) {
    union { unsigned int i; float f; } v; v.i = (unsigned int)u << 16; return v.f;
}
__device__ __forceinline__ unsigned short f2b(float x) {
    union { float f; unsigned int i; } v; v.f = x;
    unsigned int r = v.i + 0x7fffu + ((v.i >> 16) & 1u);   // RNE
    return (unsigned short)(r >> 16);
}
__device__ __forceinline__ float elu1(float x) {
    return x > 0.f ? x + 1.f : expm1f(x) + 1.f;
}

#define ASYNC_COPY16(gptr, lptr) \
    __builtin_amdgcn_global_load_lds((const __attribute__((address_space(1))) void*)(gptr), \
                                     (__attribute__((address_space(3))) void*)(lptr), 16, 0, 0)

// ---------------------------------------------------------------------------
// bf16 MFMA GEMM: C[M,N] = act(A[M,K] @ W[K,N]), W pre-transposed as Wt[N][K].
// 128x128x32 tile, 256 threads (4 waves, 2x2 of 64x64), 16x16x32 MFMA.
// A may be split column-wise at ksplit (concat case). All dims %128/%32 == 0.
// ---------------------------------------------------------------------------
template<int ACT>
__global__ __launch_bounds__(256) void gemm_bf16_kernel(
    const ushort_t* __restrict__ A0, const ushort_t* __restrict__ A1, int ksplit,
    int lda0, int lda1, const ushort_t* __restrict__ Wt, int ldw,
    ushort_t* __restrict__ C, int ldc, int Kd)
{
    __shared__ ushort_t As[128 * 32];
    __shared__ ushort_t Bs[128 * 32];

    int tid = threadIdx.x;
    int m0 = blockIdx.y * 128;
    int n0 = blockIdx.x * 128;
    int lane = tid & 63, w = tid >> 6;
    int wrow = w >> 1, wcol = w & 1;
    int quad = lane >> 4, l16 = lane & 15;

    f32x4 acc[4][4];
    #pragma unroll
    for (int i = 0; i < 4; i++)
        #pragma unroll
        for (int j = 0; j < 4; j++) acc[i][j] = (f32x4){0.f, 0.f, 0.f, 0.f};

    int c0 = tid, c1 = tid + 256;
    int ar0 = c0 >> 2, ac0 = (c0 & 3) * 8;
    int ar1 = c1 >> 2, ac1 = (c1 & 3) * 8;

    for (int kb = 0; kb < Kd; kb += 32) {
        const ushort_t* Ab; int lda, kc;
        if (kb < ksplit) { Ab = A0; lda = lda0; kc = kb; }
        else             { Ab = A1; lda = lda1; kc = kb - ksplit; }

        ASYNC_COPY16(Ab + (size_t)(m0 + ar0) * lda + kc + ac0, (char*)As + c0 * 16);
        ASYNC_COPY16(Ab + (size_t)(m0 + ar1) * lda + kc + ac1, (char*)As + c1 * 16);
        ASYNC_COPY16(Wt + (size_t)(n0 + ar0) * ldw + kb + ac0, (char*)Bs + c0 * 16);
        ASYNC_COPY16(Wt + (size_t)(n0 + ar1) * ldw + kb + ac1, (char*)Bs + c1 * 16);
        __syncthreads();

        short8 af[4], bf[4];
        #pragma unroll
        for (int mt = 0; mt < 4; mt++)
            af[mt] = *(const short8*)&As[(wrow * 64 + mt * 16 + l16) * 32 + quad * 8];
        #pragma unroll
        for (int nt = 0; nt < 4; nt++)
            bf[nt] = *(const short8*)&Bs[(wcol * 64 + nt * 16 + l16) * 32 + quad * 8];
        #pragma unroll
        for (int mt = 0; mt < 4; mt++)
            #pragma unroll
            for (int nt = 0; nt < 4; nt++)
                acc[mt][nt] = __builtin_amdgcn_mfma_f32_16x16x32_bf16(
                    af[mt], bf[nt], acc[mt][nt], 0, 0, 0);
        __syncthreads();
    }

    #pragma unroll
    for (int mt = 0; mt < 4; mt++) {
        int row = m0 + wrow * 64 + mt * 16 + quad * 4;
        #pragma unroll
        for (int nt = 0; nt < 4; nt++) {
            int col = n0 + wcol * 64 + nt * 16 + l16;
            #pragma unroll
            for (int r = 0; r < 4; r++) {
                float v = acc[mt][nt][r];
                if (ACT) v = tanhf(v);
                C[(size_t)(row + r) * ldc + col] = f2b(v);
            }
        }
    }
}

// ---------------------------------------------------------------------------
// Weight prep: fp32 [K][N] -> bf16 transposed [N][K]; q/k/v fused into [768][256].
// 2560 tile-blocks of 32x32.
// ---------------------------------------------------------------------------
__global__ __launch_bounds__(256) void wprep_kernel(
    const float* __restrict__ Wq, const float* __restrict__ Wk,
    const float* __restrict__ Wv, const float* __restrict__ Wm,
    const float* __restrict__ W1, const float* __restrict__ W2,
    ushort_t* __restrict__ Wqkvt, ushort_t* __restrict__ Wmt,
    ushort_t* __restrict__ W1t, ushort_t* __restrict__ W2t)
{
    int t = blockIdx.x;
    int layer = t / 640, r = t % 640;
    const float* src; ushort_t* dst;
    int ldsrc, lddst, tn, tk;
    if (r < 192) {
        int grp = r / 64, rr = r % 64; tn = rr / 8; tk = rr % 8;
        src = (grp == 0 ? Wq : grp == 1 ? Wk : Wv) + (size_t)layer * 65536;
        ldsrc = 256;
        dst = Wqkvt + (size_t)layer * 196608 + (size_t)grp * 65536;
        lddst = 256;
    } else if (r < 256) {
        int rr = r - 192; tn = rr / 8; tk = rr % 8;
        src = Wm + (size_t)layer * 65536; ldsrc = 256;
        dst = Wmt + (size_t)layer * 65536; lddst = 256;
    } else if (r < 512) {
        int rr = r - 256; tn = rr / 16; tk = rr % 16;
        src = W1 + (size_t)layer * 262144; ldsrc = 512;
        dst = W1t + (size_t)layer * 262144; lddst = 512;
    } else {
        int rr = r - 512; tn = rr / 16; tk = rr % 16;
        src = W2 + (size_t)layer * 131072; ldsrc = 256;
        dst = W2t + (size_t)layer * 131072; lddst = 512;
    }
    int n0 = tn * 32, k0 = tk * 32;
    __shared__ float tileS[32][33];
    int j = threadIdx.x & 31, i0 = threadIdx.x >> 5;
    #pragma unroll
    for (int p = 0; p < 4; p++) {
        int i = i0 + p * 8;
        tileS[i][j] = src[(size_t)(k0 + i) * ldsrc + n0 + j];
    }
    __syncthreads();
    #pragma unroll
    for (int p = 0; p < 4; p++) {
        int i = i0 + p * 8;
        dst[(size_t)(n0 + i) * lddst + k0 + j] = f2b(tileS[j][i]);
    }
}

// init: X fp32 master + Xbf bf16 mirror from feat0/feat1
__global__ __launch_bounds__(256) void init_kernel(
    const float* __restrict__ f0, const float* __restrict__ f1,
    float* __restrict__ X, ushort_t* __restrict__ Xbf)
{
    int idx = blockIdx.x * 256 + threadIdx.x;      // per float4; 1,048,576 total
    size_t e = (size_t)idx * 4;
    float4 v = (e < 2097152) ? *(const float4*)&f0[e] : *(const float4*)&f1[e - 2097152];
    *(float4*)&X[e] = v;
    ushort4_t u = { f2b(v.x), f2b(v.y), f2b(v.z), f2b(v.w) };
    *(ushort4_t*)&Xbf[e] = u;
}

// ---------------------------------------------------------------------------
// Self-attention KV[g,32,32] + Ksum[g,32] over S=4096, bf16 in (QKV fused, ld=768).
// ---------------------------------------------------------------------------
__global__ __launch_bounds__(256) void kv_reduce_kernel(
    const ushort_t* __restrict__ QKV,
    const int* __restrict__ mask0, const int* __restrict__ mask1,
    float* __restrict__ KV, float* __restrict__ Ksum)
{
    int g = blockIdx.y;
    int t = g >> 4, b = (g >> 3) & 1, h = g & 7;
    const int* mask = t ? mask1 : mask0;
    int rowbase = t * 8192 + b * 4096;
    int s_begin = blockIdx.x * 512;

    __shared__ float sK[4][32];
    __shared__ float sV[4][32];

    int tid = threadIdx.x;
    int s4 = tid >> 6, i = tid & 63, e = tid & 31, dq = tid >> 5;

    float acc[4] = {0.f, 0.f, 0.f, 0.f};
    float ks[4]  = {0.f, 0.f, 0.f, 0.f};

    for (int s0 = s_begin; s0 < s_begin + 512; s0 += 4) {
        int s = s0 + s4;
        int row = rowbase + s;
        float m = mask[b * 4096 + s] ? 1.f : 0.f;
        if (i < 32) sK[s4][i]      = elu1(b2f(QKV[(size_t)row * 768 + 256 + h * 32 + i])) * m;
        else        sV[s4][i - 32] = b2f(QKV[(size_t)row * 768 + 512 + h * 32 + (i - 32)]) * m;
        __syncthreads();
        #pragma unroll
        for (int j = 0; j < 4; j++) {
            int d = dq * 4 + j;
            #pragma unroll
            for (int ss = 0; ss < 4; ss++) acc[j] += sK[ss][d] * sV[ss][e];
        }
        if (e == 0) {
            #pragma unroll
            for (int j = 0; j < 4; j++) {
                int d = dq * 4 + j;
                #pragma unroll
                for (int ss = 0; ss < 4; ss++) ks[j] += sK[ss][d];
            }
        }
        __syncthreads();
    }

    #pragma unroll
    for (int j = 0; j < 4; j++)
        atomicAdd(&KV[(size_t)g * 1024 + (dq * 4 + j) * 32 + e], acc[j]);
    if (e == 0) {
        #pragma unroll
        for (int j = 0; j < 4; j++)
            atomicAdd(&Ksum[g * 32 + dq * 4 + j], ks[j]);
    }
}

__global__ __launch_bounds__(256) void attn_apply_kernel(
    const ushort_t* __restrict__ QKV, const float* __restrict__ KV,
    const float* __restrict__ Ksum, ushort_t* __restrict__ MSG)
{
    int row = blockIdx.x;
    int t = row >> 13, bb = (row >> 12) & 1;
    int gb = (t * 2 + bb) * 8;
    int c = threadIdx.x, h = c >> 5, e = c & 31;
    int g = gb + h;

    __shared__ float sQ[256];
    float qf = elu1(b2f(QKV[(size_t)row * 768 + c]));
    sQ[c] = qf;
    __syncthreads();

    float p = qf * Ksum[g * 32 + e];
    #pragma unroll
    for (int off = 16; off; off >>= 1) p += __shfl_xor(p, off, 32);
    float Z = 1.f / (p + 1e-6f);

    float acc = 0.f;
    #pragma unroll
    for (int d = 0; d < 32; d++)
        acc += sQ[h * 32 + d] * KV[(size_t)g * 1024 + d * 32 + e];

    MSG[(size_t)row * 256 + c] = f2b(acc * Z);
}

// ---------------------------------------------------------------------------
// Cross sampling pre-pass: 4 bilinear source rows + weights w/ invnorm folded.
// ---------------------------------------------------------------------------
__global__ __launch_bounds__(256) void sample_kernel(
    const ushort_t* __restrict__ Xbf, const float* __restrict__ kp0,
    const float* __restrict__ kp1, int* __restrict__ SIDX,
    float* __restrict__ SWGT)
{
    int samp = blockIdx.x * 4 + (threadIdx.x >> 6);
    int lane = threadIdx.x & 63;
    int ts = samp / 73728;
    int r = samp - ts * 73728;
    const float* kp = ts ? kp1 : kp0;

    float xx = kp[(size_t)r * 2 + 0];
    float yy = kp[(size_t)r * 2 + 1];
    float kx = xx - 3.5f, ky = yy - 3.5f;
    float px = ((kx / 507.5f) * 2.f - 1.f + 1.f) * 0.5f * 63.f;
    float py = ((ky / 507.5f) * 2.f - 1.f + 1.f) * 0.5f * 63.f;
    float x0 = floorf(px), y0 = floorf(py);
    float wx = px - x0, wy = py - y0;
    int x0i = (int)fminf(fmaxf(x0, 0.f), 63.f);
    int x1i = (int)fminf(fmaxf(x0 + 1.f, 0.f), 63.f);
    int y0i = (int)fminf(fmaxf(y0, 0.f), 63.f);
    int y1i = (int)fminf(fmaxf(y0 + 1.f, 0.f), 63.f);

    int bl = r / 9;
    int b = bl >> 12;
    int rb = ts * 8192 + b * 4096;
    int r00 = rb + y0i * 64 + x0i;
    int r01 = rb + y0i * 64 + x1i;
    int r10 = rb + y1i * 64 + x0i;
    int r11 = rb + y1i * 64 + x1i;
    float w00 = (1.f - wy) * (1.f - wx);
    float w01 = (1.f - wy) * wx;
    float w10 = wy * (1.f - wx);
    float w11 = wy * wx;

    int c4 = lane * 4;
    ushort4_t a = *(const ushort4_t*)&Xbf[(size_t)r00 * 256 + c4];
    ushort4_t bq = *(const ushort4_t*)&Xbf[(size_t)r01 * 256 + c4];
    ushort4_t cq = *(const ushort4_t*)&Xbf[(size_t)r10 * 256 + c4];
    ushort4_t dq = *(const ushort4_t*)&Xbf[(size_t)r11 * 256 + c4];
    float ss = 0.f;
    #pragma unroll
    for (int j = 0; j < 4; j++) {
        float gv = w00 * b2f(a[j]) + w01 * b2f(bq[j]) + w10 * b2f(cq[j]) + w11 * b2f(dq[j]);
        ss += gv * gv;
    }
    #pragma unroll
    for (int off = 32; off; off >>= 1) ss += __shfl_xor(ss, off, 64);

    if (lane == 0) {
        float inv = 1.f / (sqrtf(ss) + 1e-8f);
        SIDX[(size_t)samp * 4 + 0] = r00;
        SIDX[(size_t)samp * 4 + 1] = r01;
        SIDX[(size_t)samp * 4 + 2] = r10;
        SIDX[(size_t)samp * 4 + 3] = r11;
        SWGT[(size_t)samp * 4 + 0] = w00 * inv;
        SWGT[(size_t)samp * 4 + 1] = w01 * inv;
        SWGT[(size_t)samp * 4 + 2] = w10 * inv;
        SWGT[(size_t)samp * 4 + 3] = w11 * inv;
    }
}

// ---------------------------------------------------------------------------
// Cross attention (S=9) from fused QKV (q at +0, k at +256, v at +512, ld=768).
// ---------------------------------------------------------------------------
__global__ __launch_bounds__(256) void cross_attn_kernel(
    const ushort_t* __restrict__ QKV, const int* __restrict__ SIDX,
    const float* __restrict__ SWGT, const int* __restrict__ maskc0,
    const int* __restrict__ maskc1, ushort_t* __restrict__ MSG)
{
    int row = blockIdx.x;
    int t = row >> 13;
    int bl = row & 8191;
    int ts = 1 - t;
    const int* mask = (t == 0) ? maskc1 : maskc0;
    int sampBase = ts * 73728 + bl * 9;

    int c = threadIdx.x;
    float qf = elu1(b2f(QKV[(size_t)row * 768 + c]));

    float zsum = 0.f, acc = 0.f;
    #pragma unroll
    for (int s9 = 0; s9 < 9; s9++) {
        int samp = sampBase + s9;
        int4 id = ((const int4*)SIDX)[samp];
        float4 wv = ((const float4*)SWGT)[samp];
        size_t bx = (size_t)id.x * 768, by = (size_t)id.y * 768;
        size_t bz = (size_t)id.z * 768, bw = (size_t)id.w * 768;
        float kc = wv.x * b2f(QKV[bx + 256 + c]) + wv.y * b2f(QKV[by + 256 + c])
                 + wv.z * b2f(QKV[bz + 256 + c]) + wv.w * b2f(QKV[bw + 256 + c]);
        float vc = wv.x * b2f(QKV[bx + 512 + c]) + wv.y * b2f(QKV[by + 512 + c])
                 + wv.z * b2f(QKV[bz + 512 + c]) + wv.w * b2f(QKV[bw + 512 + c]);
        float kf = mask[bl * 9 + s9] ? elu1(kc) : 0.f;
        float p = qf * kf;
        #pragma unroll
        for (int off = 16; off; off >>= 1) p += __shfl_xor(p, off, 32);
        zsum += p;
        acc += p * vc;
    }
    float Z = 1.f / (zsum + 1e-6f);
    MSG[(size_t)row * 256 + c] = f2b(acc * Z);
}

// ---------------------------------------------------------------------------
// LayerNorm (C=256), bf16 in.  ln_b: out bf16.  ln_res: X += ln(in); Xbf=bf16(X).
// ---------------------------------------------------------------------------
__device__ __forceinline__ float blockReduceSum256(float v, float* sbuf) {
    #pragma unroll
    for (int off = 32; off; off >>= 1) v += __shfl_xor(v, off, 64);
    int lane = threadIdx.x & 63;
    int w = threadIdx.x >> 6;
    __syncthreads();
    if (lane == 0) sbuf[w] = v;
    __syncthreads();
    return sbuf[0] + sbuf[1] + sbuf[2] + sbuf[3];
}

__global__ __launch_bounds__(256) void ln_b_kernel(
    const ushort_t* __restrict__ in, const float* __restrict__ g,
    const float* __restrict__ bp, ushort_t* __restrict__ out)
{
    __shared__ float sbuf[4];
    int row = blockIdx.x, c = threadIdx.x;
    float x = b2f(in[(size_t)row * 256 + c]);
    float m = blockReduceSum256(x, sbuf) * (1.f / 256.f);
    float d = x - m;
    float v = blockReduceSum256(d * d, sbuf) * (1.f / 256.f);
    float y = d * rsqrtf(v + 1e-5f) * g[c] + bp[c];
    out[(size_t)row * 256 + c] = f2b(y);
}

__global__ __launch_bounds__(256) void ln_res_kernel(
    const ushort_t* __restrict__ in, const float* __restrict__ g,
    const float* __restrict__ bp, float* __restrict__ X, ushort_t* __restrict__ Xbf)
{
    __shared__ float sbuf[4];
    int row = blockIdx.x, c = threadIdx.x;
    float x = b2f(in[(size_t)row * 256 + c]);
    float m = blockReduceSum256(x, sbuf) * (1.f / 256.f);
    float d = x - m;
    float v = blockReduceSum256(d * d, sbuf) * (1.f / 256.f);
    float y = d * rsqrtf(v + 1e-5f) * g[c] + bp[c];
    float xn = X[(size_t)row * 256 + c] + y;
    X[(size_t)row * 256 + c] = xn;
    Xbf[(size_t)row * 256 + c] = f2b(xn);
}

// ---------------------------------------------------------------------------

extern "C" void kernel_launch(void* const* d_in, const int* in_sizes, int n_in,
                              void* d_out, int out_size, void* d_ws, size_t ws_size,
                              hipStream_t stream)
{
    const float* feat0 = (const float*)d_in[0];
    const float* feat1 = (const float*)d_in[1];
    const float* kp0 = (const float*)d_in[2];
    const float* kp1 = (const float*)d_in[3];
    const int* ms0 = (const int*)d_in[4];
    const int* ms1 = (const int*)d_in[5];
    const int* mc0 = (const int*)d_in[6];
    const int* mc1 = (const int*)d_in[7];
    const float* Wq = (const float*)d_in[8];
    const float* Wk = (const float*)d_in[9];
    const float* Wv = (const float*)d_in[10];
    const float* Wm = (const float*)d_in[11];
    const float* W1 = (const float*)d_in[12];
    const float* W2 = (const float*)d_in[13];
    const float* g1 = (const float*)d_in[14];
    const float* b1 = (const float*)d_in[15];
    const float* g2 = (const float*)d_in[16];
    const float* b2 = (const float*)d_in[17];

    // workspace carve (bytes; all offsets 256B-aligned). ~94 MB total.
    char* p = (char*)d_ws;
    float*    X     = (float*)p;            p += 16777216;   // 16384x256 fp32
    ushort_t* Xbf   = (ushort_t*)p;         p += 8388608;    // bf16 mirror
    ushort_t* QKV   = (ushort_t*)p;         p += 25165824;   // 16384x768 bf16
    ushort_t* MSG   = (ushort_t*)p;         p += 8388608;    // 16384x256 bf16 (aliases M2)
    ushort_t* M1T   = (ushort_t*)p;         p += 16777216;   // M1 (16384x256) / T (16384x512)
    ushort_t* L1bf  = (ushort_t*)p;         p += 8388608;    // 16384x256 bf16
    float*    KVb   = (float*)p;            p += 131072;     // 32x1024
    float*    KSb   = (float*)p;            p += 4096;       // 32x32
    int*      SIDX  = (int*)p;              p += 2359296;    // 147456x4
    float*    SWGT  = (float*)p;            p += 2359296;    // 147456x4
    ushort_t* Wqkvt = (ushort_t*)p;         p += 1572864;    // 4x768x256 bf16
    ushort_t* Wmt   = (ushort_t*)p;         p += 524288;     // 4x256x256
    ushort_t* W1t   = (ushort_t*)p;         p += 2097152;    // 4x512x512
    ushort_t* W2t   = (ushort_t*)p;         p += 1048576;    // 4x256x512
    ushort_t* M1 = M1T;
    ushort_t* T  = M1T;
    ushort_t* M2 = MSG;

    init_kernel<<<4096, 256, 0, stream>>>(feat0, feat1, X, Xbf);
    wprep_kernel<<<2560, 256, 0, stream>>>(Wq, Wk, Wv, Wm, W1, W2, Wqkvt, Wmt, W1t, W2t);

    auto gemm = [&](const ushort_t* A0, const ushort_t* A1, int ksplit, int lda0, int lda1,
                    const ushort_t* Wtp, int ldw, ushort_t* Cp, int ldc, int N, int Kd, int act) {
        dim3 grid(N / 128, NROWS / 128);
        if (act)
            gemm_bf16_kernel<1><<<grid, 256, 0, stream>>>(A0, A1, ksplit, lda0, lda1, Wtp, ldw, Cp, ldc, Kd);
        else
            gemm_bf16_kernel<0><<<grid, 256, 0, stream>>>(A0, A1, ksplit, lda0, lda1, Wtp, ldw, Cp, ldc, Kd);
    };

    for (int i = 0; i < 4; i++) {
        const ushort_t* Wqkvt_l = Wqkvt + (size_t)i * 196608;
        const ushort_t* Wmt_l   = Wmt   + (size_t)i * 65536;
        const ushort_t* W1t_l   = W1t   + (size_t)i * 262144;
        const ushort_t* W2t_l   = W2t   + (size_t)i * 131072;
        const float* g1_l = g1 + (size_t)i * 256;
        const float* b1_l = b1 + (size_t)i * 256;
        const float* g2_l = g2 + (size_t)i * 256;
        const float* b2_l = b2 + (size_t)i * 256;
        bool is_self = (i == 0 || i == 2);

        gemm(Xbf, nullptr, 1 << 30, 256, 0, Wqkvt_l, 256, QKV, 768, 768, 256, 0);

        if (is_self) {
            hipMemsetAsync(KVb, 0, 33792 * 4, stream);
            kv_reduce_kernel<<<dim3(8, 32), 256, 0, stream>>>(QKV, ms0, ms1, KVb, KSb);
            attn_apply_kernel<<<NROWS, 256, 0, stream>>>(QKV, KVb, KSb, MSG);
        } else {
            sample_kernel<<<36864, 256, 0, stream>>>(Xbf, kp0, kp1, SIDX, SWGT);
            cross_attn_kernel<<<NROWS, 256, 0, stream>>>(QKV, SIDX, SWGT, mc0, mc1, MSG);
        }

        gemm(MSG, nullptr, 1 << 30, 256, 0, Wmt_l, 256, M1, 256, 256, 256, 0);
        ln_b_kernel<<<NROWS, 256, 0, stream>>>(M1, g1_l, b1_l, L1bf);
        gemm(Xbf, L1bf, 256, 256, 256, W1t_l, 512, T, 512, 512, 512, 1);  // tanh
        gemm(T, nullptr, 1 << 30, 512, 0, W2t_l, 512, M2, 256, 256, 512, 0);
        ln_res_kernel<<<NROWS, 256, 0, stream>>>(M2, g2_l, b2_l, X, Xbf);
    }

    hipMemcpyAsync(d_out, X, 16777216ull, hipMemcpyDeviceToDevice, stream);
}

// Round 3
// 851.072 us; speedup vs baseline: 2.7960x; 1.1947x over previous
//
#include <hip/hip_runtime.h>
#include <cstddef>

// Shapes (hard-coded): B=2, L=4096 (64x64), C=256, H=8, D=32, K=9, scale=8,
// layers: self,cross,self,cross. X rows: 0..8191 feat0 (b0,b1), 8192..16383 feat1.

#define NROWS 16384

typedef unsigned short ushort_t;
typedef __attribute__((ext_vector_type(8))) short short8;
typedef __attribute__((ext_vector_type(4))) float f32x4;
typedef __attribute__((ext_vector_type(4))) unsigned short ushort4_t;

__device__ __forceinline__ float b2f(unsigned short u) {
    union { unsigned int i; float f; } v; v.i = (unsigned int)u << 16; return v.f;
}
__device__ __forceinline__ unsigned short f2b(float x) {
    union { float f; unsigned int i; } v; v.f = x;
    unsigned int r = v.i + 0x7fffu + ((v.i >> 16) & 1u);   // RNE
    return (unsigned short)(r >> 16);
}
__device__ __forceinline__ float elu1(float x) {
    return x > 0.f ? x + 1.f : expm1f(x) + 1.f;
}

#define ASYNC_COPY16(gptr, lptr) \
    __builtin_amdgcn_global_load_lds((const __attribute__((address_space(1))) void*)(gptr), \
                                     (__attribute__((address_space(3))) void*)(lptr), 16, 0, 0)

// ---------------------------------------------------------------------------
// bf16 MFMA GEMM: C[M,N] = act(A[M,K] @ W[K,N]), W pre-transposed as Wt[N][K].
// 128x128x32 tile, 256 threads (4 waves, 2x2 of 64x64), 16x16x32 MFMA.
// A may be split column-wise at ksplit (concat case). All dims %128/%32 == 0.
// ---------------------------------------------------------------------------
template<int ACT>
__global__ __launch_bounds__(256) void gemm_bf16_kernel(
    const ushort_t* __restrict__ A0, const ushort_t* __restrict__ A1, int ksplit,
    int lda0, int lda1, const ushort_t* __restrict__ Wt, int ldw,
    ushort_t* __restrict__ C, int ldc, int Kd)
{
    __shared__ ushort_t As[128 * 32];
    __shared__ ushort_t Bs[128 * 32];

    int tid = threadIdx.x;
    int m0 = blockIdx.y * 128;
    int n0 = blockIdx.x * 128;
    int lane = tid & 63, w = tid >> 6;
    int wrow = w >> 1, wcol = w & 1;
    int quad = lane >> 4, l16 = lane & 15;

    f32x4 acc[4][4];
    #pragma unroll
    for (int i = 0; i < 4; i++)
        #pragma unroll
        for (int j = 0; j < 4; j++) acc[i][j] = (f32x4){0.f, 0.f, 0.f, 0.f};

    int c0 = tid, c1 = tid + 256;
    int ar0 = c0 >> 2, ac0 = (c0 & 3) * 8;
    int ar1 = c1 >> 2, ac1 = (c1 & 3) * 8;

    for (int kb = 0; kb < Kd; kb += 32) {
        const ushort_t* Ab; int lda, kc;
        if (kb < ksplit) { Ab = A0; lda = lda0; kc = kb; }
        else             { Ab = A1; lda = lda1; kc = kb - ksplit; }

        ASYNC_COPY16(Ab + (size_t)(m0 + ar0) * lda + kc + ac0, (char*)As + c0 * 16);
        ASYNC_COPY16(Ab + (size_t)(m0 + ar1) * lda + kc + ac1, (char*)As + c1 * 16);
        ASYNC_COPY16(Wt + (size_t)(n0 + ar0) * ldw + kb + ac0, (char*)Bs + c0 * 16);
        ASYNC_COPY16(Wt + (size_t)(n0 + ar1) * ldw + kb + ac1, (char*)Bs + c1 * 16);
        __syncthreads();

        short8 af[4], bf[4];
        #pragma unroll
        for (int mt = 0; mt < 4; mt++)
            af[mt] = *(const short8*)&As[(wrow * 64 + mt * 16 + l16) * 32 + quad * 8];
        #pragma unroll
        for (int nt = 0; nt < 4; nt++)
            bf[nt] = *(const short8*)&Bs[(wcol * 64 + nt * 16 + l16) * 32 + quad * 8];
        #pragma unroll
        for (int mt = 0; mt < 4; mt++)
            #pragma unroll
            for (int nt = 0; nt < 4; nt++)
                acc[mt][nt] = __builtin_amdgcn_mfma_f32_16x16x32_bf16(
                    af[mt], bf[nt], acc[mt][nt], 0, 0, 0);
        __syncthreads();
    }

    #pragma unroll
    for (int mt = 0; mt < 4; mt++) {
        int row = m0 + wrow * 64 + mt * 16 + quad * 4;
        #pragma unroll
        for (int nt = 0; nt < 4; nt++) {
            int col = n0 + wcol * 64 + nt * 16 + l16;
            #pragma unroll
            for (int r = 0; r < 4; r++) {
                float v = acc[mt][nt][r];
                if (ACT) v = tanhf(v);
                C[(size_t)(row + r) * ldc + col] = f2b(v);
            }
        }
    }
}

// ---------------------------------------------------------------------------
// Weight prep: fp32 [K][N] -> bf16 transposed [N][K]; q/k/v fused into [768][256].
// ---------------------------------------------------------------------------
__global__ __launch_bounds__(256) void wprep_kernel(
    const float* __restrict__ Wq, const float* __restrict__ Wk,
    const float* __restrict__ Wv, const float* __restrict__ Wm,
    const float* __restrict__ W1, const float* __restrict__ W2,
    ushort_t* __restrict__ Wqkvt, ushort_t* __restrict__ Wmt,
    ushort_t* __restrict__ W1t, ushort_t* __restrict__ W2t)
{
    int t = blockIdx.x;
    int layer = t / 640, r = t % 640;
    const float* src; ushort_t* dst;
    int ldsrc, lddst, tn, tk;
    if (r < 192) {
        int grp = r / 64, rr = r % 64; tn = rr / 8; tk = rr % 8;
        src = (grp == 0 ? Wq : grp == 1 ? Wk : Wv) + (size_t)layer * 65536;
        ldsrc = 256;
        dst = Wqkvt + (size_t)layer * 196608 + (size_t)grp * 65536;
        lddst = 256;
    } else if (r < 256) {
        int rr = r - 192; tn = rr / 8; tk = rr % 8;
        src = Wm + (size_t)layer * 65536; ldsrc = 256;
        dst = Wmt + (size_t)layer * 65536; lddst = 256;
    } else if (r < 512) {
        int rr = r - 256; tn = rr / 16; tk = rr % 16;
        src = W1 + (size_t)layer * 262144; ldsrc = 512;
        dst = W1t + (size_t)layer * 262144; lddst = 512;
    } else {
        int rr = r - 512; tn = rr / 16; tk = rr % 16;
        src = W2 + (size_t)layer * 131072; ldsrc = 256;
        dst = W2t + (size_t)layer * 131072; lddst = 512;
    }
    int n0 = tn * 32, k0 = tk * 32;
    __shared__ float tileS[32][33];
    int j = threadIdx.x & 31, i0 = threadIdx.x >> 5;
    #pragma unroll
    for (int p = 0; p < 4; p++) {
        int i = i0 + p * 8;
        tileS[i][j] = src[(size_t)(k0 + i) * ldsrc + n0 + j];
    }
    __syncthreads();
    #pragma unroll
    for (int p = 0; p < 4; p++) {
        int i = i0 + p * 8;
        dst[(size_t)(n0 + i) * lddst + k0 + j] = f2b(tileS[j][i]);
    }
}

// init: X fp32 master + Xbf bf16 mirror from feat0/feat1
__global__ __launch_bounds__(256) void init_kernel(
    const float* __restrict__ f0, const float* __restrict__ f1,
    float* __restrict__ X, ushort_t* __restrict__ Xbf)
{
    int idx = blockIdx.x * 256 + threadIdx.x;      // per float4; 1,048,576 total
    size_t e = (size_t)idx * 4;
    float4 v = (e < 2097152) ? *(const float4*)&f0[e] : *(const float4*)&f1[e - 2097152];
    *(float4*)&X[e] = v;
    ushort4_t u = { f2b(v.x), f2b(v.y), f2b(v.z), f2b(v.w) };
    *(ushort4_t*)&Xbf[e] = u;
}

// ---------------------------------------------------------------------------
// Self-attention KV[g,32,32] + Ksum[g,32] over S=4096, bf16 in (QKV fused, ld=768).
// Restructured: grid (16 s-chunks x 32 groups); stage 32 rows/step into LDS
// (fp32, elu+mask pre-applied); inner loop: ds_read_b128 K-quad + b32 V.
// Barriers: 16/block (was 1024).
// ---------------------------------------------------------------------------
__global__ __launch_bounds__(256) void kv_reduce_kernel(
    const ushort_t* __restrict__ QKV,
    const int* __restrict__ mask0, const int* __restrict__ mask1,
    float* __restrict__ KV, float* __restrict__ Ksum)
{
    int g = blockIdx.y;
    int t = g >> 4, b = (g >> 3) & 1, h = g & 7;
    const int* mask = t ? mask1 : mask0;
    int rowbase = t * 8192 + b * 4096;
    int s_begin = blockIdx.x * 256;

    __shared__ float sK[32][32];
    __shared__ float sV[32][32];

    int tid = threadIdx.x;
    int e  = tid & 31;
    int dq = tid >> 5;              // 0..7 ; this thread owns d = dq*4..dq*4+3

    float acc[4] = {0.f, 0.f, 0.f, 0.f};
    float ks[4]  = {0.f, 0.f, 0.f, 0.f};

    for (int s0 = s_begin; s0 < s_begin + 256; s0 += 32) {
        // stage 32 rows: each thread handles 2 of 512 (row, part) units,
        // part<8 -> K quad (elu+mask), part>=8 -> V quad (mask)
        #pragma unroll
        for (int q = 0; q < 2; q++) {
            int idx = tid + q * 256;
            int rl = idx >> 4;
            int part = idx & 15;
            int s = s0 + rl;
            size_t row = (size_t)(rowbase + s);
            float m = mask[b * 4096 + s] ? 1.f : 0.f;
            if (part < 8) {
                ushort4_t u = *(const ushort4_t*)&QKV[row * 768 + 256 + h * 32 + part * 4];
                float4 f = { elu1(b2f(u.x)) * m, elu1(b2f(u.y)) * m,
                             elu1(b2f(u.z)) * m, elu1(b2f(u.w)) * m };
                *(float4*)&sK[rl][part * 4] = f;
            } else {
                ushort4_t u = *(const ushort4_t*)&QKV[row * 768 + 512 + h * 32 + (part - 8) * 4];
                float4 f = { b2f(u.x) * m, b2f(u.y) * m, b2f(u.z) * m, b2f(u.w) * m };
                *(float4*)&sV[rl][(part - 8) * 4] = f;
            }
        }
        __syncthreads();

        #pragma unroll
        for (int s = 0; s < 32; s++) {
            float4 kq = *(const float4*)&sK[s][dq * 4];
            float vv = sV[s][e];
            acc[0] += kq.x * vv;
            acc[1] += kq.y * vv;
            acc[2] += kq.z * vv;
            acc[3] += kq.w * vv;
            ks[0] += kq.x; ks[1] += kq.y; ks[2] += kq.z; ks[3] += kq.w;
        }
        __syncthreads();
    }

    #pragma unroll
    for (int j = 0; j < 4; j++)
        atomicAdd(&KV[(size_t)g * 1024 + (dq * 4 + j) * 32 + e], acc[j]);
    if (e == 0) {
        #pragma unroll
        for (int j = 0; j < 4; j++)
            atomicAdd(&Ksum[g * 32 + dq * 4 + j], ks[j]);
    }
}

__global__ __launch_bounds__(256) void attn_apply_kernel(
    const ushort_t* __restrict__ QKV, const float* __restrict__ KV,
    const float* __restrict__ Ksum, ushort_t* __restrict__ MSG)
{
    int row = blockIdx.x;
    int t = row >> 13, bb = (row >> 12) & 1;
    int gb = (t * 2 + bb) * 8;
    int c = threadIdx.x, h = c >> 5, e = c & 31;
    int g = gb + h;

    __shared__ float sQ[256];
    float qf = elu1(b2f(QKV[(size_t)row * 768 + c]));
    sQ[c] = qf;
    __syncthreads();

    float p = qf * Ksum[g * 32 + e];
    #pragma unroll
    for (int off = 16; off; off >>= 1) p += __shfl_xor(p, off, 32);
    float Z = 1.f / (p + 1e-6f);

    float acc = 0.f;
    #pragma unroll
    for (int d = 0; d < 32; d++)
        acc += sQ[h * 32 + d] * KV[(size_t)g * 1024 + d * 32 + e];

    MSG[(size_t)row * 256 + c] = f2b(acc * Z);
}

// ---------------------------------------------------------------------------
// Cross sampling pre-pass: 4 bilinear source rows + weights w/ invnorm folded.
// ---------------------------------------------------------------------------
__global__ __launch_bounds__(256) void sample_kernel(
    const ushort_t* __restrict__ Xbf, const float* __restrict__ kp0,
    const float* __restrict__ kp1, int* __restrict__ SIDX,
    float* __restrict__ SWGT)
{
    int samp = blockIdx.x * 4 + (threadIdx.x >> 6);
    int lane = threadIdx.x & 63;
    int ts = samp / 73728;
    int r = samp - ts * 73728;
    const float* kp = ts ? kp1 : kp0;

    float xx = kp[(size_t)r * 2 + 0];
    float yy = kp[(size_t)r * 2 + 1];
    float kx = xx - 3.5f, ky = yy - 3.5f;
    float px = ((kx / 507.5f) * 2.f - 1.f + 1.f) * 0.5f * 63.f;
    float py = ((ky / 507.5f) * 2.f - 1.f + 1.f) * 0.5f * 63.f;
    float x0 = floorf(px), y0 = floorf(py);
    float wx = px - x0, wy = py - y0;
    int x0i = (int)fminf(fmaxf(x0, 0.f), 63.f);
    int x1i = (int)fminf(fmaxf(x0 + 1.f, 0.f), 63.f);
    int y0i = (int)fminf(fmaxf(y0, 0.f), 63.f);
    int y1i = (int)fminf(fmaxf(y0 + 1.f, 0.f), 63.f);

    int bl = r / 9;
    int b = bl >> 12;
    int rb = ts * 8192 + b * 4096;
    int r00 = rb + y0i * 64 + x0i;
    int r01 = rb + y0i * 64 + x1i;
    int r10 = rb + y1i * 64 + x0i;
    int r11 = rb + y1i * 64 + x1i;
    float w00 = (1.f - wy) * (1.f - wx);
    float w01 = (1.f - wy) * wx;
    float w10 = wy * (1.f - wx);
    float w11 = wy * wx;

    int c4 = lane * 4;
    ushort4_t a = *(const ushort4_t*)&Xbf[(size_t)r00 * 256 + c4];
    ushort4_t bq = *(const ushort4_t*)&Xbf[(size_t)r01 * 256 + c4];
    ushort4_t cq = *(const ushort4_t*)&Xbf[(size_t)r10 * 256 + c4];
    ushort4_t dq = *(const ushort4_t*)&Xbf[(size_t)r11 * 256 + c4];
    float ss = 0.f;
    #pragma unroll
    for (int j = 0; j < 4; j++) {
        float gv = w00 * b2f(a[j]) + w01 * b2f(bq[j]) + w10 * b2f(cq[j]) + w11 * b2f(dq[j]);
        ss += gv * gv;
    }
    #pragma unroll
    for (int off = 32; off; off >>= 1) ss += __shfl_xor(ss, off, 64);

    if (lane == 0) {
        float inv = 1.f / (sqrtf(ss) + 1e-8f);
        SIDX[(size_t)samp * 4 + 0] = r00;
        SIDX[(size_t)samp * 4 + 1] = r01;
        SIDX[(size_t)samp * 4 + 2] = r10;
        SIDX[(size_t)samp * 4 + 3] = r11;
        SWGT[(size_t)samp * 4 + 0] = w00 * inv;
        SWGT[(size_t)samp * 4 + 1] = w01 * inv;
        SWGT[(size_t)samp * 4 + 2] = w10 * inv;
        SWGT[(size_t)samp * 4 + 3] = w11 * inv;
    }
}

// ---------------------------------------------------------------------------
// Cross attention (S=9) from fused QKV (q at +0, k at +256, v at +512, ld=768).
// ---------------------------------------------------------------------------
__global__ __launch_bounds__(256) void cross_attn_kernel(
    const ushort_t* __restrict__ QKV, const int* __restrict__ SIDX,
    const float* __restrict__ SWGT, const int* __restrict__ maskc0,
    const int* __restrict__ maskc1, ushort_t* __restrict__ MSG)
{
    int row = blockIdx.x;
    int t = row >> 13;
    int bl = row & 8191;
    int ts = 1 - t;
    const int* mask = (t == 0) ? maskc1 : maskc0;
    int sampBase = ts * 73728 + bl * 9;

    int c = threadIdx.x;
    float qf = elu1(b2f(QKV[(size_t)row * 768 + c]));

    float zsum = 0.f, acc = 0.f;
    #pragma unroll
    for (int s9 = 0; s9 < 9; s9++) {
        int samp = sampBase + s9;
        int4 id = ((const int4*)SIDX)[samp];
        float4 wv = ((const float4*)SWGT)[samp];
        size_t bx = (size_t)id.x * 768, by = (size_t)id.y * 768;
        size_t bz = (size_t)id.z * 768, bw = (size_t)id.w * 768;
        float kc = wv.x * b2f(QKV[bx + 256 + c]) + wv.y * b2f(QKV[by + 256 + c])
                 + wv.z * b2f(QKV[bz + 256 + c]) + wv.w * b2f(QKV[bw + 256 + c]);
        float vc = wv.x * b2f(QKV[bx + 512 + c]) + wv.y * b2f(QKV[by + 512 + c])
                 + wv.z * b2f(QKV[bz + 512 + c]) + wv.w * b2f(QKV[bw + 512 + c]);
        float kf = mask[bl * 9 + s9] ? elu1(kc) : 0.f;
        float p = qf * kf;
        #pragma unroll
        for (int off = 16; off; off >>= 1) p += __shfl_xor(p, off, 32);
        zsum += p;
        acc += p * vc;
    }
    float Z = 1.f / (zsum + 1e-6f);
    MSG[(size_t)row * 256 + c] = f2b(acc * Z);
}

// ---------------------------------------------------------------------------
// LayerNorm (C=256), bf16 in.  ln_b: out bf16.  ln_res: X += ln(in); Xbf=bf16(X).
// ---------------------------------------------------------------------------
__device__ __forceinline__ float blockReduceSum256(float v, float* sbuf) {
    #pragma unroll
    for (int off = 32; off; off >>= 1) v += __shfl_xor(v, off, 64);
    int lane = threadIdx.x & 63;
    int w = threadIdx.x >> 6;
    __syncthreads();
    if (lane == 0) sbuf[w] = v;
    __syncthreads();
    return sbuf[0] + sbuf[1] + sbuf[2] + sbuf[3];
}

__global__ __launch_bounds__(256) void ln_b_kernel(
    const ushort_t* __restrict__ in, const float* __restrict__ g,
    const float* __restrict__ bp, ushort_t* __restrict__ out)
{
    __shared__ float sbuf[4];
    int row = blockIdx.x, c = threadIdx.x;
    float x = b2f(in[(size_t)row * 256 + c]);
    float m = blockReduceSum256(x, sbuf) * (1.f / 256.f);
    float d = x - m;
    float v = blockReduceSum256(d * d, sbuf) * (1.f / 256.f);
    float y = d * rsqrtf(v + 1e-5f) * g[c] + bp[c];
    out[(size_t)row * 256 + c] = f2b(y);
}

__global__ __launch_bounds__(256) void ln_res_kernel(
    const ushort_t* __restrict__ in, const float* __restrict__ g,
    const float* __restrict__ bp, float* __restrict__ X, ushort_t* __restrict__ Xbf)
{
    __shared__ float sbuf[4];
    int row = blockIdx.x, c = threadIdx.x;
    float x = b2f(in[(size_t)row * 256 + c]);
    float m = blockReduceSum256(x, sbuf) * (1.f / 256.f);
    float d = x - m;
    float v = blockReduceSum256(d * d, sbuf) * (1.f / 256.f);
    float y = d * rsqrtf(v + 1e-5f) * g[c] + bp[c];
    float xn = X[(size_t)row * 256 + c] + y;
    X[(size_t)row * 256 + c] = xn;
    Xbf[(size_t)row * 256 + c] = f2b(xn);
}

// ---------------------------------------------------------------------------

extern "C" void kernel_launch(void* const* d_in, const int* in_sizes, int n_in,
                              void* d_out, int out_size, void* d_ws, size_t ws_size,
                              hipStream_t stream)
{
    const float* feat0 = (const float*)d_in[0];
    const float* feat1 = (const float*)d_in[1];
    const float* kp0 = (const float*)d_in[2];
    const float* kp1 = (const float*)d_in[3];
    const int* ms0 = (const int*)d_in[4];
    const int* ms1 = (const int*)d_in[5];
    const int* mc0 = (const int*)d_in[6];
    const int* mc1 = (const int*)d_in[7];
    const float* Wq = (const float*)d_in[8];
    const float* Wk = (const float*)d_in[9];
    const float* Wv = (const float*)d_in[10];
    const float* Wm = (const float*)d_in[11];
    const float* W1 = (const float*)d_in[12];
    const float* W2 = (const float*)d_in[13];
    const float* g1 = (const float*)d_in[14];
    const float* b1 = (const float*)d_in[15];
    const float* g2 = (const float*)d_in[16];
    const float* b2 = (const float*)d_in[17];

    // workspace carve (bytes; all offsets 256B-aligned). ~94 MB total.
    char* p = (char*)d_ws;
    float*    X     = (float*)p;            p += 16777216;   // 16384x256 fp32
    ushort_t* Xbf   = (ushort_t*)p;         p += 8388608;    // bf16 mirror
    ushort_t* QKV   = (ushort_t*)p;         p += 25165824;   // 16384x768 bf16
    ushort_t* MSG   = (ushort_t*)p;         p += 8388608;    // 16384x256 bf16 (aliases M2)
    ushort_t* M1T   = (ushort_t*)p;         p += 16777216;   // M1 (16384x256) / T (16384x512)
    ushort_t* L1bf  = (ushort_t*)p;         p += 8388608;    // 16384x256 bf16
    float*    KVb   = (float*)p;            p += 131072;     // 32x1024
    float*    KSb   = (float*)p;            p += 4096;       // 32x32
    int*      SIDX  = (int*)p;              p += 2359296;    // 147456x4
    float*    SWGT  = (float*)p;            p += 2359296;    // 147456x4
    ushort_t* Wqkvt = (ushort_t*)p;         p += 1572864;    // 4x768x256 bf16
    ushort_t* Wmt   = (ushort_t*)p;         p += 524288;     // 4x256x256
    ushort_t* W1t   = (ushort_t*)p;         p += 2097152;    // 4x512x512
    ushort_t* W2t   = (ushort_t*)p;         p += 1048576;    // 4x256x512
    ushort_t* M1 = M1T;
    ushort_t* T  = M1T;
    ushort_t* M2 = MSG;

    init_kernel<<<4096, 256, 0, stream>>>(feat0, feat1, X, Xbf);
    wprep_kernel<<<2560, 256, 0, stream>>>(Wq, Wk, Wv, Wm, W1, W2, Wqkvt, Wmt, W1t, W2t);

    auto gemm = [&](const ushort_t* A0, const ushort_t* A1, int ksplit, int lda0, int lda1,
                    const ushort_t* Wtp, int ldw, ushort_t* Cp, int ldc, int N, int Kd, int act) {
        dim3 grid(N / 128, NROWS / 128);
        if (act)
            gemm_bf16_kernel<1><<<grid, 256, 0, stream>>>(A0, A1, ksplit, lda0, lda1, Wtp, ldw, Cp, ldc, Kd);
        else
            gemm_bf16_kernel<0><<<grid, 256, 0, stream>>>(A0, A1, ksplit, lda0, lda1, Wtp, ldw, Cp, ldc, Kd);
    };

    for (int i = 0; i < 4; i++) {
        const ushort_t* Wqkvt_l = Wqkvt + (size_t)i * 196608;
        const ushort_t* Wmt_l   = Wmt   + (size_t)i * 65536;
        const ushort_t* W1t_l   = W1t   + (size_t)i * 262144;
        const ushort_t* W2t_l   = W2t   + (size_t)i * 131072;
        const float* g1_l = g1 + (size_t)i * 256;
        const float* b1_l = b1 + (size_t)i * 256;
        const float* g2_l = g2 + (size_t)i * 256;
        const float* b2_l = b2 + (size_t)i * 256;
        bool is_self = (i == 0 || i == 2);

        gemm(Xbf, nullptr, 1 << 30, 256, 0, Wqkvt_l, 256, QKV, 768, 768, 256, 0);

        if (is_self) {
            hipMemsetAsync(KVb, 0, 33792 * 4, stream);
            kv_reduce_kernel<<<dim3(16, 32), 256, 0, stream>>>(QKV, ms0, ms1, KVb, KSb);
            attn_apply_kernel<<<NROWS, 256, 0, stream>>>(QKV, KVb, KSb, MSG);
        } else {
            sample_kernel<<<36864, 256, 0, stream>>>(Xbf, kp0, kp1, SIDX, SWGT);
            cross_attn_kernel<<<NROWS, 256, 0, stream>>>(QKV, SIDX, SWGT, mc0, mc1, MSG);
        }

        gemm(MSG, nullptr, 1 << 30, 256, 0, Wmt_l, 256, M1, 256, 256, 256, 0);
        ln_b_kernel<<<NROWS, 256, 0, stream>>>(M1, g1_l, b1_l, L1bf);
        gemm(Xbf, L1bf, 256, 256, 256, W1t_l, 512, T, 512, 512, 512, 1);  // tanh
        gemm(T, nullptr, 1 << 30, 512, 0, W2t_l, 512, M2, 256, 256, 512, 0);
        ln_res_kernel<<<NROWS, 256, 0, stream>>>(M2, g2_l, b2_l, X, Xbf);
    }

    hipMemcpyAsync(d_out, X, 16777216ull, hipMemcpyDeviceToDevice, stream);
}

// Round 4
// 722.685 us; speedup vs baseline: 3.2927x; 1.1777x over previous
//
#include <hip/hip_runtime.h>
#include <cstddef>

// Shapes (hard-coded): B=2, L=4096 (64x64), C=256, H=8, D=32, K=9, scale=8,
// layers: self,cross,self,cross. X rows: 0..8191 feat0 (b0,b1), 8192..16383 feat1.

#define NROWS 16384

typedef unsigned short ushort_t;
typedef __attribute__((ext_vector_type(8))) short short8;
typedef __attribute__((ext_vector_type(4))) float f32x4;
typedef __attribute__((ext_vector_type(4))) unsigned short ushort4_t;

__device__ __forceinline__ float b2f(unsigned short u) {
    union { unsigned int i; float f; } v; v.i = (unsigned int)u << 16; return v.f;
}
__device__ __forceinline__ unsigned short f2b(float x) {
    union { float f; unsigned int i; } v; v.f = x;
    unsigned int r = v.i + 0x7fffu + ((v.i >> 16) & 1u);   // RNE
    return (unsigned short)(r >> 16);
}
// elu(x)+1: for x<=0, elu = exp(x)-1, so elu+1 = exp(x) exactly.
__device__ __forceinline__ float elu1(float x) {
    return x > 0.f ? x + 1.f : __expf(x);
}

#define ASYNC_COPY16(gptr, lptr) \
    __builtin_amdgcn_global_load_lds((const __attribute__((address_space(1))) void*)(gptr), \
                                     (__attribute__((address_space(3))) void*)(lptr), 16, 0, 0)

// ---------------------------------------------------------------------------
// bf16 MFMA GEMM: C[M,N] = act(A[M,K] @ W[K,N]), W pre-transposed as Wt[N][K].
// 128x128x32 tile, 256 threads (4 waves, 2x2 of 64x64), 16x16x32 MFMA.
// ---------------------------------------------------------------------------
template<int ACT>
__global__ __launch_bounds__(256) void gemm_bf16_kernel(
    const ushort_t* __restrict__ A0, const ushort_t* __restrict__ A1, int ksplit,
    int lda0, int lda1, const ushort_t* __restrict__ Wt, int ldw,
    ushort_t* __restrict__ C, int ldc, int Kd)
{
    __shared__ ushort_t As[128 * 32];
    __shared__ ushort_t Bs[128 * 32];

    int tid = threadIdx.x;
    int m0 = blockIdx.y * 128;
    int n0 = blockIdx.x * 128;
    int lane = tid & 63, w = tid >> 6;
    int wrow = w >> 1, wcol = w & 1;
    int quad = lane >> 4, l16 = lane & 15;

    f32x4 acc[4][4];
    #pragma unroll
    for (int i = 0; i < 4; i++)
        #pragma unroll
        for (int j = 0; j < 4; j++) acc[i][j] = (f32x4){0.f, 0.f, 0.f, 0.f};

    int c0 = tid, c1 = tid + 256;
    int ar0 = c0 >> 2, ac0 = (c0 & 3) * 8;
    int ar1 = c1 >> 2, ac1 = (c1 & 3) * 8;

    for (int kb = 0; kb < Kd; kb += 32) {
        const ushort_t* Ab; int lda, kc;
        if (kb < ksplit) { Ab = A0; lda = lda0; kc = kb; }
        else             { Ab = A1; lda = lda1; kc = kb - ksplit; }

        ASYNC_COPY16(Ab + (size_t)(m0 + ar0) * lda + kc + ac0, (char*)As + c0 * 16);
        ASYNC_COPY16(Ab + (size_t)(m0 + ar1) * lda + kc + ac1, (char*)As + c1 * 16);
        ASYNC_COPY16(Wt + (size_t)(n0 + ar0) * ldw + kb + ac0, (char*)Bs + c0 * 16);
        ASYNC_COPY16(Wt + (size_t)(n0 + ar1) * ldw + kb + ac1, (char*)Bs + c1 * 16);
        __syncthreads();

        short8 af[4], bf[4];
        #pragma unroll
        for (int mt = 0; mt < 4; mt++)
            af[mt] = *(const short8*)&As[(wrow * 64 + mt * 16 + l16) * 32 + quad * 8];
        #pragma unroll
        for (int nt = 0; nt < 4; nt++)
            bf[nt] = *(const short8*)&Bs[(wcol * 64 + nt * 16 + l16) * 32 + quad * 8];
        #pragma unroll
        for (int mt = 0; mt < 4; mt++)
            #pragma unroll
            for (int nt = 0; nt < 4; nt++)
                acc[mt][nt] = __builtin_amdgcn_mfma_f32_16x16x32_bf16(
                    af[mt], bf[nt], acc[mt][nt], 0, 0, 0);
        __syncthreads();
    }

    #pragma unroll
    for (int mt = 0; mt < 4; mt++) {
        int row = m0 + wrow * 64 + mt * 16 + quad * 4;
        #pragma unroll
        for (int nt = 0; nt < 4; nt++) {
            int col = n0 + wcol * 64 + nt * 16 + l16;
            #pragma unroll
            for (int r = 0; r < 4; r++) {
                float v = acc[mt][nt][r];
                if (ACT) v = tanhf(v);
                C[(size_t)(row + r) * ldc + col] = f2b(v);
            }
        }
    }
}

// ---------------------------------------------------------------------------
// Weight prep: fp32 [K][N] -> bf16 transposed [N][K]; q/k/v fused into [768][256].
// ---------------------------------------------------------------------------
__global__ __launch_bounds__(256) void wprep_kernel(
    const float* __restrict__ Wq, const float* __restrict__ Wk,
    const float* __restrict__ Wv, const float* __restrict__ Wm,
    const float* __restrict__ W1, const float* __restrict__ W2,
    ushort_t* __restrict__ Wqkvt, ushort_t* __restrict__ Wmt,
    ushort_t* __restrict__ W1t, ushort_t* __restrict__ W2t)
{
    int t = blockIdx.x;
    int layer = t / 640, r = t % 640;
    const float* src; ushort_t* dst;
    int ldsrc, lddst, tn, tk;
    if (r < 192) {
        int grp = r / 64, rr = r % 64; tn = rr / 8; tk = rr % 8;
        src = (grp == 0 ? Wq : grp == 1 ? Wk : Wv) + (size_t)layer * 65536;
        ldsrc = 256;
        dst = Wqkvt + (size_t)layer * 196608 + (size_t)grp * 65536;
        lddst = 256;
    } else if (r < 256) {
        int rr = r - 192; tn = rr / 8; tk = rr % 8;
        src = Wm + (size_t)layer * 65536; ldsrc = 256;
        dst = Wmt + (size_t)layer * 65536; lddst = 256;
    } else if (r < 512) {
        int rr = r - 256; tn = rr / 16; tk = rr % 16;
        src = W1 + (size_t)layer * 262144; ldsrc = 512;
        dst = W1t + (size_t)layer * 262144; lddst = 512;
    } else {
        int rr = r - 512; tn = rr / 16; tk = rr % 16;
        src = W2 + (size_t)layer * 131072; ldsrc = 256;
        dst = W2t + (size_t)layer * 131072; lddst = 512;
    }
    int n0 = tn * 32, k0 = tk * 32;
    __shared__ float tileS[32][33];
    int j = threadIdx.x & 31, i0 = threadIdx.x >> 5;
    #pragma unroll
    for (int p = 0; p < 4; p++) {
        int i = i0 + p * 8;
        tileS[i][j] = src[(size_t)(k0 + i) * ldsrc + n0 + j];
    }
    __syncthreads();
    #pragma unroll
    for (int p = 0; p < 4; p++) {
        int i = i0 + p * 8;
        dst[(size_t)(n0 + i) * lddst + k0 + j] = f2b(tileS[j][i]);
    }
}

// init: X fp32 master + Xbf bf16 mirror from feat0/feat1
__global__ __launch_bounds__(256) void init_kernel(
    const float* __restrict__ f0, const float* __restrict__ f1,
    float* __restrict__ X, ushort_t* __restrict__ Xbf)
{
    int idx = blockIdx.x * 256 + threadIdx.x;      // per float4; 1,048,576 total
    size_t e = (size_t)idx * 4;
    float4 v = (e < 2097152) ? *(const float4*)&f0[e] : *(const float4*)&f1[e - 2097152];
    *(float4*)&X[e] = v;
    ushort4_t u = { f2b(v.x), f2b(v.y), f2b(v.z), f2b(v.w) };
    *(ushort4_t*)&Xbf[e] = u;
}

// ---------------------------------------------------------------------------
// Self-attention KV[g,32,32] + Ksum[g,32] over S=4096, bf16 in (QKV fused, ld=768).
// ---------------------------------------------------------------------------
__global__ __launch_bounds__(256) void kv_reduce_kernel(
    const ushort_t* __restrict__ QKV,
    const int* __restrict__ mask0, const int* __restrict__ mask1,
    float* __restrict__ KV, float* __restrict__ Ksum)
{
    int g = blockIdx.y;
    int t = g >> 4, b = (g >> 3) & 1, h = g & 7;
    const int* mask = t ? mask1 : mask0;
    int rowbase = t * 8192 + b * 4096;
    int s_begin = blockIdx.x * 256;

    __shared__ float sK[32][32];
    __shared__ float sV[32][32];

    int tid = threadIdx.x;
    int e  = tid & 31;
    int dq = tid >> 5;              // 0..7 ; this thread owns d = dq*4..dq*4+3

    float acc[4] = {0.f, 0.f, 0.f, 0.f};
    float ks[4]  = {0.f, 0.f, 0.f, 0.f};

    for (int s0 = s_begin; s0 < s_begin + 256; s0 += 32) {
        #pragma unroll
        for (int q = 0; q < 2; q++) {
            int idx = tid + q * 256;
            int rl = idx >> 4;
            int part = idx & 15;
            int s = s0 + rl;
            size_t row = (size_t)(rowbase + s);
            float m = mask[b * 4096 + s] ? 1.f : 0.f;
            if (part < 8) {
                ushort4_t u = *(const ushort4_t*)&QKV[row * 768 + 256 + h * 32 + part * 4];
                float4 f = { elu1(b2f(u.x)) * m, elu1(b2f(u.y)) * m,
                             elu1(b2f(u.z)) * m, elu1(b2f(u.w)) * m };
                *(float4*)&sK[rl][part * 4] = f;
            } else {
                ushort4_t u = *(const ushort4_t*)&QKV[row * 768 + 512 + h * 32 + (part - 8) * 4];
                float4 f = { b2f(u.x) * m, b2f(u.y) * m, b2f(u.z) * m, b2f(u.w) * m };
                *(float4*)&sV[rl][(part - 8) * 4] = f;
            }
        }
        __syncthreads();

        #pragma unroll
        for (int s = 0; s < 32; s++) {
            float4 kq = *(const float4*)&sK[s][dq * 4];
            float vv = sV[s][e];
            acc[0] += kq.x * vv;
            acc[1] += kq.y * vv;
            acc[2] += kq.z * vv;
            acc[3] += kq.w * vv;
            ks[0] += kq.x; ks[1] += kq.y; ks[2] += kq.z; ks[3] += kq.w;
        }
        __syncthreads();
    }

    #pragma unroll
    for (int j = 0; j < 4; j++)
        atomicAdd(&KV[(size_t)g * 1024 + (dq * 4 + j) * 32 + e], acc[j]);
    if (e == 0) {
        #pragma unroll
        for (int j = 0; j < 4; j++)
            atomicAdd(&Ksum[g * 32 + dq * 4 + j], ks[j]);
    }
}

__global__ __launch_bounds__(256) void attn_apply_kernel(
    const ushort_t* __restrict__ QKV, const float* __restrict__ KV,
    const float* __restrict__ Ksum, ushort_t* __restrict__ MSG)
{
    int row = blockIdx.x;
    int t = row >> 13, bb = (row >> 12) & 1;
    int gb = (t * 2 + bb) * 8;
    int c = threadIdx.x, h = c >> 5, e = c & 31;
    int g = gb + h;

    __shared__ float sQ[256];
    float qf = elu1(b2f(QKV[(size_t)row * 768 + c]));
    sQ[c] = qf;
    __syncthreads();

    float p = qf * Ksum[g * 32 + e];
    #pragma unroll
    for (int off = 16; off; off >>= 1) p += __shfl_xor(p, off, 32);
    float Z = 1.f / (p + 1e-6f);

    float acc = 0.f;
    #pragma unroll
    for (int d = 0; d < 32; d++)
        acc += sQ[h * 32 + d] * KV[(size_t)g * 1024 + d * 32 + e];

    MSG[(size_t)row * 256 + c] = f2b(acc * Z);
}

// ---------------------------------------------------------------------------
// Fused cross attention (S=9): one WAVE per query row, 4 channels per lane.
// Each sample (bilinear keypoint) is consumed by exactly one query row, so
// the sampling pre-pass (indices, weights, descriptor L2-norm) is computed
// inline. kproj = bilin(Gk)*invnorm; Kf = mask ? elu1 : 0; out = Z*sum score*Vf.
// ---------------------------------------------------------------------------
__global__ __launch_bounds__(256) void cross_fused_kernel(
    const ushort_t* __restrict__ QKV, const ushort_t* __restrict__ Xbf,
    const float* __restrict__ kp0, const float* __restrict__ kp1,
    const int* __restrict__ maskc0, const int* __restrict__ maskc1,
    ushort_t* __restrict__ MSG)
{
    int row = blockIdx.x * 4 + (threadIdx.x >> 6);
    int lane = threadIdx.x & 63;
    int t = row >> 13;
    int bl = row & 8191;               // b*4096 + l
    int ts = 1 - t;                    // source image
    const float* kp = ts ? kp1 : kp0;
    const int* mask = (t == 0) ? maskc1 : maskc0;
    int rb = ts * 8192 + (bl >> 12) * 4096;   // source row base (b of query)

    int c4 = lane * 4;                 // this lane's 4 channels

    // query features (elu+1)
    ushort4_t qu = *(const ushort4_t*)&QKV[(size_t)row * 768 + c4];
    float qf0 = elu1(b2f(qu.x)), qf1 = elu1(b2f(qu.y));
    float qf2 = elu1(b2f(qu.z)), qf3 = elu1(b2f(qu.w));

    float zsum = 0.f;
    float acc0 = 0.f, acc1 = 0.f, acc2 = 0.f, acc3 = 0.f;

    for (int s9 = 0; s9 < 9; s9++) {
        int r = bl * 9 + s9;
        float xx = kp[(size_t)r * 2 + 0];
        float yy = kp[(size_t)r * 2 + 1];
        float px = ((xx - 3.5f) / 507.5f) * 63.f;   // ((k/507.5)*2-1+1)*0.5*63
        float py = ((yy - 3.5f) / 507.5f) * 63.f;
        float x0 = floorf(px), y0 = floorf(py);
        float wx = px - x0, wy = py - y0;
        int x0i = (int)fminf(fmaxf(x0, 0.f), 63.f);
        int x1i = (int)fminf(fmaxf(x0 + 1.f, 0.f), 63.f);
        int y0i = (int)fminf(fmaxf(y0, 0.f), 63.f);
        int y1i = (int)fminf(fmaxf(y0 + 1.f, 0.f), 63.f);
        size_t r00 = rb + y0i * 64 + x0i;
        size_t r01 = rb + y0i * 64 + x1i;
        size_t r10 = rb + y1i * 64 + x0i;
        size_t r11 = rb + y1i * 64 + x1i;
        float w00 = (1.f - wy) * (1.f - wx);
        float w01 = (1.f - wy) * wx;
        float w10 = wy * (1.f - wx);
        float w11 = wy * wx;

        // descriptor norm over the raw feature bilinear blend
        ushort4_t n00 = *(const ushort4_t*)&Xbf[r00 * 256 + c4];
        ushort4_t n01 = *(const ushort4_t*)&Xbf[r01 * 256 + c4];
        ushort4_t n10 = *(const ushort4_t*)&Xbf[r10 * 256 + c4];
        ushort4_t n11 = *(const ushort4_t*)&Xbf[r11 * 256 + c4];
        float ss = 0.f;
        #pragma unroll
        for (int j = 0; j < 4; j++) {
            float gv = w00 * b2f(n00[j]) + w01 * b2f(n01[j])
                     + w10 * b2f(n10[j]) + w11 * b2f(n11[j]);
            ss += gv * gv;
        }
        #pragma unroll
        for (int off = 32; off; off >>= 1) ss += __shfl_xor(ss, off, 64);
        float inv = 1.f / (sqrtf(ss) + 1e-8f);
        float u00 = w00 * inv, u01 = w01 * inv, u10 = w10 * inv, u11 = w11 * inv;

        // K and V gathers (QKV: k at +256, v at +512)
        ushort4_t k00 = *(const ushort4_t*)&QKV[r00 * 768 + 256 + c4];
        ushort4_t k01 = *(const ushort4_t*)&QKV[r01 * 768 + 256 + c4];
        ushort4_t k10 = *(const ushort4_t*)&QKV[r10 * 768 + 256 + c4];
        ushort4_t k11 = *(const ushort4_t*)&QKV[r11 * 768 + 256 + c4];
        ushort4_t v00 = *(const ushort4_t*)&QKV[r00 * 768 + 512 + c4];
        ushort4_t v01 = *(const ushort4_t*)&QKV[r01 * 768 + 512 + c4];
        ushort4_t v10 = *(const ushort4_t*)&QKV[r10 * 768 + 512 + c4];
        ushort4_t v11 = *(const ushort4_t*)&QKV[r11 * 768 + 512 + c4];

        bool mk = mask[r] != 0;
        float kc0 = u00 * b2f(k00[0]) + u01 * b2f(k01[0]) + u10 * b2f(k10[0]) + u11 * b2f(k11[0]);
        float kc1 = u00 * b2f(k00[1]) + u01 * b2f(k01[1]) + u10 * b2f(k10[1]) + u11 * b2f(k11[1]);
        float kc2 = u00 * b2f(k00[2]) + u01 * b2f(k01[2]) + u10 * b2f(k10[2]) + u11 * b2f(k11[2]);
        float kc3 = u00 * b2f(k00[3]) + u01 * b2f(k01[3]) + u10 * b2f(k10[3]) + u11 * b2f(k11[3]);
        float vc0 = u00 * b2f(v00[0]) + u01 * b2f(v01[0]) + u10 * b2f(v10[0]) + u11 * b2f(v11[0]);
        float vc1 = u00 * b2f(v00[1]) + u01 * b2f(v01[1]) + u10 * b2f(v10[1]) + u11 * b2f(v11[1]);
        float vc2 = u00 * b2f(v00[2]) + u01 * b2f(v01[2]) + u10 * b2f(v10[2]) + u11 * b2f(v11[2]);
        float vc3 = u00 * b2f(v00[3]) + u01 * b2f(v01[3]) + u10 * b2f(v10[3]) + u11 * b2f(v11[3]);

        float p = mk ? (qf0 * elu1(kc0) + qf1 * elu1(kc1)
                      + qf2 * elu1(kc2) + qf3 * elu1(kc3)) : 0.f;
        // reduce within head: head = lane>>3 (8 lanes x 4 ch = 32 ch)
        p += __shfl_xor(p, 1, 64);
        p += __shfl_xor(p, 2, 64);
        p += __shfl_xor(p, 4, 64);

        zsum += p;
        acc0 += p * vc0; acc1 += p * vc1; acc2 += p * vc2; acc3 += p * vc3;
    }

    float Z = 1.f / (zsum + 1e-6f);
    ushort4_t o = { f2b(acc0 * Z), f2b(acc1 * Z), f2b(acc2 * Z), f2b(acc3 * Z) };
    *(ushort4_t*)&MSG[(size_t)row * 256 + c4] = o;
}

// ---------------------------------------------------------------------------
// LayerNorm (C=256), wave-per-row (4 rows/block), 4 ch/lane, shuffle-only.
// ln_b: bf16 in -> bf16 out.  ln_res: X += ln(in); Xbf = bf16(X).
// ---------------------------------------------------------------------------
__device__ __forceinline__ float waveReduceSum(float v) {
    #pragma unroll
    for (int off = 32; off; off >>= 1) v += __shfl_xor(v, off, 64);
    return v;
}

__global__ __launch_bounds__(256) void ln_b_kernel(
    const ushort_t* __restrict__ in, const float* __restrict__ g,
    const float* __restrict__ bp, ushort_t* __restrict__ out)
{
    int row = blockIdx.x * 4 + (threadIdx.x >> 6);
    int lane = threadIdx.x & 63;
    int c4 = lane * 4;
    ushort4_t u = *(const ushort4_t*)&in[(size_t)row * 256 + c4];
    float x0 = b2f(u.x), x1 = b2f(u.y), x2 = b2f(u.z), x3 = b2f(u.w);
    float m = waveReduceSum(x0 + x1 + x2 + x3) * (1.f / 256.f);
    float d0 = x0 - m, d1 = x1 - m, d2 = x2 - m, d3 = x3 - m;
    float v = waveReduceSum(d0 * d0 + d1 * d1 + d2 * d2 + d3 * d3) * (1.f / 256.f);
    float rs = rsqrtf(v + 1e-5f);
    float4 gg = *(const float4*)&g[c4];
    float4 bb = *(const float4*)&bp[c4];
    ushort4_t o = { f2b(d0 * rs * gg.x + bb.x), f2b(d1 * rs * gg.y + bb.y),
                    f2b(d2 * rs * gg.z + bb.z), f2b(d3 * rs * gg.w + bb.w) };
    *(ushort4_t*)&out[(size_t)row * 256 + c4] = o;
}

__global__ __launch_bounds__(256) void ln_res_kernel(
    const ushort_t* __restrict__ in, const float* __restrict__ g,
    const float* __restrict__ bp, float* __restrict__ X, ushort_t* __restrict__ Xbf)
{
    int row = blockIdx.x * 4 + (threadIdx.x >> 6);
    int lane = threadIdx.x & 63;
    int c4 = lane * 4;
    ushort4_t u = *(const ushort4_t*)&in[(size_t)row * 256 + c4];
    float x0 = b2f(u.x), x1 = b2f(u.y), x2 = b2f(u.z), x3 = b2f(u.w);
    float m = waveReduceSum(x0 + x1 + x2 + x3) * (1.f / 256.f);
    float d0 = x0 - m, d1 = x1 - m, d2 = x2 - m, d3 = x3 - m;
    float v = waveReduceSum(d0 * d0 + d1 * d1 + d2 * d2 + d3 * d3) * (1.f / 256.f);
    float rs = rsqrtf(v + 1e-5f);
    float4 gg = *(const float4*)&g[c4];
    float4 bb = *(const float4*)&bp[c4];
    float4 xo = *(float4*)&X[(size_t)row * 256 + c4];
    xo.x += d0 * rs * gg.x + bb.x;
    xo.y += d1 * rs * gg.y + bb.y;
    xo.z += d2 * rs * gg.z + bb.z;
    xo.w += d3 * rs * gg.w + bb.w;
    *(float4*)&X[(size_t)row * 256 + c4] = xo;
    ushort4_t o = { f2b(xo.x), f2b(xo.y), f2b(xo.z), f2b(xo.w) };
    *(ushort4_t*)&Xbf[(size_t)row * 256 + c4] = o;
}

// ---------------------------------------------------------------------------

extern "C" void kernel_launch(void* const* d_in, const int* in_sizes, int n_in,
                              void* d_out, int out_size, void* d_ws, size_t ws_size,
                              hipStream_t stream)
{
    const float* feat0 = (const float*)d_in[0];
    const float* feat1 = (const float*)d_in[1];
    const float* kp0 = (const float*)d_in[2];
    const float* kp1 = (const float*)d_in[3];
    const int* ms0 = (const int*)d_in[4];
    const int* ms1 = (const int*)d_in[5];
    const int* mc0 = (const int*)d_in[6];
    const int* mc1 = (const int*)d_in[7];
    const float* Wq = (const float*)d_in[8];
    const float* Wk = (const float*)d_in[9];
    const float* Wv = (const float*)d_in[10];
    const float* Wm = (const float*)d_in[11];
    const float* W1 = (const float*)d_in[12];
    const float* W2 = (const float*)d_in[13];
    const float* g1 = (const float*)d_in[14];
    const float* b1 = (const float*)d_in[15];
    const float* g2 = (const float*)d_in[16];
    const float* b2 = (const float*)d_in[17];

    // workspace carve (bytes; all offsets 256B-aligned). ~90 MB total.
    char* p = (char*)d_ws;
    float*    X     = (float*)p;            p += 16777216;   // 16384x256 fp32
    ushort_t* Xbf   = (ushort_t*)p;         p += 8388608;    // bf16 mirror
    ushort_t* QKV   = (ushort_t*)p;         p += 25165824;   // 16384x768 bf16
    ushort_t* MSG   = (ushort_t*)p;         p += 8388608;    // 16384x256 bf16 (aliases M2)
    ushort_t* M1T   = (ushort_t*)p;         p += 16777216;   // M1 (16384x256) / T (16384x512)
    ushort_t* L1bf  = (ushort_t*)p;         p += 8388608;    // 16384x256 bf16
    float*    KVb   = (float*)p;            p += 131072;     // 32x1024
    float*    KSb   = (float*)p;            p += 4096;       // 32x32
    ushort_t* Wqkvt = (ushort_t*)p;         p += 1572864;    // 4x768x256 bf16
    ushort_t* Wmt   = (ushort_t*)p;         p += 524288;     // 4x256x256
    ushort_t* W1t   = (ushort_t*)p;         p += 2097152;    // 4x512x512
    ushort_t* W2t   = (ushort_t*)p;         p += 1048576;    // 4x256x512
    ushort_t* M1 = M1T;
    ushort_t* T  = M1T;
    ushort_t* M2 = MSG;

    init_kernel<<<4096, 256, 0, stream>>>(feat0, feat1, X, Xbf);
    wprep_kernel<<<2560, 256, 0, stream>>>(Wq, Wk, Wv, Wm, W1, W2, Wqkvt, Wmt, W1t, W2t);

    auto gemm = [&](const ushort_t* A0, const ushort_t* A1, int ksplit, int lda0, int lda1,
                    const ushort_t* Wtp, int ldw, ushort_t* Cp, int ldc, int N, int Kd, int act) {
        dim3 grid(N / 128, NROWS / 128);
        if (act)
            gemm_bf16_kernel<1><<<grid, 256, 0, stream>>>(A0, A1, ksplit, lda0, lda1, Wtp, ldw, Cp, ldc, Kd);
        else
            gemm_bf16_kernel<0><<<grid, 256, 0, stream>>>(A0, A1, ksplit, lda0, lda1, Wtp, ldw, Cp, ldc, Kd);
    };

    for (int i = 0; i < 4; i++) {
        const ushort_t* Wqkvt_l = Wqkvt + (size_t)i * 196608;
        const ushort_t* Wmt_l   = Wmt   + (size_t)i * 65536;
        const ushort_t* W1t_l   = W1t   + (size_t)i * 262144;
        const ushort_t* W2t_l   = W2t   + (size_t)i * 131072;
        const float* g1_l = g1 + (size_t)i * 256;
        const float* b1_l = b1 + (size_t)i * 256;
        const float* g2_l = g2 + (size_t)i * 256;
        const float* b2_l = b2 + (size_t)i * 256;
        bool is_self = (i == 0 || i == 2);

        gemm(Xbf, nullptr, 1 << 30, 256, 0, Wqkvt_l, 256, QKV, 768, 768, 256, 0);

        if (is_self) {
            hipMemsetAsync(KVb, 0, 33792 * 4, stream);
            kv_reduce_kernel<<<dim3(16, 32), 256, 0, stream>>>(QKV, ms0, ms1, KVb, KSb);
            attn_apply_kernel<<<NROWS, 256, 0, stream>>>(QKV, KVb, KSb, MSG);
        } else {
            cross_fused_kernel<<<NROWS / 4, 256, 0, stream>>>(QKV, Xbf, kp0, kp1, mc0, mc1, MSG);
        }

        gemm(MSG, nullptr, 1 << 30, 256, 0, Wmt_l, 256, M1, 256, 256, 256, 0);
        ln_b_kernel<<<NROWS / 4, 256, 0, stream>>>(M1, g1_l, b1_l, L1bf);
        gemm(Xbf, L1bf, 256, 256, 256, W1t_l, 512, T, 512, 512, 512, 1);  // tanh
        gemm(T, nullptr, 1 << 30, 512, 0, W2t_l, 512, M2, 256, 256, 512, 0);
        ln_res_kernel<<<NROWS / 4, 256, 0, stream>>>(M2, g2_l, b2_l, X, Xbf);
    }

    hipMemcpyAsync(d_out, X, 16777216ull, hipMemcpyDeviceToDevice, stream);
}

// Round 5
// 704.083 us; speedup vs baseline: 3.3797x; 1.0264x over previous
//
#include <hip/hip_runtime.h>
#include <cstddef>

// Shapes (hard-coded): B=2, L=4096 (64x64), C=256, H=8, D=32, K=9, scale=8,
// layers: self,cross,self,cross. X rows: 0..8191 feat0 (b0,b1), 8192..16383 feat1.

#define NROWS 16384

typedef unsigned short ushort_t;
typedef __attribute__((ext_vector_type(8))) short short8;
typedef __attribute__((ext_vector_type(4))) float f32x4;
typedef __attribute__((ext_vector_type(4))) unsigned short ushort4_t;
typedef __attribute__((ext_vector_type(8))) unsigned short ushort8_t;

__device__ __forceinline__ float b2f(unsigned short u) {
    union { unsigned int i; float f; } v; v.i = (unsigned int)u << 16; return v.f;
}
__device__ __forceinline__ unsigned short f2b(float x) {
    union { float f; unsigned int i; } v; v.f = x;
    unsigned int r = v.i + 0x7fffu + ((v.i >> 16) & 1u);   // RNE
    return (unsigned short)(r >> 16);
}
// elu(x)+1: for x<=0, elu = exp(x)-1, so elu+1 = exp(x) exactly.
__device__ __forceinline__ float elu1(float x) {
    return x > 0.f ? x + 1.f : __expf(x);
}

#define ASYNC_COPY16(gptr, lptr) \
    __builtin_amdgcn_global_load_lds((const __attribute__((address_space(1))) void*)(gptr), \
                                     (__attribute__((address_space(3))) void*)(lptr), 16, 0, 0)

// ---------------------------------------------------------------------------
// bf16 MFMA GEMM: C[M,N] = act(A[M,K] @ W[K,N]), W pre-transposed as Wt[N][K].
// 128x128x32 tile, 256 threads (4 waves, 2x2 of 64x64), 16x16x32 MFMA.
// ---------------------------------------------------------------------------
template<int ACT>
__global__ __launch_bounds__(256) void gemm_bf16_kernel(
    const ushort_t* __restrict__ A0, const ushort_t* __restrict__ A1, int ksplit,
    int lda0, int lda1, const ushort_t* __restrict__ Wt, int ldw,
    ushort_t* __restrict__ C, int ldc, int Kd)
{
    __shared__ ushort_t As[128 * 32];
    __shared__ ushort_t Bs[128 * 32];

    int tid = threadIdx.x;
    int m0 = blockIdx.y * 128;
    int n0 = blockIdx.x * 128;
    int lane = tid & 63, w = tid >> 6;
    int wrow = w >> 1, wcol = w & 1;
    int quad = lane >> 4, l16 = lane & 15;

    f32x4 acc[4][4];
    #pragma unroll
    for (int i = 0; i < 4; i++)
        #pragma unroll
        for (int j = 0; j < 4; j++) acc[i][j] = (f32x4){0.f, 0.f, 0.f, 0.f};

    int c0 = tid, c1 = tid + 256;
    int ar0 = c0 >> 2, ac0 = (c0 & 3) * 8;
    int ar1 = c1 >> 2, ac1 = (c1 & 3) * 8;

    for (int kb = 0; kb < Kd; kb += 32) {
        const ushort_t* Ab; int lda, kc;
        if (kb < ksplit) { Ab = A0; lda = lda0; kc = kb; }
        else             { Ab = A1; lda = lda1; kc = kb - ksplit; }

        ASYNC_COPY16(Ab + (size_t)(m0 + ar0) * lda + kc + ac0, (char*)As + c0 * 16);
        ASYNC_COPY16(Ab + (size_t)(m0 + ar1) * lda + kc + ac1, (char*)As + c1 * 16);
        ASYNC_COPY16(Wt + (size_t)(n0 + ar0) * ldw + kb + ac0, (char*)Bs + c0 * 16);
        ASYNC_COPY16(Wt + (size_t)(n0 + ar1) * ldw + kb + ac1, (char*)Bs + c1 * 16);
        __syncthreads();

        short8 af[4], bf[4];
        #pragma unroll
        for (int mt = 0; mt < 4; mt++)
            af[mt] = *(const short8*)&As[(wrow * 64 + mt * 16 + l16) * 32 + quad * 8];
        #pragma unroll
        for (int nt = 0; nt < 4; nt++)
            bf[nt] = *(const short8*)&Bs[(wcol * 64 + nt * 16 + l16) * 32 + quad * 8];
        #pragma unroll
        for (int mt = 0; mt < 4; mt++)
            #pragma unroll
            for (int nt = 0; nt < 4; nt++)
                acc[mt][nt] = __builtin_amdgcn_mfma_f32_16x16x32_bf16(
                    af[mt], bf[nt], acc[mt][nt], 0, 0, 0);
        __syncthreads();
    }

    #pragma unroll
    for (int mt = 0; mt < 4; mt++) {
        int row = m0 + wrow * 64 + mt * 16 + quad * 4;
        #pragma unroll
        for (int nt = 0; nt < 4; nt++) {
            int col = n0 + wcol * 64 + nt * 16 + l16;
            #pragma unroll
            for (int r = 0; r < 4; r++) {
                float v = acc[mt][nt][r];
                if (ACT) v = tanhf(v);
                C[(size_t)(row + r) * ldc + col] = f2b(v);
            }
        }
    }
}

// ---------------------------------------------------------------------------
// Weight prep: fp32 [K][N] -> bf16 transposed [N][K]; q/k/v fused into [768][256].
// ---------------------------------------------------------------------------
__global__ __launch_bounds__(256) void wprep_kernel(
    const float* __restrict__ Wq, const float* __restrict__ Wk,
    const float* __restrict__ Wv, const float* __restrict__ Wm,
    const float* __restrict__ W1, const float* __restrict__ W2,
    ushort_t* __restrict__ Wqkvt, ushort_t* __restrict__ Wmt,
    ushort_t* __restrict__ W1t, ushort_t* __restrict__ W2t)
{
    int t = blockIdx.x;
    int layer = t / 640, r = t % 640;
    const float* src; ushort_t* dst;
    int ldsrc, lddst, tn, tk;
    if (r < 192) {
        int grp = r / 64, rr = r % 64; tn = rr / 8; tk = rr % 8;
        src = (grp == 0 ? Wq : grp == 1 ? Wk : Wv) + (size_t)layer * 65536;
        ldsrc = 256;
        dst = Wqkvt + (size_t)layer * 196608 + (size_t)grp * 65536;
        lddst = 256;
    } else if (r < 256) {
        int rr = r - 192; tn = rr / 8; tk = rr % 8;
        src = Wm + (size_t)layer * 65536; ldsrc = 256;
        dst = Wmt + (size_t)layer * 65536; lddst = 256;
    } else if (r < 512) {
        int rr = r - 256; tn = rr / 16; tk = rr % 16;
        src = W1 + (size_t)layer * 262144; ldsrc = 512;
        dst = W1t + (size_t)layer * 262144; lddst = 512;
    } else {
        int rr = r - 512; tn = rr / 16; tk = rr % 16;
        src = W2 + (size_t)layer * 131072; ldsrc = 256;
        dst = W2t + (size_t)layer * 131072; lddst = 512;
    }
    int n0 = tn * 32, k0 = tk * 32;
    __shared__ float tileS[32][33];
    int j = threadIdx.x & 31, i0 = threadIdx.x >> 5;
    #pragma unroll
    for (int p = 0; p < 4; p++) {
        int i = i0 + p * 8;
        tileS[i][j] = src[(size_t)(k0 + i) * ldsrc + n0 + j];
    }
    __syncthreads();
    #pragma unroll
    for (int p = 0; p < 4; p++) {
        int i = i0 + p * 8;
        dst[(size_t)(n0 + i) * lddst + k0 + j] = f2b(tileS[j][i]);
    }
}

// init: X fp32 master + Xbf bf16 mirror from feat0/feat1
__global__ __launch_bounds__(256) void init_kernel(
    const float* __restrict__ f0, const float* __restrict__ f1,
    float* __restrict__ X, ushort_t* __restrict__ Xbf)
{
    int idx = blockIdx.x * 256 + threadIdx.x;      // per float4; 1,048,576 total
    size_t e = (size_t)idx * 4;
    float4 v = (e < 2097152) ? *(const float4*)&f0[e] : *(const float4*)&f1[e - 2097152];
    *(float4*)&X[e] = v;
    ushort4_t u = { f2b(v.x), f2b(v.y), f2b(v.z), f2b(v.w) };
    *(ushort4_t*)&Xbf[e] = u;
}

// ---------------------------------------------------------------------------
// Self-attention KV[g,32,32] + Ksum[g,32] over S=4096, bf16 in (QKV fused, ld=768).
// ---------------------------------------------------------------------------
__global__ __launch_bounds__(256) void kv_reduce_kernel(
    const ushort_t* __restrict__ QKV,
    const int* __restrict__ mask0, const int* __restrict__ mask1,
    float* __restrict__ KV, float* __restrict__ Ksum)
{
    int g = blockIdx.y;
    int t = g >> 4, b = (g >> 3) & 1, h = g & 7;
    const int* mask = t ? mask1 : mask0;
    int rowbase = t * 8192 + b * 4096;
    int s_begin = blockIdx.x * 256;

    __shared__ float sK[32][32];
    __shared__ float sV[32][32];

    int tid = threadIdx.x;
    int e  = tid & 31;
    int dq = tid >> 5;              // 0..7 ; this thread owns d = dq*4..dq*4+3

    float acc[4] = {0.f, 0.f, 0.f, 0.f};
    float ks[4]  = {0.f, 0.f, 0.f, 0.f};

    for (int s0 = s_begin; s0 < s_begin + 256; s0 += 32) {
        #pragma unroll
        for (int q = 0; q < 2; q++) {
            int idx = tid + q * 256;
            int rl = idx >> 4;
            int part = idx & 15;
            int s = s0 + rl;
            size_t row = (size_t)(rowbase + s);
            float m = mask[b * 4096 + s] ? 1.f : 0.f;
            if (part < 8) {
                ushort4_t u = *(const ushort4_t*)&QKV[row * 768 + 256 + h * 32 + part * 4];
                float4 f = { elu1(b2f(u.x)) * m, elu1(b2f(u.y)) * m,
                             elu1(b2f(u.z)) * m, elu1(b2f(u.w)) * m };
                *(float4*)&sK[rl][part * 4] = f;
            } else {
                ushort4_t u = *(const ushort4_t*)&QKV[row * 768 + 512 + h * 32 + (part - 8) * 4];
                float4 f = { b2f(u.x) * m, b2f(u.y) * m, b2f(u.z) * m, b2f(u.w) * m };
                *(float4*)&sV[rl][(part - 8) * 4] = f;
            }
        }
        __syncthreads();

        #pragma unroll
        for (int s = 0; s < 32; s++) {
            float4 kq = *(const float4*)&sK[s][dq * 4];
            float vv = sV[s][e];
            acc[0] += kq.x * vv;
            acc[1] += kq.y * vv;
            acc[2] += kq.z * vv;
            acc[3] += kq.w * vv;
            ks[0] += kq.x; ks[1] += kq.y; ks[2] += kq.z; ks[3] += kq.w;
        }
        __syncthreads();
    }

    #pragma unroll
    for (int j = 0; j < 4; j++)
        atomicAdd(&KV[(size_t)g * 1024 + (dq * 4 + j) * 32 + e], acc[j]);
    if (e == 0) {
        #pragma unroll
        for (int j = 0; j < 4; j++)
            atomicAdd(&Ksum[g * 32 + dq * 4 + j], ks[j]);
    }
}

__global__ __launch_bounds__(256) void attn_apply_kernel(
    const ushort_t* __restrict__ QKV, const float* __restrict__ KV,
    const float* __restrict__ Ksum, ushort_t* __restrict__ MSG)
{
    int row = blockIdx.x;
    int t = row >> 13, bb = (row >> 12) & 1;
    int gb = (t * 2 + bb) * 8;
    int c = threadIdx.x, h = c >> 5, e = c & 31;
    int g = gb + h;

    __shared__ float sQ[256];
    float qf = elu1(b2f(QKV[(size_t)row * 768 + c]));
    sQ[c] = qf;
    __syncthreads();

    float p = qf * Ksum[g * 32 + e];
    #pragma unroll
    for (int off = 16; off; off >>= 1) p += __shfl_xor(p, off, 32);
    float Z = 1.f / (p + 1e-6f);

    float acc = 0.f;
    #pragma unroll
    for (int d = 0; d < 32; d++)
        acc += sQ[h * 32 + d] * KV[(size_t)g * 1024 + d * 32 + e];

    MSG[(size_t)row * 256 + c] = f2b(acc * Z);
}

// ---------------------------------------------------------------------------
// Gram table: for every bilinear anchor cell (65x65 per image, edges clamped)
// the 10 pairwise dot products of the 4 corner feature rows.
// ||sum wi*xi||^2 = sum_ij wi*wj*<xi,xj>.  One wave per anchor.
// G order: 00,01,02,03,11,12,13,22,23,33.
// ---------------------------------------------------------------------------
__global__ __launch_bounds__(256) void gram_kernel(
    const ushort_t* __restrict__ Xbf, float* __restrict__ Gm)
{
    int a = blockIdx.x * 4 + (threadIdx.x >> 6);
    int lane = threadIdx.x & 63;
    int img = a / 4225;
    int rr = a - img * 4225;
    int ay = rr / 65, ax = rr - ay * 65;
    int xa = ax > 0 ? ax - 1 : 0;
    int xb = ax < 64 ? ax : 63;     // but ax==0 must map to 0
    if (ax == 0) xb = 0;
    int ya = ay > 0 ? ay - 1 : 0;
    int yb = ay < 64 ? ay : 63;
    if (ay == 0) yb = 0;

    size_t rbase = (size_t)img * 4096;
    size_t r0 = (rbase + ya * 64 + xa) * 256;
    size_t r1 = (rbase + ya * 64 + xb) * 256;
    size_t r2 = (rbase + yb * 64 + xa) * 256;
    size_t r3 = (rbase + yb * 64 + xb) * 256;

    int c4 = lane * 4;
    ushort4_t u0 = *(const ushort4_t*)&Xbf[r0 + c4];
    ushort4_t u1 = *(const ushort4_t*)&Xbf[r1 + c4];
    ushort4_t u2 = *(const ushort4_t*)&Xbf[r2 + c4];
    ushort4_t u3 = *(const ushort4_t*)&Xbf[r3 + c4];

    float p[10] = {0,0,0,0,0,0,0,0,0,0};
    #pragma unroll
    for (int j = 0; j < 4; j++) {
        float f0 = b2f(u0[j]), f1 = b2f(u1[j]), f2 = b2f(u2[j]), f3 = b2f(u3[j]);
        p[0] += f0 * f0; p[1] += f0 * f1; p[2] += f0 * f2; p[3] += f0 * f3;
        p[4] += f1 * f1; p[5] += f1 * f2; p[6] += f1 * f3;
        p[7] += f2 * f2; p[8] += f2 * f3; p[9] += f3 * f3;
    }
    #pragma unroll
    for (int k = 0; k < 10; k++)
        #pragma unroll
        for (int off = 32; off; off >>= 1) p[k] += __shfl_xor(p[k], off, 64);

    if (lane == 0) {
        #pragma unroll
        for (int k = 0; k < 10; k++) Gm[(size_t)a * 10 + k] = p[k];
    }
}

// ---------------------------------------------------------------------------
// Fused cross attention (S=9): half-wave (32 lanes) per query row, 8 ch/lane.
// Norm from the Gram table (no X gather); K/V gathered as 16B ushort8 loads.
// ---------------------------------------------------------------------------
__global__ __launch_bounds__(256) void cross_fused_kernel(
    const ushort_t* __restrict__ QKV, const float* __restrict__ Gm,
    const float* __restrict__ kp0, const float* __restrict__ kp1,
    const int* __restrict__ maskc0, const int* __restrict__ maskc1,
    ushort_t* __restrict__ MSG)
{
    int wv = threadIdx.x >> 6;
    int lane = threadIdx.x & 63;
    int half = lane >> 5;
    int l32 = lane & 31;
    int row = blockIdx.x * 8 + wv * 2 + half;

    int t = row >> 13;
    int bl = row & 8191;               // b*4096 + l
    int ts = 1 - t;                    // source image
    const float* kp = ts ? kp1 : kp0;
    const int* mask = (t == 0) ? maskc1 : maskc0;
    int img = ts * 2 + (bl >> 12);
    size_t rb = (size_t)img * 4096;    // source row base
    const float* Gimg = Gm + (size_t)img * 42250;

    int c8 = l32 * 8;                  // this lane's 8 channels

    ushort8_t qu = *(const ushort8_t*)&QKV[(size_t)row * 768 + c8];
    float qf[8];
    #pragma unroll
    for (int j = 0; j < 8; j++) qf[j] = elu1(b2f(qu[j]));

    float zsum = 0.f;
    float acc[8] = {0,0,0,0,0,0,0,0};

    for (int s9 = 0; s9 < 9; s9++) {
        int r = bl * 9 + s9;
        float xx = kp[(size_t)r * 2 + 0];
        float yy = kp[(size_t)r * 2 + 1];
        float px = (xx - 3.5f) * (63.f / 507.5f);
        float py = (yy - 3.5f) * (63.f / 507.5f);
        float fx = floorf(px), fy = floorf(py);
        float wx = px - fx, wy = py - fy;
        int ix = (int)fx, iy = (int)fy;            // -1..63
        int xa = ix > 0 ? ix : 0;
        int xb = ix + 1 > 0 ? (ix + 1 < 63 ? ix + 1 : 63) : 0;
        int ya = iy > 0 ? iy : 0;
        int yb = iy + 1 > 0 ? (iy + 1 < 63 ? iy + 1 : 63) : 0;

        float w0 = (1.f - wy) * (1.f - wx);
        float w1 = (1.f - wy) * wx;
        float w2 = wy * (1.f - wx);
        float w3 = wy * wx;

        // norm^2 from Gram table (anchor (iy+1, ix+1))
        const float* G = &Gimg[(size_t)((iy + 1) * 65 + (ix + 1)) * 10];
        float g00 = G[0], g01 = G[1], g02 = G[2], g03 = G[3], g11 = G[4];
        float g12 = G[5], g13 = G[6], g22 = G[7], g23 = G[8], g33 = G[9];
        float ss = w0 * w0 * g00 + w1 * w1 * g11 + w2 * w2 * g22 + w3 * w3 * g33
                 + 2.f * (w0 * w1 * g01 + w0 * w2 * g02 + w0 * w3 * g03
                        + w1 * w2 * g12 + w1 * w3 * g13 + w2 * w3 * g23);
        float inv = 1.f / (sqrtf(ss) + 1e-8f);
        float u0 = w0 * inv, u1 = w1 * inv, u2 = w2 * inv, u3 = w3 * inv;

        size_t s00 = (rb + ya * 64 + xa) * 768;
        size_t s01 = (rb + ya * 64 + xb) * 768;
        size_t s10 = (rb + yb * 64 + xa) * 768;
        size_t s11 = (rb + yb * 64 + xb) * 768;

        ushort8_t k00 = *(const ushort8_t*)&QKV[s00 + 256 + c8];
        ushort8_t k01 = *(const ushort8_t*)&QKV[s01 + 256 + c8];
        ushort8_t k10 = *(const ushort8_t*)&QKV[s10 + 256 + c8];
        ushort8_t k11 = *(const ushort8_t*)&QKV[s11 + 256 + c8];
        ushort8_t v00 = *(const ushort8_t*)&QKV[s00 + 512 + c8];
        ushort8_t v01 = *(const ushort8_t*)&QKV[s01 + 512 + c8];
        ushort8_t v10 = *(const ushort8_t*)&QKV[s10 + 512 + c8];
        ushort8_t v11 = *(const ushort8_t*)&QKV[s11 + 512 + c8];

        bool mk = mask[r] != 0;
        float vc[8];
        float p = 0.f;
        #pragma unroll
        for (int j = 0; j < 8; j++) {
            float kc = u0 * b2f(k00[j]) + u1 * b2f(k01[j])
                     + u2 * b2f(k10[j]) + u3 * b2f(k11[j]);
            vc[j] = u0 * b2f(v00[j]) + u1 * b2f(v01[j])
                  + u2 * b2f(v10[j]) + u3 * b2f(v11[j]);
            p += qf[j] * elu1(kc);
        }
        p = mk ? p : 0.f;
        // head = 32 ch = 4 lanes (group aligned): reduce over 4 lanes
        p += __shfl_xor(p, 1, 64);
        p += __shfl_xor(p, 2, 64);

        zsum += p;
        #pragma unroll
        for (int j = 0; j < 8; j++) acc[j] += p * vc[j];
    }

    float Z = 1.f / (zsum + 1e-6f);
    ushort8_t o;
    #pragma unroll
    for (int j = 0; j < 8; j++) o[j] = f2b(acc[j] * Z);
    *(ushort8_t*)&MSG[(size_t)row * 256 + c8] = o;
}

// ---------------------------------------------------------------------------
// LayerNorm (C=256), wave-per-row (4 rows/block), 4 ch/lane, shuffle-only.
// ---------------------------------------------------------------------------
__device__ __forceinline__ float waveReduceSum(float v) {
    #pragma unroll
    for (int off = 32; off; off >>= 1) v += __shfl_xor(v, off, 64);
    return v;
}

__global__ __launch_bounds__(256) void ln_b_kernel(
    const ushort_t* __restrict__ in, const float* __restrict__ g,
    const float* __restrict__ bp, ushort_t* __restrict__ out)
{
    int row = blockIdx.x * 4 + (threadIdx.x >> 6);
    int lane = threadIdx.x & 63;
    int c4 = lane * 4;
    ushort4_t u = *(const ushort4_t*)&in[(size_t)row * 256 + c4];
    float x0 = b2f(u.x), x1 = b2f(u.y), x2 = b2f(u.z), x3 = b2f(u.w);
    float m = waveReduceSum(x0 + x1 + x2 + x3) * (1.f / 256.f);
    float d0 = x0 - m, d1 = x1 - m, d2 = x2 - m, d3 = x3 - m;
    float v = waveReduceSum(d0 * d0 + d1 * d1 + d2 * d2 + d3 * d3) * (1.f / 256.f);
    float rs = rsqrtf(v + 1e-5f);
    float4 gg = *(const float4*)&g[c4];
    float4 bb = *(const float4*)&bp[c4];
    ushort4_t o = { f2b(d0 * rs * gg.x + bb.x), f2b(d1 * rs * gg.y + bb.y),
                    f2b(d2 * rs * gg.z + bb.z), f2b(d3 * rs * gg.w + bb.w) };
    *(ushort4_t*)&out[(size_t)row * 256 + c4] = o;
}

__global__ __launch_bounds__(256) void ln_res_kernel(
    const ushort_t* __restrict__ in, const float* __restrict__ g,
    const float* __restrict__ bp, float* __restrict__ X, ushort_t* __restrict__ Xbf)
{
    int row = blockIdx.x * 4 + (threadIdx.x >> 6);
    int lane = threadIdx.x & 63;
    int c4 = lane * 4;
    ushort4_t u = *(const ushort4_t*)&in[(size_t)row * 256 + c4];
    float x0 = b2f(u.x), x1 = b2f(u.y), x2 = b2f(u.z), x3 = b2f(u.w);
    float m = waveReduceSum(x0 + x1 + x2 + x3) * (1.f / 256.f);
    float d0 = x0 - m, d1 = x1 - m, d2 = x2 - m, d3 = x3 - m;
    float v = waveReduceSum(d0 * d0 + d1 * d1 + d2 * d2 + d3 * d3) * (1.f / 256.f);
    float rs = rsqrtf(v + 1e-5f);
    float4 gg = *(const float4*)&g[c4];
    float4 bb = *(const float4*)&bp[c4];
    float4 xo = *(float4*)&X[(size_t)row * 256 + c4];
    xo.x += d0 * rs * gg.x + bb.x;
    xo.y += d1 * rs * gg.y + bb.y;
    xo.z += d2 * rs * gg.z + bb.z;
    xo.w += d3 * rs * gg.w + bb.w;
    *(float4*)&X[(size_t)row * 256 + c4] = xo;
    ushort4_t o = { f2b(xo.x), f2b(xo.y), f2b(xo.z), f2b(xo.w) };
    *(ushort4_t*)&Xbf[(size_t)row * 256 + c4] = o;
}

// ---------------------------------------------------------------------------

extern "C" void kernel_launch(void* const* d_in, const int* in_sizes, int n_in,
                              void* d_out, int out_size, void* d_ws, size_t ws_size,
                              hipStream_t stream)
{
    const float* feat0 = (const float*)d_in[0];
    const float* feat1 = (const float*)d_in[1];
    const float* kp0 = (const float*)d_in[2];
    const float* kp1 = (const float*)d_in[3];
    const int* ms0 = (const int*)d_in[4];
    const int* ms1 = (const int*)d_in[5];
    const int* mc0 = (const int*)d_in[6];
    const int* mc1 = (const int*)d_in[7];
    const float* Wq = (const float*)d_in[8];
    const float* Wk = (const float*)d_in[9];
    const float* Wv = (const float*)d_in[10];
    const float* Wm = (const float*)d_in[11];
    const float* W1 = (const float*)d_in[12];
    const float* W2 = (const float*)d_in[13];
    const float* g1 = (const float*)d_in[14];
    const float* b1 = (const float*)d_in[15];
    const float* g2 = (const float*)d_in[16];
    const float* b2 = (const float*)d_in[17];

    // workspace carve (bytes; all offsets 256B-aligned). ~86 MB total.
    char* p = (char*)d_ws;
    float*    X     = (float*)p;            p += 16777216;   // 16384x256 fp32
    ushort_t* Xbf   = (ushort_t*)p;         p += 8388608;    // bf16 mirror
    ushort_t* QKV   = (ushort_t*)p;         p += 25165824;   // 16384x768 bf16
    ushort_t* MSG   = (ushort_t*)p;         p += 8388608;    // 16384x256 bf16 (aliases M2)
    ushort_t* M1T   = (ushort_t*)p;         p += 16777216;   // M1 (16384x256) / T (16384x512)
    ushort_t* L1bf  = (ushort_t*)p;         p += 8388608;    // 16384x256 bf16
    float*    KVb   = (float*)p;            p += 131072;     // 32x1024
    float*    KSb   = (float*)p;            p += 4096;       // 32x32
    float*    Gm    = (float*)p;            p += 679936;     // 4x65x65x10 fp32 Gram
    ushort_t* Wqkvt = (ushort_t*)p;         p += 1572864;    // 4x768x256 bf16
    ushort_t* Wmt   = (ushort_t*)p;         p += 524288;     // 4x256x256
    ushort_t* W1t   = (ushort_t*)p;         p += 2097152;    // 4x512x512
    ushort_t* W2t   = (ushort_t*)p;         p += 1048576;    // 4x256x512
    ushort_t* M1 = M1T;
    ushort_t* T  = M1T;
    ushort_t* M2 = MSG;

    init_kernel<<<4096, 256, 0, stream>>>(feat0, feat1, X, Xbf);
    wprep_kernel<<<2560, 256, 0, stream>>>(Wq, Wk, Wv, Wm, W1, W2, Wqkvt, Wmt, W1t, W2t);

    auto gemm = [&](const ushort_t* A0, const ushort_t* A1, int ksplit, int lda0, int lda1,
                    const ushort_t* Wtp, int ldw, ushort_t* Cp, int ldc, int N, int Kd, int act) {
        dim3 grid(N / 128, NROWS / 128);
        if (act)
            gemm_bf16_kernel<1><<<grid, 256, 0, stream>>>(A0, A1, ksplit, lda0, lda1, Wtp, ldw, Cp, ldc, Kd);
        else
            gemm_bf16_kernel<0><<<grid, 256, 0, stream>>>(A0, A1, ksplit, lda0, lda1, Wtp, ldw, Cp, ldc, Kd);
    };

    for (int i = 0; i < 4; i++) {
        const ushort_t* Wqkvt_l = Wqkvt + (size_t)i * 196608;
        const ushort_t* Wmt_l   = Wmt   + (size_t)i * 65536;
        const ushort_t* W1t_l   = W1t   + (size_t)i * 262144;
        const ushort_t* W2t_l   = W2t   + (size_t)i * 131072;
        const float* g1_l = g1 + (size_t)i * 256;
        const float* b1_l = b1 + (size_t)i * 256;
        const float* g2_l = g2 + (size_t)i * 256;
        const float* b2_l = b2 + (size_t)i * 256;
        bool is_self = (i == 0 || i == 2);

        gemm(Xbf, nullptr, 1 << 30, 256, 0, Wqkvt_l, 256, QKV, 768, 768, 256, 0);

        if (is_self) {
            hipMemsetAsync(KVb, 0, 33792 * 4, stream);
            kv_reduce_kernel<<<dim3(16, 32), 256, 0, stream>>>(QKV, ms0, ms1, KVb, KSb);
            attn_apply_kernel<<<NROWS, 256, 0, stream>>>(QKV, KVb, KSb, MSG);
        } else {
            gram_kernel<<<4225, 256, 0, stream>>>(Xbf, Gm);
            cross_fused_kernel<<<NROWS / 8, 256, 0, stream>>>(QKV, Gm, kp0, kp1, mc0, mc1, MSG);
        }

        gemm(MSG, nullptr, 1 << 30, 256, 0, Wmt_l, 256, M1, 256, 256, 256, 0);
        ln_b_kernel<<<NROWS / 4, 256, 0, stream>>>(M1, g1_l, b1_l, L1bf);
        gemm(Xbf, L1bf, 256, 256, 256, W1t_l, 512, T, 512, 512, 512, 1);  // tanh
        gemm(T, nullptr, 1 << 30, 512, 0, W2t_l, 512, M2, 256, 256, 512, 0);
        ln_res_kernel<<<NROWS / 4, 256, 0, stream>>>(M2, g2_l, b2_l, X, Xbf);
    }

    hipMemcpyAsync(d_out, X, 16777216ull, hipMemcpyDeviceToDevice, stream);
}

// Round 6
// 653.163 us; speedup vs baseline: 3.6432x; 1.0780x over previous
//
#include <hip/hip_runtime.h>
#include <cstddef>

// Shapes (hard-coded): B=2, L=4096 (64x64), C=256, H=8, D=32, K=9, scale=8,
// layers: self,cross,self,cross. X rows: 0..8191 feat0 (b0,b1), 8192..16383 feat1.

#define NROWS 16384

typedef unsigned short ushort_t;
typedef __attribute__((ext_vector_type(8))) short short8;
typedef __attribute__((ext_vector_type(4))) float f32x4;
typedef __attribute__((ext_vector_type(4))) unsigned short ushort4_t;
typedef __attribute__((ext_vector_type(8))) unsigned short ushort8_t;

__device__ __forceinline__ float b2f(unsigned short u) {
    union { unsigned int i; float f; } v; v.i = (unsigned int)u << 16; return v.f;
}
__device__ __forceinline__ unsigned short f2b(float x) {
    union { float f; unsigned int i; } v; v.f = x;
    unsigned int r = v.i + 0x7fffu + ((v.i >> 16) & 1u);   // RNE
    return (unsigned short)(r >> 16);
}
// elu(x)+1: for x<=0, elu = exp(x)-1, so elu+1 = exp(x) exactly.
__device__ __forceinline__ float elu1(float x) {
    return x > 0.f ? x + 1.f : __expf(x);
}

#define ASYNC_COPY16(gptr, lptr) \
    __builtin_amdgcn_global_load_lds((const __attribute__((address_space(1))) void*)(gptr), \
                                     (__attribute__((address_space(3))) void*)(lptr), 16, 0, 0)

// ---------------------------------------------------------------------------
// bf16 MFMA GEMM: C[M,N] = act(A[M,K] @ W[K,N]), W pre-transposed as Wt[N][K].
// 128x128x32 tile, 256 threads (4 waves, 2x2 of 64x64), 16x16x32 MFMA.
// ---------------------------------------------------------------------------
template<int ACT>
__global__ __launch_bounds__(256) void gemm_bf16_kernel(
    const ushort_t* __restrict__ A0, const ushort_t* __restrict__ A1, int ksplit,
    int lda0, int lda1, const ushort_t* __restrict__ Wt, int ldw,
    ushort_t* __restrict__ C, int ldc, int Kd)
{
    __shared__ ushort_t As[128 * 32];
    __shared__ ushort_t Bs[128 * 32];

    int tid = threadIdx.x;
    int m0 = blockIdx.y * 128;
    int n0 = blockIdx.x * 128;
    int lane = tid & 63, w = tid >> 6;
    int wrow = w >> 1, wcol = w & 1;
    int quad = lane >> 4, l16 = lane & 15;

    f32x4 acc[4][4];
    #pragma unroll
    for (int i = 0; i < 4; i++)
        #pragma unroll
        for (int j = 0; j < 4; j++) acc[i][j] = (f32x4){0.f, 0.f, 0.f, 0.f};

    int c0 = tid, c1 = tid + 256;
    int ar0 = c0 >> 2, ac0 = (c0 & 3) * 8;
    int ar1 = c1 >> 2, ac1 = (c1 & 3) * 8;

    for (int kb = 0; kb < Kd; kb += 32) {
        const ushort_t* Ab; int lda, kc;
        if (kb < ksplit) { Ab = A0; lda = lda0; kc = kb; }
        else             { Ab = A1; lda = lda1; kc = kb - ksplit; }

        ASYNC_COPY16(Ab + (size_t)(m0 + ar0) * lda + kc + ac0, (char*)As + c0 * 16);
        ASYNC_COPY16(Ab + (size_t)(m0 + ar1) * lda + kc + ac1, (char*)As + c1 * 16);
        ASYNC_COPY16(Wt + (size_t)(n0 + ar0) * ldw + kb + ac0, (char*)Bs + c0 * 16);
        ASYNC_COPY16(Wt + (size_t)(n0 + ar1) * ldw + kb + ac1, (char*)Bs + c1 * 16);
        __syncthreads();

        short8 af[4], bf[4];
        #pragma unroll
        for (int mt = 0; mt < 4; mt++)
            af[mt] = *(const short8*)&As[(wrow * 64 + mt * 16 + l16) * 32 + quad * 8];
        #pragma unroll
        for (int nt = 0; nt < 4; nt++)
            bf[nt] = *(const short8*)&Bs[(wcol * 64 + nt * 16 + l16) * 32 + quad * 8];
        #pragma unroll
        for (int mt = 0; mt < 4; mt++)
            #pragma unroll
            for (int nt = 0; nt < 4; nt++)
                acc[mt][nt] = __builtin_amdgcn_mfma_f32_16x16x32_bf16(
                    af[mt], bf[nt], acc[mt][nt], 0, 0, 0);
        __syncthreads();
    }

    #pragma unroll
    for (int mt = 0; mt < 4; mt++) {
        int row = m0 + wrow * 64 + mt * 16 + quad * 4;
        #pragma unroll
        for (int nt = 0; nt < 4; nt++) {
            int col = n0 + wcol * 64 + nt * 16 + l16;
            #pragma unroll
            for (int r = 0; r < 4; r++) {
                float v = acc[mt][nt][r];
                if (ACT) v = tanhf(v);
                C[(size_t)(row + r) * ldc + col] = f2b(v);
            }
        }
    }
}

// ---------------------------------------------------------------------------
// GEMM + fused LayerNorm, N=256 (whole row in one block). 64 rows x 256 cols
// per block, 4 waves (each 64x64, wave w owns cols w*64..). BK=64.
// RES=0: OutBf = bf16(LN(A@Wt))           (the Wm -> ln1 path)
// RES=1: xn = Xin + LN(A@Wt); Xout = xn; OutBf = bf16(xn)  (W2 -> ln2 + resid)
// ---------------------------------------------------------------------------
template<int RES>
__global__ __launch_bounds__(256) void gemm_ln_kernel(
    const ushort_t* __restrict__ A, int lda,
    const ushort_t* __restrict__ Wt, int ldw, int Kd,
    const float* __restrict__ g, const float* __restrict__ bp,
    ushort_t* __restrict__ OutBf,
    const float* __restrict__ Xin, float* __restrict__ Xout)
{
    __shared__ ushort_t As[64 * 64];    // 8 KB
    __shared__ ushort_t Bs[256 * 64];   // 32 KB
    __shared__ float rsum[4][64];
    __shared__ float rsq[4][64];

    int tid = threadIdx.x;
    int m0 = blockIdx.x * 64;
    int lane = tid & 63, w = tid >> 6;
    int quad = lane >> 4, l16 = lane & 15;

    f32x4 acc[4][4];
    #pragma unroll
    for (int i = 0; i < 4; i++)
        #pragma unroll
        for (int j = 0; j < 4; j++) acc[i][j] = (f32x4){0.f, 0.f, 0.f, 0.f};

    for (int kb = 0; kb < Kd; kb += 64) {
        // stage A: 64x64 = 512 16B-chunks; chunk c -> row c>>3, col (c&7)*8
        #pragma unroll
        for (int q = 0; q < 2; q++) {
            int c = q * 256 + tid;
            ASYNC_COPY16(A + (size_t)(m0 + (c >> 3)) * lda + kb + (c & 7) * 8,
                         (char*)As + c * 16);
        }
        // stage B: 256x64 = 2048 chunks
        #pragma unroll
        for (int q = 0; q < 8; q++) {
            int c = q * 256 + tid;
            ASYNC_COPY16(Wt + (size_t)(c >> 3) * ldw + kb + (c & 7) * 8,
                         (char*)Bs + c * 16);
        }
        __syncthreads();

        #pragma unroll
        for (int kk = 0; kk < 2; kk++) {
            short8 af[4], bf[4];
            #pragma unroll
            for (int mt = 0; mt < 4; mt++)
                af[mt] = *(const short8*)&As[(mt * 16 + l16) * 64 + kk * 32 + quad * 8];
            #pragma unroll
            for (int nt = 0; nt < 4; nt++)
                bf[nt] = *(const short8*)&Bs[(w * 64 + nt * 16 + l16) * 64 + kk * 32 + quad * 8];
            #pragma unroll
            for (int mt = 0; mt < 4; mt++)
                #pragma unroll
                for (int nt = 0; nt < 4; nt++)
                    acc[mt][nt] = __builtin_amdgcn_mfma_f32_16x16x32_bf16(
                        af[mt], bf[nt], acc[mt][nt], 0, 0, 0);
        }
        __syncthreads();
    }

    // row partial sums over this wave's 64 cols
    float s1[4][4], s2[4][4];
    #pragma unroll
    for (int mt = 0; mt < 4; mt++)
        #pragma unroll
        for (int r = 0; r < 4; r++) {
            float s = 0.f, q = 0.f;
            #pragma unroll
            for (int nt = 0; nt < 4; nt++) {
                float v = acc[mt][nt][r];
                s += v; q += v * v;
            }
            // reduce across l16 (16 lanes of this quad)
            #pragma unroll
            for (int off = 1; off < 16; off <<= 1) {
                s += __shfl_xor(s, off, 64);
                q += __shfl_xor(q, off, 64);
            }
            s1[mt][r] = s; s2[mt][r] = q;
        }
    if (l16 == 0) {
        #pragma unroll
        for (int mt = 0; mt < 4; mt++)
            #pragma unroll
            for (int r = 0; r < 4; r++) {
                rsum[w][mt * 16 + quad * 4 + r] = s1[mt][r];
                rsq[w][mt * 16 + quad * 4 + r]  = s2[mt][r];
            }
    }
    __syncthreads();

    #pragma unroll
    for (int mt = 0; mt < 4; mt++) {
        #pragma unroll
        for (int r = 0; r < 4; r++) {
            int rl = mt * 16 + quad * 4 + r;
            float s = rsum[0][rl] + rsum[1][rl] + rsum[2][rl] + rsum[3][rl];
            float q = rsq[0][rl] + rsq[1][rl] + rsq[2][rl] + rsq[3][rl];
            float m = s * (1.f / 256.f);
            float var = q * (1.f / 256.f) - m * m;
            float rs = rsqrtf(var + 1e-5f);
            size_t row = (size_t)(m0 + rl);
            #pragma unroll
            for (int nt = 0; nt < 4; nt++) {
                int col = w * 64 + nt * 16 + l16;
                float y = (acc[mt][nt][r] - m) * rs * g[col] + bp[col];
                if (RES) {
                    float xn = Xin[row * 256 + col] + y;
                    Xout[row * 256 + col] = xn;
                    OutBf[row * 256 + col] = f2b(xn);
                } else {
                    OutBf[row * 256 + col] = f2b(y);
                }
            }
        }
    }
}

// ---------------------------------------------------------------------------
// Weight prep: fp32 [K][N] -> bf16 transposed [N][K]; q/k/v fused into [768][256].
// ---------------------------------------------------------------------------
__global__ __launch_bounds__(256) void wprep_kernel(
    const float* __restrict__ Wq, const float* __restrict__ Wk,
    const float* __restrict__ Wv, const float* __restrict__ Wm,
    const float* __restrict__ W1, const float* __restrict__ W2,
    ushort_t* __restrict__ Wqkvt, ushort_t* __restrict__ Wmt,
    ushort_t* __restrict__ W1t, ushort_t* __restrict__ W2t)
{
    int t = blockIdx.x;
    int layer = t / 640, r = t % 640;
    const float* src; ushort_t* dst;
    int ldsrc, lddst, tn, tk;
    if (r < 192) {
        int grp = r / 64, rr = r % 64; tn = rr / 8; tk = rr % 8;
        src = (grp == 0 ? Wq : grp == 1 ? Wk : Wv) + (size_t)layer * 65536;
        ldsrc = 256;
        dst = Wqkvt + (size_t)layer * 196608 + (size_t)grp * 65536;
        lddst = 256;
    } else if (r < 256) {
        int rr = r - 192; tn = rr / 8; tk = rr % 8;
        src = Wm + (size_t)layer * 65536; ldsrc = 256;
        dst = Wmt + (size_t)layer * 65536; lddst = 256;
    } else if (r < 512) {
        int rr = r - 256; tn = rr / 16; tk = rr % 16;
        src = W1 + (size_t)layer * 262144; ldsrc = 512;
        dst = W1t + (size_t)layer * 262144; lddst = 512;
    } else {
        int rr = r - 512; tn = rr / 16; tk = rr % 16;
        src = W2 + (size_t)layer * 131072; ldsrc = 256;
        dst = W2t + (size_t)layer * 131072; lddst = 512;
    }
    int n0 = tn * 32, k0 = tk * 32;
    __shared__ float tileS[32][33];
    int j = threadIdx.x & 31, i0 = threadIdx.x >> 5;
    #pragma unroll
    for (int p = 0; p < 4; p++) {
        int i = i0 + p * 8;
        tileS[i][j] = src[(size_t)(k0 + i) * ldsrc + n0 + j];
    }
    __syncthreads();
    #pragma unroll
    for (int p = 0; p < 4; p++) {
        int i = i0 + p * 8;
        dst[(size_t)(n0 + i) * lddst + k0 + j] = f2b(tileS[j][i]);
    }
}

// init: X fp32 master + Xbf bf16 mirror from feat0/feat1
__global__ __launch_bounds__(256) void init_kernel(
    const float* __restrict__ f0, const float* __restrict__ f1,
    float* __restrict__ X, ushort_t* __restrict__ Xbf)
{
    int idx = blockIdx.x * 256 + threadIdx.x;      // per float4; 1,048,576 total
    size_t e = (size_t)idx * 4;
    float4 v = (e < 2097152) ? *(const float4*)&f0[e] : *(const float4*)&f1[e - 2097152];
    *(float4*)&X[e] = v;
    ushort4_t u = { f2b(v.x), f2b(v.y), f2b(v.z), f2b(v.w) };
    *(ushort4_t*)&Xbf[e] = u;
}

// ---------------------------------------------------------------------------
// Self-attention KV[g,32,32] + Ksum[g,32] over S=4096, bf16 in (QKV fused, ld=768).
// ---------------------------------------------------------------------------
__global__ __launch_bounds__(256) void kv_reduce_kernel(
    const ushort_t* __restrict__ QKV,
    const int* __restrict__ mask0, const int* __restrict__ mask1,
    float* __restrict__ KV, float* __restrict__ Ksum)
{
    int g = blockIdx.y;
    int t = g >> 4, b = (g >> 3) & 1, h = g & 7;
    const int* mask = t ? mask1 : mask0;
    int rowbase = t * 8192 + b * 4096;
    int s_begin = blockIdx.x * 256;

    __shared__ float sK[32][32];
    __shared__ float sV[32][32];

    int tid = threadIdx.x;
    int e  = tid & 31;
    int dq = tid >> 5;              // 0..7 ; this thread owns d = dq*4..dq*4+3

    float acc[4] = {0.f, 0.f, 0.f, 0.f};
    float ks[4]  = {0.f, 0.f, 0.f, 0.f};

    for (int s0 = s_begin; s0 < s_begin + 256; s0 += 32) {
        #pragma unroll
        for (int q = 0; q < 2; q++) {
            int idx = tid + q * 256;
            int rl = idx >> 4;
            int part = idx & 15;
            int s = s0 + rl;
            size_t row = (size_t)(rowbase + s);
            float m = mask[b * 4096 + s] ? 1.f : 0.f;
            if (part < 8) {
                ushort4_t u = *(const ushort4_t*)&QKV[row * 768 + 256 + h * 32 + part * 4];
                float4 f = { elu1(b2f(u.x)) * m, elu1(b2f(u.y)) * m,
                             elu1(b2f(u.z)) * m, elu1(b2f(u.w)) * m };
                *(float4*)&sK[rl][part * 4] = f;
            } else {
                ushort4_t u = *(const ushort4_t*)&QKV[row * 768 + 512 + h * 32 + (part - 8) * 4];
                float4 f = { b2f(u.x) * m, b2f(u.y) * m, b2f(u.z) * m, b2f(u.w) * m };
                *(float4*)&sV[rl][(part - 8) * 4] = f;
            }
        }
        __syncthreads();

        #pragma unroll
        for (int s = 0; s < 32; s++) {
            float4 kq = *(const float4*)&sK[s][dq * 4];
            float vv = sV[s][e];
            acc[0] += kq.x * vv;
            acc[1] += kq.y * vv;
            acc[2] += kq.z * vv;
            acc[3] += kq.w * vv;
            ks[0] += kq.x; ks[1] += kq.y; ks[2] += kq.z; ks[3] += kq.w;
        }
        __syncthreads();
    }

    #pragma unroll
    for (int j = 0; j < 4; j++)
        atomicAdd(&KV[(size_t)g * 1024 + (dq * 4 + j) * 32 + e], acc[j]);
    if (e == 0) {
        #pragma unroll
        for (int j = 0; j < 4; j++)
            atomicAdd(&Ksum[g * 32 + dq * 4 + j], ks[j]);
    }
}

__global__ __launch_bounds__(256) void attn_apply_kernel(
    const ushort_t* __restrict__ QKV, const float* __restrict__ KV,
    const float* __restrict__ Ksum, ushort_t* __restrict__ MSG)
{
    int row = blockIdx.x;
    int t = row >> 13, bb = (row >> 12) & 1;
    int gb = (t * 2 + bb) * 8;
    int c = threadIdx.x, h = c >> 5, e = c & 31;
    int g = gb + h;

    __shared__ float sQ[256];
    float qf = elu1(b2f(QKV[(size_t)row * 768 + c]));
    sQ[c] = qf;
    __syncthreads();

    float p = qf * Ksum[g * 32 + e];
    #pragma unroll
    for (int off = 16; off; off >>= 1) p += __shfl_xor(p, off, 32);
    float Z = 1.f / (p + 1e-6f);

    float acc = 0.f;
    #pragma unroll
    for (int d = 0; d < 32; d++)
        acc += sQ[h * 32 + d] * KV[(size_t)g * 1024 + d * 32 + e];

    MSG[(size_t)row * 256 + c] = f2b(acc * Z);
}

// ---------------------------------------------------------------------------
// Gram table: for every bilinear anchor cell (65x65 per image, edges clamped)
// the 10 pairwise dot products of the 4 corner feature rows.
// ||sum wi*xi||^2 = sum_ij wi*wj*<xi,xj>.  One wave per anchor.
// G order: 00,01,02,03,11,12,13,22,23,33.
// ---------------------------------------------------------------------------
__global__ __launch_bounds__(256) void gram_kernel(
    const ushort_t* __restrict__ Xbf, float* __restrict__ Gm)
{
    int a = blockIdx.x * 4 + (threadIdx.x >> 6);
    int lane = threadIdx.x & 63;
    int img = a / 4225;
    int rr = a - img * 4225;
    int ay = rr / 65, ax = rr - ay * 65;
    int xa = ax > 0 ? ax - 1 : 0;
    int xb = ax < 64 ? ax : 63;
    if (ax == 0) xb = 0;
    int ya = ay > 0 ? ay - 1 : 0;
    int yb = ay < 64 ? ay : 63;
    if (ay == 0) yb = 0;

    size_t rbase = (size_t)img * 4096;
    size_t r0 = (rbase + ya * 64 + xa) * 256;
    size_t r1 = (rbase + ya * 64 + xb) * 256;
    size_t r2 = (rbase + yb * 64 + xa) * 256;
    size_t r3 = (rbase + yb * 64 + xb) * 256;

    int c4 = lane * 4;
    ushort4_t u0 = *(const ushort4_t*)&Xbf[r0 + c4];
    ushort4_t u1 = *(const ushort4_t*)&Xbf[r1 + c4];
    ushort4_t u2 = *(const ushort4_t*)&Xbf[r2 + c4];
    ushort4_t u3 = *(const ushort4_t*)&Xbf[r3 + c4];

    float p[10] = {0,0,0,0,0,0,0,0,0,0};
    #pragma unroll
    for (int j = 0; j < 4; j++) {
        float f0 = b2f(u0[j]), f1 = b2f(u1[j]), f2 = b2f(u2[j]), f3 = b2f(u3[j]);
        p[0] += f0 * f0; p[1] += f0 * f1; p[2] += f0 * f2; p[3] += f0 * f3;
        p[4] += f1 * f1; p[5] += f1 * f2; p[6] += f1 * f3;
        p[7] += f2 * f2; p[8] += f2 * f3; p[9] += f3 * f3;
    }
    #pragma unroll
    for (int k = 0; k < 10; k++)
        #pragma unroll
        for (int off = 32; off; off >>= 1) p[k] += __shfl_xor(p[k], off, 64);

    if (lane == 0) {
        #pragma unroll
        for (int k = 0; k < 10; k++) Gm[(size_t)a * 10 + k] = p[k];
    }
}

// ---------------------------------------------------------------------------
// Fused cross attention (S=9): half-wave (32 lanes) per query row, 8 ch/lane.
// Norm from the Gram table; K/V gathered as 16B ushort8 loads. Masked-out
// samples skip ALL gathers/compute (mask uniform per half-wave).
// ---------------------------------------------------------------------------
__global__ __launch_bounds__(256) void cross_fused_kernel(
    const ushort_t* __restrict__ QKV, const float* __restrict__ Gm,
    const float* __restrict__ kp0, const float* __restrict__ kp1,
    const int* __restrict__ maskc0, const int* __restrict__ maskc1,
    ushort_t* __restrict__ MSG)
{
    int wv = threadIdx.x >> 6;
    int lane = threadIdx.x & 63;
    int half = lane >> 5;
    int l32 = lane & 31;
    int row = blockIdx.x * 8 + wv * 2 + half;

    int t = row >> 13;
    int bl = row & 8191;               // b*4096 + l
    int ts = 1 - t;                    // source image
    const float* kp = ts ? kp1 : kp0;
    const int* mask = (t == 0) ? maskc1 : maskc0;
    int img = ts * 2 + (bl >> 12);
    size_t rb = (size_t)img * 4096;    // source row base
    const float* Gimg = Gm + (size_t)img * 42250;

    int c8 = l32 * 8;                  // this lane's 8 channels

    ushort8_t qu = *(const ushort8_t*)&QKV[(size_t)row * 768 + c8];
    float qf[8];
    #pragma unroll
    for (int j = 0; j < 8; j++) qf[j] = elu1(b2f(qu[j]));

    float zsum = 0.f;
    float acc[8] = {0,0,0,0,0,0,0,0};

    for (int s9 = 0; s9 < 9; s9++) {
        int r = bl * 9 + s9;
        bool mk = mask[r] != 0;
        if (mk) {
            float xx = kp[(size_t)r * 2 + 0];
            float yy = kp[(size_t)r * 2 + 1];
            float px = (xx - 3.5f) * (63.f / 507.5f);
            float py = (yy - 3.5f) * (63.f / 507.5f);
            float fx = floorf(px), fy = floorf(py);
            float wx = px - fx, wy = py - fy;
            int ix = (int)fx, iy = (int)fy;            // -1..63
            int xa = ix > 0 ? ix : 0;
            int xb = ix + 1 > 0 ? (ix + 1 < 63 ? ix + 1 : 63) : 0;
            int ya = iy > 0 ? iy : 0;
            int yb = iy + 1 > 0 ? (iy + 1 < 63 ? iy + 1 : 63) : 0;

            float w0 = (1.f - wy) * (1.f - wx);
            float w1 = (1.f - wy) * wx;
            float w2 = wy * (1.f - wx);
            float w3 = wy * wx;

            const float* G = &Gimg[(size_t)((iy + 1) * 65 + (ix + 1)) * 10];
            float g00 = G[0], g01 = G[1], g02 = G[2], g03 = G[3], g11 = G[4];
            float g12 = G[5], g13 = G[6], g22 = G[7], g23 = G[8], g33 = G[9];
            float ss = w0 * w0 * g00 + w1 * w1 * g11 + w2 * w2 * g22 + w3 * w3 * g33
                     + 2.f * (w0 * w1 * g01 + w0 * w2 * g02 + w0 * w3 * g03
                            + w1 * w2 * g12 + w1 * w3 * g13 + w2 * w3 * g23);
            float inv = 1.f / (sqrtf(ss) + 1e-8f);
            float u0 = w0 * inv, u1 = w1 * inv, u2 = w2 * inv, u3 = w3 * inv;

            size_t s00 = (rb + ya * 64 + xa) * 768;
            size_t s01 = (rb + ya * 64 + xb) * 768;
            size_t s10 = (rb + yb * 64 + xa) * 768;
            size_t s11 = (rb + yb * 64 + xb) * 768;

            ushort8_t k00 = *(const ushort8_t*)&QKV[s00 + 256 + c8];
            ushort8_t k01 = *(const ushort8_t*)&QKV[s01 + 256 + c8];
            ushort8_t k10 = *(const ushort8_t*)&QKV[s10 + 256 + c8];
            ushort8_t k11 = *(const ushort8_t*)&QKV[s11 + 256 + c8];
            ushort8_t v00 = *(const ushort8_t*)&QKV[s00 + 512 + c8];
            ushort8_t v01 = *(const ushort8_t*)&QKV[s01 + 512 + c8];
            ushort8_t v10 = *(const ushort8_t*)&QKV[s10 + 512 + c8];
            ushort8_t v11 = *(const ushort8_t*)&QKV[s11 + 512 + c8];

            float vc[8];
            float p = 0.f;
            #pragma unroll
            for (int j = 0; j < 8; j++) {
                float kc = u0 * b2f(k00[j]) + u1 * b2f(k01[j])
                         + u2 * b2f(k10[j]) + u3 * b2f(k11[j]);
                vc[j] = u0 * b2f(v00[j]) + u1 * b2f(v01[j])
                      + u2 * b2f(v10[j]) + u3 * b2f(v11[j]);
                p += qf[j] * elu1(kc);
            }
            // head = 32 ch = 4 lanes (group aligned): reduce over 4 lanes
            p += __shfl_xor(p, 1, 64);
            p += __shfl_xor(p, 2, 64);

            zsum += p;
            #pragma unroll
            for (int j = 0; j < 8; j++) acc[j] += p * vc[j];
        }
    }

    float Z = 1.f / (zsum + 1e-6f);
    ushort8_t o;
    #pragma unroll
    for (int j = 0; j < 8; j++) o[j] = f2b(acc[j] * Z);
    *(ushort8_t*)&MSG[(size_t)row * 256 + c8] = o;
}

// ---------------------------------------------------------------------------

extern "C" void kernel_launch(void* const* d_in, const int* in_sizes, int n_in,
                              void* d_out, int out_size, void* d_ws, size_t ws_size,
                              hipStream_t stream)
{
    const float* feat0 = (const float*)d_in[0];
    const float* feat1 = (const float*)d_in[1];
    const float* kp0 = (const float*)d_in[2];
    const float* kp1 = (const float*)d_in[3];
    const int* ms0 = (const int*)d_in[4];
    const int* ms1 = (const int*)d_in[5];
    const int* mc0 = (const int*)d_in[6];
    const int* mc1 = (const int*)d_in[7];
    const float* Wq = (const float*)d_in[8];
    const float* Wk = (const float*)d_in[9];
    const float* Wv = (const float*)d_in[10];
    const float* Wm = (const float*)d_in[11];
    const float* W1 = (const float*)d_in[12];
    const float* W2 = (const float*)d_in[13];
    const float* g1 = (const float*)d_in[14];
    const float* b1 = (const float*)d_in[15];
    const float* g2 = (const float*)d_in[16];
    const float* b2 = (const float*)d_in[17];

    // workspace carve (bytes; all offsets 256B-aligned). ~70 MB total.
    char* p = (char*)d_ws;
    float*    X     = (float*)p;            p += 16777216;   // 16384x256 fp32
    ushort_t* Xbf   = (ushort_t*)p;         p += 8388608;    // bf16 mirror
    ushort_t* QKV   = (ushort_t*)p;         p += 25165824;   // 16384x768 bf16
    ushort_t* MSG   = (ushort_t*)p;         p += 8388608;    // 16384x256 bf16
    ushort_t* T     = (ushort_t*)p;         p += 16777216;   // 16384x512 bf16
    ushort_t* L1bf  = (ushort_t*)p;         p += 8388608;    // 16384x256 bf16
    float*    KVb   = (float*)p;            p += 131072;     // 32x1024
    float*    KSb   = (float*)p;            p += 4096;       // 32x32
    float*    Gm    = (float*)p;            p += 679936;     // 4x65x65x10 fp32 Gram
    ushort_t* Wqkvt = (ushort_t*)p;         p += 1572864;    // 4x768x256 bf16
    ushort_t* Wmt   = (ushort_t*)p;         p += 524288;     // 4x256x256
    ushort_t* W1t   = (ushort_t*)p;         p += 2097152;    // 4x512x512
    ushort_t* W2t   = (ushort_t*)p;         p += 1048576;    // 4x256x512

    init_kernel<<<4096, 256, 0, stream>>>(feat0, feat1, X, Xbf);
    wprep_kernel<<<2560, 256, 0, stream>>>(Wq, Wk, Wv, Wm, W1, W2, Wqkvt, Wmt, W1t, W2t);

    auto gemm = [&](const ushort_t* A0, const ushort_t* A1, int ksplit, int lda0, int lda1,
                    const ushort_t* Wtp, int ldw, ushort_t* Cp, int ldc, int N, int Kd, int act) {
        dim3 grid(N / 128, NROWS / 128);
        if (act)
            gemm_bf16_kernel<1><<<grid, 256, 0, stream>>>(A0, A1, ksplit, lda0, lda1, Wtp, ldw, Cp, ldc, Kd);
        else
            gemm_bf16_kernel<0><<<grid, 256, 0, stream>>>(A0, A1, ksplit, lda0, lda1, Wtp, ldw, Cp, ldc, Kd);
    };

    for (int i = 0; i < 4; i++) {
        const ushort_t* Wqkvt_l = Wqkvt + (size_t)i * 196608;
        const ushort_t* Wmt_l   = Wmt   + (size_t)i * 65536;
        const ushort_t* W1t_l   = W1t   + (size_t)i * 262144;
        const ushort_t* W2t_l   = W2t   + (size_t)i * 131072;
        const float* g1_l = g1 + (size_t)i * 256;
        const float* b1_l = b1 + (size_t)i * 256;
        const float* g2_l = g2 + (size_t)i * 256;
        const float* b2_l = b2 + (size_t)i * 256;
        bool is_self = (i == 0 || i == 2);

        gemm(Xbf, nullptr, 1 << 30, 256, 0, Wqkvt_l, 256, QKV, 768, 768, 256, 0);

        if (is_self) {
            hipMemsetAsync(KVb, 0, 33792 * 4, stream);
            kv_reduce_kernel<<<dim3(16, 32), 256, 0, stream>>>(QKV, ms0, ms1, KVb, KSb);
            attn_apply_kernel<<<NROWS, 256, 0, stream>>>(QKV, KVb, KSb, MSG);
        } else {
            gram_kernel<<<4225, 256, 0, stream>>>(Xbf, Gm);
            cross_fused_kernel<<<NROWS / 8, 256, 0, stream>>>(QKV, Gm, kp0, kp1, mc0, mc1, MSG);
        }

        // M1 = MSG @ Wm ; L1 = ln1(M1)  (fused)
        gemm_ln_kernel<0><<<NROWS / 64, 256, 0, stream>>>(
            MSG, 256, Wmt_l, 256, 256, g1_l, b1_l, L1bf, nullptr, nullptr);
        // T = tanh(cat(Xbf, L1) @ W1)
        gemm(Xbf, L1bf, 256, 256, 256, W1t_l, 512, T, 512, 512, 512, 1);
        // M2 = T @ W2 ; X += ln2(M2) ; Xbf = bf16(X)   (fused; last layer -> d_out)
        float* Xout = (i == 3) ? (float*)d_out : X;
        gemm_ln_kernel<1><<<NROWS / 64, 256, 0, stream>>>(
            T, 512, W2t_l, 512, 512, g2_l, b2_l, Xbf, X, Xout);
    }
}

// Round 7
// 638.649 us; speedup vs baseline: 3.7260x; 1.0227x over previous
//
#include <hip/hip_runtime.h>
#include <cstddef>

// Shapes (hard-coded): B=2, L=4096 (64x64), C=256, H=8, D=32, K=9, scale=8,
// layers: self,cross,self,cross. X rows: 0..8191 feat0 (b0,b1), 8192..16383 feat1.

#define NROWS 16384

typedef unsigned short ushort_t;
typedef __attribute__((ext_vector_type(8))) short short8;
typedef __attribute__((ext_vector_type(4))) float f32x4;
typedef __attribute__((ext_vector_type(4))) unsigned short ushort4_t;
typedef __attribute__((ext_vector_type(8))) unsigned short ushort8_t;

__device__ __forceinline__ float b2f(unsigned short u) {
    union { unsigned int i; float f; } v; v.i = (unsigned int)u << 16; return v.f;
}
__device__ __forceinline__ unsigned short f2b(float x) {
    union { float f; unsigned int i; } v; v.f = x;
    unsigned int r = v.i + 0x7fffu + ((v.i >> 16) & 1u);   // RNE
    return (unsigned short)(r >> 16);
}
// elu(x)+1: for x<=0, elu = exp(x)-1, so elu+1 = exp(x) exactly.
__device__ __forceinline__ float elu1(float x) {
    return x > 0.f ? x + 1.f : __expf(x);
}

#define ASYNC_COPY16(gptr, lptr) \
    __builtin_amdgcn_global_load_lds((const __attribute__((address_space(1))) void*)(gptr), \
                                     (__attribute__((address_space(3))) void*)(lptr), 16, 0, 0)

// ---------------------------------------------------------------------------
// bf16 MFMA GEMM: C[M,N] = act(A[M,K] @ W[K,N]), W pre-transposed as Wt[N][K].
// 128x128 tile, BK=64 (two 32-col LDS panels -> 32 MFMA per barrier pair).
// 256 threads (4 waves, 2x2 of 64x64), 16x16x32 MFMA.
// LDS layout per buffer: panel kk (kk=0,1) of 128x32, element (row,col) at
// [kk*4096 + row*32 + col] ushorts. global_load_lds slot s (16B) = s*16 bytes;
// slot -> (kk = s>>9, row = (s&511)>>2, c4 = s&3), global col = kk*32 + c4*8.
// ---------------------------------------------------------------------------
template<int ACT>
__global__ __launch_bounds__(256) void gemm_bf16_kernel(
    const ushort_t* __restrict__ A0, const ushort_t* __restrict__ A1, int ksplit,
    int lda0, int lda1, const ushort_t* __restrict__ Wt, int ldw,
    ushort_t* __restrict__ C, int ldc, int Kd)
{
    __shared__ ushort_t As[128 * 64];   // 16 KB
    __shared__ ushort_t Bs[128 * 64];   // 16 KB

    int tid = threadIdx.x;
    int m0 = blockIdx.y * 128;
    int n0 = blockIdx.x * 128;
    int lane = tid & 63, w = tid >> 6;
    int wrow = w >> 1, wcol = w & 1;
    int quad = lane >> 4, l16 = lane & 15;

    f32x4 acc[4][4];
    #pragma unroll
    for (int i = 0; i < 4; i++)
        #pragma unroll
        for (int j = 0; j < 4; j++) acc[i][j] = (f32x4){0.f, 0.f, 0.f, 0.f};

    for (int kb = 0; kb < Kd; kb += 64) {
        const ushort_t* Ab; int lda, kc;
        if (kb < ksplit) { Ab = A0; lda = lda0; kc = kb; }
        else             { Ab = A1; lda = lda1; kc = kb - ksplit; }

        #pragma unroll
        for (int q = 0; q < 4; q++) {
            int s = q * 256 + tid;
            int kk = s >> 9, p = s & 511;
            int row = p >> 2, c4 = p & 3;
            ASYNC_COPY16(Ab + (size_t)(m0 + row) * lda + kc + kk * 32 + c4 * 8,
                         (char*)As + s * 16);
        }
        #pragma unroll
        for (int q = 0; q < 4; q++) {
            int s = q * 256 + tid;
            int kk = s >> 9, p = s & 511;
            int row = p >> 2, c4 = p & 3;
            ASYNC_COPY16(Wt + (size_t)(n0 + row) * ldw + kb + kk * 32 + c4 * 8,
                         (char*)Bs + s * 16);
        }
        __syncthreads();

        #pragma unroll
        for (int kk = 0; kk < 2; kk++) {
            short8 af[4], bf[4];
            #pragma unroll
            for (int mt = 0; mt < 4; mt++)
                af[mt] = *(const short8*)&As[kk * 4096 + (wrow * 64 + mt * 16 + l16) * 32 + quad * 8];
            #pragma unroll
            for (int nt = 0; nt < 4; nt++)
                bf[nt] = *(const short8*)&Bs[kk * 4096 + (wcol * 64 + nt * 16 + l16) * 32 + quad * 8];
            #pragma unroll
            for (int mt = 0; mt < 4; mt++)
                #pragma unroll
                for (int nt = 0; nt < 4; nt++)
                    acc[mt][nt] = __builtin_amdgcn_mfma_f32_16x16x32_bf16(
                        af[mt], bf[nt], acc[mt][nt], 0, 0, 0);
        }
        __syncthreads();
    }

    #pragma unroll
    for (int mt = 0; mt < 4; mt++) {
        int row = m0 + wrow * 64 + mt * 16 + quad * 4;
        #pragma unroll
        for (int nt = 0; nt < 4; nt++) {
            int col = n0 + wcol * 64 + nt * 16 + l16;
            #pragma unroll
            for (int r = 0; r < 4; r++) {
                float v = acc[mt][nt][r];
                if (ACT) v = tanhf(v);
                C[(size_t)(row + r) * ldc + col] = f2b(v);
            }
        }
    }
}

// ---------------------------------------------------------------------------
// GEMM + fused LayerNorm, N=256 (whole row in one block). 32 rows x 256 cols
// per block (grid 512 -> 2 blocks/CU), 4 waves (wave w owns cols w*64). BK=64
// with the same two-panel LDS layout.
// RES=0: OutBf = bf16(LN(A@Wt))           (the Wm -> ln1 path)
// RES=1: xn = Xin + LN(A@Wt); Xout = xn; OutBf = bf16(xn)  (W2 -> ln2 + resid)
// ---------------------------------------------------------------------------
template<int RES>
__global__ __launch_bounds__(256) void gemm_ln_kernel(
    const ushort_t* __restrict__ A, int lda,
    const ushort_t* __restrict__ Wt, int ldw, int Kd,
    const float* __restrict__ g, const float* __restrict__ bp,
    ushort_t* __restrict__ OutBf,
    const float* __restrict__ Xin, float* __restrict__ Xout)
{
    __shared__ ushort_t As[32 * 64];    // 4 KB, panels of 32x32
    __shared__ ushort_t Bs[256 * 64];   // 32 KB, panels of 256x32
    __shared__ float rsum[4][32];
    __shared__ float rsq[4][32];

    int tid = threadIdx.x;
    int m0 = blockIdx.x * 32;
    int lane = tid & 63, w = tid >> 6;
    int quad = lane >> 4, l16 = lane & 15;

    f32x4 acc[2][4];
    #pragma unroll
    for (int i = 0; i < 2; i++)
        #pragma unroll
        for (int j = 0; j < 4; j++) acc[i][j] = (f32x4){0.f, 0.f, 0.f, 0.f};

    for (int kb = 0; kb < Kd; kb += 64) {
        // As: 32x64 = 256 chunks; slot s=tid: kk=s>>7, p=s&127, row=p>>2, c4=p&3
        {
            int s = tid;
            int kk = s >> 7, p = s & 127;
            int row = p >> 2, c4 = p & 3;
            ASYNC_COPY16(A + (size_t)(m0 + row) * lda + kb + kk * 32 + c4 * 8,
                         (char*)As + s * 16);
        }
        // Bs: 256x64 = 2048 chunks; kk=s>>10, p=s&1023, row=p>>2, c4=p&3
        #pragma unroll
        for (int q = 0; q < 8; q++) {
            int s = q * 256 + tid;
            int kk = s >> 10, p = s & 1023;
            int row = p >> 2, c4 = p & 3;
            ASYNC_COPY16(Wt + (size_t)(row) * ldw + kb + kk * 32 + c4 * 8,
                         (char*)Bs + s * 16);
        }
        __syncthreads();

        #pragma unroll
        for (int kk = 0; kk < 2; kk++) {
            short8 af[2], bf[4];
            #pragma unroll
            for (int mt = 0; mt < 2; mt++)
                af[mt] = *(const short8*)&As[kk * 1024 + (mt * 16 + l16) * 32 + quad * 8];
            #pragma unroll
            for (int nt = 0; nt < 4; nt++)
                bf[nt] = *(const short8*)&Bs[kk * 8192 + (w * 64 + nt * 16 + l16) * 32 + quad * 8];
            #pragma unroll
            for (int mt = 0; mt < 2; mt++)
                #pragma unroll
                for (int nt = 0; nt < 4; nt++)
                    acc[mt][nt] = __builtin_amdgcn_mfma_f32_16x16x32_bf16(
                        af[mt], bf[nt], acc[mt][nt], 0, 0, 0);
        }
        __syncthreads();
    }

    // row partial sums over this wave's 64 cols
    #pragma unroll
    for (int mt = 0; mt < 2; mt++)
        #pragma unroll
        for (int r = 0; r < 4; r++) {
            float s = 0.f, q = 0.f;
            #pragma unroll
            for (int nt = 0; nt < 4; nt++) {
                float v = acc[mt][nt][r];
                s += v; q += v * v;
            }
            #pragma unroll
            for (int off = 1; off < 16; off <<= 1) {
                s += __shfl_xor(s, off, 64);
                q += __shfl_xor(q, off, 64);
            }
            if (l16 == 0) {
                rsum[w][mt * 16 + quad * 4 + r] = s;
                rsq[w][mt * 16 + quad * 4 + r]  = q;
            }
        }
    __syncthreads();

    #pragma unroll
    for (int mt = 0; mt < 2; mt++) {
        #pragma unroll
        for (int r = 0; r < 4; r++) {
            int rl = mt * 16 + quad * 4 + r;
            float s = rsum[0][rl] + rsum[1][rl] + rsum[2][rl] + rsum[3][rl];
            float q = rsq[0][rl] + rsq[1][rl] + rsq[2][rl] + rsq[3][rl];
            float m = s * (1.f / 256.f);
            float var = q * (1.f / 256.f) - m * m;
            float rs = rsqrtf(var + 1e-5f);
            size_t row = (size_t)(m0 + rl);
            #pragma unroll
            for (int nt = 0; nt < 4; nt++) {
                int col = w * 64 + nt * 16 + l16;
                float y = (acc[mt][nt][r] - m) * rs * g[col] + bp[col];
                if (RES) {
                    float xn = Xin[row * 256 + col] + y;
                    Xout[row * 256 + col] = xn;
                    OutBf[row * 256 + col] = f2b(xn);
                } else {
                    OutBf[row * 256 + col] = f2b(y);
                }
            }
        }
    }
}

// ---------------------------------------------------------------------------
// Weight prep: fp32 [K][N] -> bf16 transposed [N][K]; q/k/v fused into [768][256].
// ---------------------------------------------------------------------------
__global__ __launch_bounds__(256) void wprep_kernel(
    const float* __restrict__ Wq, const float* __restrict__ Wk,
    const float* __restrict__ Wv, const float* __restrict__ Wm,
    const float* __restrict__ W1, const float* __restrict__ W2,
    ushort_t* __restrict__ Wqkvt, ushort_t* __restrict__ Wmt,
    ushort_t* __restrict__ W1t, ushort_t* __restrict__ W2t)
{
    int t = blockIdx.x;
    int layer = t / 640, r = t % 640;
    const float* src; ushort_t* dst;
    int ldsrc, lddst, tn, tk;
    if (r < 192) {
        int grp = r / 64, rr = r % 64; tn = rr / 8; tk = rr % 8;
        src = (grp == 0 ? Wq : grp == 1 ? Wk : Wv) + (size_t)layer * 65536;
        ldsrc = 256;
        dst = Wqkvt + (size_t)layer * 196608 + (size_t)grp * 65536;
        lddst = 256;
    } else if (r < 256) {
        int rr = r - 192; tn = rr / 8; tk = rr % 8;
        src = Wm + (size_t)layer * 65536; ldsrc = 256;
        dst = Wmt + (size_t)layer * 65536; lddst = 256;
    } else if (r < 512) {
        int rr = r - 256; tn = rr / 16; tk = rr % 16;
        src = W1 + (size_t)layer * 262144; ldsrc = 512;
        dst = W1t + (size_t)layer * 262144; lddst = 512;
    } else {
        int rr = r - 512; tn = rr / 16; tk = rr % 16;
        src = W2 + (size_t)layer * 131072; ldsrc = 256;
        dst = W2t + (size_t)layer * 131072; lddst = 512;
    }
    int n0 = tn * 32, k0 = tk * 32;
    __shared__ float tileS[32][33];
    int j = threadIdx.x & 31, i0 = threadIdx.x >> 5;
    #pragma unroll
    for (int p = 0; p < 4; p++) {
        int i = i0 + p * 8;
        tileS[i][j] = src[(size_t)(k0 + i) * ldsrc + n0 + j];
    }
    __syncthreads();
    #pragma unroll
    for (int p = 0; p < 4; p++) {
        int i = i0 + p * 8;
        dst[(size_t)(n0 + i) * lddst + k0 + j] = f2b(tileS[j][i]);
    }
}

// init: X fp32 master + Xbf bf16 mirror from feat0/feat1
__global__ __launch_bounds__(256) void init_kernel(
    const float* __restrict__ f0, const float* __restrict__ f1,
    float* __restrict__ X, ushort_t* __restrict__ Xbf)
{
    int idx = blockIdx.x * 256 + threadIdx.x;      // per float4; 1,048,576 total
    size_t e = (size_t)idx * 4;
    float4 v = (e < 2097152) ? *(const float4*)&f0[e] : *(const float4*)&f1[e - 2097152];
    *(float4*)&X[e] = v;
    ushort4_t u = { f2b(v.x), f2b(v.y), f2b(v.z), f2b(v.w) };
    *(ushort4_t*)&Xbf[e] = u;
}

// ---------------------------------------------------------------------------
// Self-attention KV[g,32,32] + Ksum[g,32] over S=4096, bf16 in (QKV fused, ld=768).
// ---------------------------------------------------------------------------
__global__ __launch_bounds__(256) void kv_reduce_kernel(
    const ushort_t* __restrict__ QKV,
    const int* __restrict__ mask0, const int* __restrict__ mask1,
    float* __restrict__ KV, float* __restrict__ Ksum)
{
    int g = blockIdx.y;
    int t = g >> 4, b = (g >> 3) & 1, h = g & 7;
    const int* mask = t ? mask1 : mask0;
    int rowbase = t * 8192 + b * 4096;
    int s_begin = blockIdx.x * 256;

    __shared__ float sK[32][32];
    __shared__ float sV[32][32];

    int tid = threadIdx.x;
    int e  = tid & 31;
    int dq = tid >> 5;              // 0..7 ; this thread owns d = dq*4..dq*4+3

    float acc[4] = {0.f, 0.f, 0.f, 0.f};
    float ks[4]  = {0.f, 0.f, 0.f, 0.f};

    for (int s0 = s_begin; s0 < s_begin + 256; s0 += 32) {
        #pragma unroll
        for (int q = 0; q < 2; q++) {
            int idx = tid + q * 256;
            int rl = idx >> 4;
            int part = idx & 15;
            int s = s0 + rl;
            size_t row = (size_t)(rowbase + s);
            float m = mask[b * 4096 + s] ? 1.f : 0.f;
            if (part < 8) {
                ushort4_t u = *(const ushort4_t*)&QKV[row * 768 + 256 + h * 32 + part * 4];
                float4 f = { elu1(b2f(u.x)) * m, elu1(b2f(u.y)) * m,
                             elu1(b2f(u.z)) * m, elu1(b2f(u.w)) * m };
                *(float4*)&sK[rl][part * 4] = f;
            } else {
                ushort4_t u = *(const ushort4_t*)&QKV[row * 768 + 512 + h * 32 + (part - 8) * 4];
                float4 f = { b2f(u.x) * m, b2f(u.y) * m, b2f(u.z) * m, b2f(u.w) * m };
                *(float4*)&sV[rl][(part - 8) * 4] = f;
            }
        }
        __syncthreads();

        #pragma unroll
        for (int s = 0; s < 32; s++) {
            float4 kq = *(const float4*)&sK[s][dq * 4];
            float vv = sV[s][e];
            acc[0] += kq.x * vv;
            acc[1] += kq.y * vv;
            acc[2] += kq.z * vv;
            acc[3] += kq.w * vv;
            ks[0] += kq.x; ks[1] += kq.y; ks[2] += kq.z; ks[3] += kq.w;
        }
        __syncthreads();
    }

    #pragma unroll
    for (int j = 0; j < 4; j++)
        atomicAdd(&KV[(size_t)g * 1024 + (dq * 4 + j) * 32 + e], acc[j]);
    if (e == 0) {
        #pragma unroll
        for (int j = 0; j < 4; j++)
            atomicAdd(&Ksum[g * 32 + dq * 4 + j], ks[j]);
    }
}

__global__ __launch_bounds__(256) void attn_apply_kernel(
    const ushort_t* __restrict__ QKV, const float* __restrict__ KV,
    const float* __restrict__ Ksum, ushort_t* __restrict__ MSG)
{
    int row = blockIdx.x;
    int t = row >> 13, bb = (row >> 12) & 1;
    int gb = (t * 2 + bb) * 8;
    int c = threadIdx.x, h = c >> 5, e = c & 31;
    int g = gb + h;

    __shared__ float sQ[256];
    float qf = elu1(b2f(QKV[(size_t)row * 768 + c]));
    sQ[c] = qf;
    __syncthreads();

    float p = qf * Ksum[g * 32 + e];
    #pragma unroll
    for (int off = 16; off; off >>= 1) p += __shfl_xor(p, off, 32);
    float Z = 1.f / (p + 1e-6f);

    float acc = 0.f;
    #pragma unroll
    for (int d = 0; d < 32; d++)
        acc += sQ[h * 32 + d] * KV[(size_t)g * 1024 + d * 32 + e];

    MSG[(size_t)row * 256 + c] = f2b(acc * Z);
}

// ---------------------------------------------------------------------------
// Gram table: for every bilinear anchor cell (65x65 per image, edges clamped)
// the 10 pairwise dot products of the 4 corner feature rows.
// ---------------------------------------------------------------------------
__global__ __launch_bounds__(256) void gram_kernel(
    const ushort_t* __restrict__ Xbf, float* __restrict__ Gm)
{
    int a = blockIdx.x * 4 + (threadIdx.x >> 6);
    int lane = threadIdx.x & 63;
    int img = a / 4225;
    int rr = a - img * 4225;
    int ay = rr / 65, ax = rr - ay * 65;
    int xa = ax > 0 ? ax - 1 : 0;
    int xb = ax < 64 ? ax : 63;
    if (ax == 0) xb = 0;
    int ya = ay > 0 ? ay - 1 : 0;
    int yb = ay < 64 ? ay : 63;
    if (ay == 0) yb = 0;

    size_t rbase = (size_t)img * 4096;
    size_t r0 = (rbase + ya * 64 + xa) * 256;
    size_t r1 = (rbase + ya * 64 + xb) * 256;
    size_t r2 = (rbase + yb * 64 + xa) * 256;
    size_t r3 = (rbase + yb * 64 + xb) * 256;

    int c4 = lane * 4;
    ushort4_t u0 = *(const ushort4_t*)&Xbf[r0 + c4];
    ushort4_t u1 = *(const ushort4_t*)&Xbf[r1 + c4];
    ushort4_t u2 = *(const ushort4_t*)&Xbf[r2 + c4];
    ushort4_t u3 = *(const ushort4_t*)&Xbf[r3 + c4];

    float p[10] = {0,0,0,0,0,0,0,0,0,0};
    #pragma unroll
    for (int j = 0; j < 4; j++) {
        float f0 = b2f(u0[j]), f1 = b2f(u1[j]), f2 = b2f(u2[j]), f3 = b2f(u3[j]);
        p[0] += f0 * f0; p[1] += f0 * f1; p[2] += f0 * f2; p[3] += f0 * f3;
        p[4] += f1 * f1; p[5] += f1 * f2; p[6] += f1 * f3;
        p[7] += f2 * f2; p[8] += f2 * f3; p[9] += f3 * f3;
    }
    #pragma unroll
    for (int k = 0; k < 10; k++)
        #pragma unroll
        for (int off = 32; off; off >>= 1) p[k] += __shfl_xor(p[k], off, 64);

    if (lane == 0) {
        #pragma unroll
        for (int k = 0; k < 10; k++) Gm[(size_t)a * 10 + k] = p[k];
    }
}

// ---------------------------------------------------------------------------
// Fused cross attention (S=9): ONE WAVE per query row, 8 ch/lane per half-wave
// (both halves cover all 256 ch). Samples interleaved across halves (5/4),
// combined at the end via shfl_xor(...,32). Mask-skip per sample.
// ---------------------------------------------------------------------------
__global__ __launch_bounds__(256) void cross_fused_kernel(
    const ushort_t* __restrict__ QKV, const float* __restrict__ Gm,
    const float* __restrict__ kp0, const float* __restrict__ kp1,
    const int* __restrict__ maskc0, const int* __restrict__ maskc1,
    ushort_t* __restrict__ MSG)
{
    int wv = threadIdx.x >> 6;
    int lane = threadIdx.x & 63;
    int half = lane >> 5;
    int l32 = lane & 31;
    int row = blockIdx.x * 4 + wv;

    int t = row >> 13;
    int bl = row & 8191;               // b*4096 + l
    int ts = 1 - t;                    // source image
    const float* kp = ts ? kp1 : kp0;
    const int* mask = (t == 0) ? maskc1 : maskc0;
    int img = ts * 2 + (bl >> 12);
    size_t rb = (size_t)img * 4096;    // source row base
    const float* Gimg = Gm + (size_t)img * 42250;

    int c8 = l32 * 8;                  // this lane's 8 channels

    ushort8_t qu = *(const ushort8_t*)&QKV[(size_t)row * 768 + c8];
    float qf[8];
    #pragma unroll
    for (int j = 0; j < 8; j++) qf[j] = elu1(b2f(qu[j]));

    float zsum = 0.f;
    float acc[8] = {0,0,0,0,0,0,0,0};

    for (int s9 = half; s9 < 9; s9 += 2) {
        int r = bl * 9 + s9;
        bool mk = mask[r] != 0;
        if (mk) {
            float xx = kp[(size_t)r * 2 + 0];
            float yy = kp[(size_t)r * 2 + 1];
            float px = (xx - 3.5f) * (63.f / 507.5f);
            float py = (yy - 3.5f) * (63.f / 507.5f);
            float fx = floorf(px), fy = floorf(py);
            float wx = px - fx, wy = py - fy;
            int ix = (int)fx, iy = (int)fy;            // -1..63
            int xa = ix > 0 ? ix : 0;
            int xb = ix + 1 > 0 ? (ix + 1 < 63 ? ix + 1 : 63) : 0;
            int ya = iy > 0 ? iy : 0;
            int yb = iy + 1 > 0 ? (iy + 1 < 63 ? iy + 1 : 63) : 0;

            float w0 = (1.f - wy) * (1.f - wx);
            float w1 = (1.f - wy) * wx;
            float w2 = wy * (1.f - wx);
            float w3 = wy * wx;

            const float* G = &Gimg[(size_t)((iy + 1) * 65 + (ix + 1)) * 10];
            float g00 = G[0], g01 = G[1], g02 = G[2], g03 = G[3], g11 = G[4];
            float g12 = G[5], g13 = G[6], g22 = G[7], g23 = G[8], g33 = G[9];
            float ss = w0 * w0 * g00 + w1 * w1 * g11 + w2 * w2 * g22 + w3 * w3 * g33
                     + 2.f * (w0 * w1 * g01 + w0 * w2 * g02 + w0 * w3 * g03
                            + w1 * w2 * g12 + w1 * w3 * g13 + w2 * w3 * g23);
            float inv = 1.f / (sqrtf(ss) + 1e-8f);
            float u0 = w0 * inv, u1 = w1 * inv, u2 = w2 * inv, u3 = w3 * inv;

            size_t s00 = (rb + ya * 64 + xa) * 768;
            size_t s01 = (rb + ya * 64 + xb) * 768;
            size_t s10 = (rb + yb * 64 + xa) * 768;
            size_t s11 = (rb + yb * 64 + xb) * 768;

            ushort8_t k00 = *(const ushort8_t*)&QKV[s00 + 256 + c8];
            ushort8_t k01 = *(const ushort8_t*)&QKV[s01 + 256 + c8];
            ushort8_t k10 = *(const ushort8_t*)&QKV[s10 + 256 + c8];
            ushort8_t k11 = *(const ushort8_t*)&QKV[s11 + 256 + c8];
            ushort8_t v00 = *(const ushort8_t*)&QKV[s00 + 512 + c8];
            ushort8_t v01 = *(const ushort8_t*)&QKV[s01 + 512 + c8];
            ushort8_t v10 = *(const ushort8_t*)&QKV[s10 + 512 + c8];
            ushort8_t v11 = *(const ushort8_t*)&QKV[s11 + 512 + c8];

            float vc[8];
            float p = 0.f;
            #pragma unroll
            for (int j = 0; j < 8; j++) {
                float kc = u0 * b2f(k00[j]) + u1 * b2f(k01[j])
                         + u2 * b2f(k10[j]) + u3 * b2f(k11[j]);
                vc[j] = u0 * b2f(v00[j]) + u1 * b2f(v01[j])
                      + u2 * b2f(v10[j]) + u3 * b2f(v11[j]);
                p += qf[j] * elu1(kc);
            }
            // head = 32 ch = 4 lanes (group aligned): reduce over 4 lanes
            p += __shfl_xor(p, 1, 64);
            p += __shfl_xor(p, 2, 64);

            zsum += p;
            #pragma unroll
            for (int j = 0; j < 8; j++) acc[j] += p * vc[j];
        }
    }

    // combine the two halves (same channels, disjoint samples)
    zsum += __shfl_xor(zsum, 32, 64);
    #pragma unroll
    for (int j = 0; j < 8; j++) acc[j] += __shfl_xor(acc[j], 32, 64);

    if (half == 0) {
        float Z = 1.f / (zsum + 1e-6f);
        ushort8_t o;
        #pragma unroll
        for (int j = 0; j < 8; j++) o[j] = f2b(acc[j] * Z);
        *(ushort8_t*)&MSG[(size_t)row * 256 + c8] = o;
    }
}

// ---------------------------------------------------------------------------

extern "C" void kernel_launch(void* const* d_in, const int* in_sizes, int n_in,
                              void* d_out, int out_size, void* d_ws, size_t ws_size,
                              hipStream_t stream)
{
    const float* feat0 = (const float*)d_in[0];
    const float* feat1 = (const float*)d_in[1];
    const float* kp0 = (const float*)d_in[2];
    const float* kp1 = (const float*)d_in[3];
    const int* ms0 = (const int*)d_in[4];
    const int* ms1 = (const int*)d_in[5];
    const int* mc0 = (const int*)d_in[6];
    const int* mc1 = (const int*)d_in[7];
    const float* Wq = (const float*)d_in[8];
    const float* Wk = (const float*)d_in[9];
    const float* Wv = (const float*)d_in[10];
    const float* Wm = (const float*)d_in[11];
    const float* W1 = (const float*)d_in[12];
    const float* W2 = (const float*)d_in[13];
    const float* g1 = (const float*)d_in[14];
    const float* b1 = (const float*)d_in[15];
    const float* g2 = (const float*)d_in[16];
    const float* b2 = (const float*)d_in[17];

    // workspace carve (bytes; all offsets 256B-aligned). ~70 MB total.
    char* p = (char*)d_ws;
    float*    X     = (float*)p;            p += 16777216;   // 16384x256 fp32
    ushort_t* Xbf   = (ushort_t*)p;         p += 8388608;    // bf16 mirror
    ushort_t* QKV   = (ushort_t*)p;         p += 25165824;   // 16384x768 bf16
    ushort_t* MSG   = (ushort_t*)p;         p += 8388608;    // 16384x256 bf16
    ushort_t* T     = (ushort_t*)p;         p += 16777216;   // 16384x512 bf16
    ushort_t* L1bf  = (ushort_t*)p;         p += 8388608;    // 16384x256 bf16
    float*    KVb   = (float*)p;            p += 131072;     // 32x1024
    float*    KSb   = (float*)p;            p += 4096;       // 32x32
    float*    Gm    = (float*)p;            p += 679936;     // 4x65x65x10 fp32 Gram
    ushort_t* Wqkvt = (ushort_t*)p;         p += 1572864;    // 4x768x256 bf16
    ushort_t* Wmt   = (ushort_t*)p;         p += 524288;     // 4x256x256
    ushort_t* W1t   = (ushort_t*)p;         p += 2097152;    // 4x512x512
    ushort_t* W2t   = (ushort_t*)p;         p += 1048576;    // 4x256x512

    init_kernel<<<4096, 256, 0, stream>>>(feat0, feat1, X, Xbf);
    wprep_kernel<<<2560, 256, 0, stream>>>(Wq, Wk, Wv, Wm, W1, W2, Wqkvt, Wmt, W1t, W2t);

    auto gemm = [&](const ushort_t* A0, const ushort_t* A1, int ksplit, int lda0, int lda1,
                    const ushort_t* Wtp, int ldw, ushort_t* Cp, int ldc, int N, int Kd, int act) {
        dim3 grid(N / 128, NROWS / 128);
        if (act)
            gemm_bf16_kernel<1><<<grid, 256, 0, stream>>>(A0, A1, ksplit, lda0, lda1, Wtp, ldw, Cp, ldc, Kd);
        else
            gemm_bf16_kernel<0><<<grid, 256, 0, stream>>>(A0, A1, ksplit, lda0, lda1, Wtp, ldw, Cp, ldc, Kd);
    };

    for (int i = 0; i < 4; i++) {
        const ushort_t* Wqkvt_l = Wqkvt + (size_t)i * 196608;
        const ushort_t* Wmt_l   = Wmt   + (size_t)i * 65536;
        const ushort_t* W1t_l   = W1t   + (size_t)i * 262144;
        const ushort_t* W2t_l   = W2t   + (size_t)i * 131072;
        const float* g1_l = g1 + (size_t)i * 256;
        const float* b1_l = b1 + (size_t)i * 256;
        const float* g2_l = g2 + (size_t)i * 256;
        const float* b2_l = b2 + (size_t)i * 256;
        bool is_self = (i == 0 || i == 2);

        gemm(Xbf, nullptr, 1 << 30, 256, 0, Wqkvt_l, 256, QKV, 768, 768, 256, 0);

        if (is_self) {
            hipMemsetAsync(KVb, 0, 33792 * 4, stream);
            kv_reduce_kernel<<<dim3(16, 32), 256, 0, stream>>>(QKV, ms0, ms1, KVb, KSb);
            attn_apply_kernel<<<NROWS, 256, 0, stream>>>(QKV, KVb, KSb, MSG);
        } else {
            gram_kernel<<<4225, 256, 0, stream>>>(Xbf, Gm);
            cross_fused_kernel<<<NROWS / 4, 256, 0, stream>>>(QKV, Gm, kp0, kp1, mc0, mc1, MSG);
        }

        // M1 = MSG @ Wm ; L1 = ln1(M1)  (fused)
        gemm_ln_kernel<0><<<NROWS / 32, 256, 0, stream>>>(
            MSG, 256, Wmt_l, 256, 256, g1_l, b1_l, L1bf, nullptr, nullptr);
        // T = tanh(cat(Xbf, L1) @ W1)
        gemm(Xbf, L1bf, 256, 256, 256, W1t_l, 512, T, 512, 512, 512, 1);
        // M2 = T @ W2 ; X += ln2(M2) ; Xbf = bf16(X)   (fused; last layer -> d_out)
        float* Xout = (i == 3) ? (float*)d_out : X;
        gemm_ln_kernel<1><<<NROWS / 32, 256, 0, stream>>>(
            T, 512, W2t_l, 512, 512, g2_l, b2_l, Xbf, X, Xout);
    }
}

// Round 8
// 613.357 us; speedup vs baseline: 3.8796x; 1.0412x over previous
//
#include <hip/hip_runtime.h>
#include <cstddef>

// Shapes (hard-coded): B=2, L=4096 (64x64), C=256, H=8, D=32, K=9, scale=8,
// layers: self,cross,self,cross. X rows: 0..8191 feat0 (b0,b1), 8192..16383 feat1.

#define NROWS 16384

typedef unsigned short ushort_t;
typedef __attribute__((ext_vector_type(8))) short short8;
typedef __attribute__((ext_vector_type(4))) float f32x4;
typedef __attribute__((ext_vector_type(4))) unsigned short ushort4_t;
typedef __attribute__((ext_vector_type(8))) unsigned short ushort8_t;

__device__ __forceinline__ float b2f(unsigned short u) {
    union { unsigned int i; float f; } v; v.i = (unsigned int)u << 16; return v.f;
}
__device__ __forceinline__ unsigned short f2b(float x) {
    union { float f; unsigned int i; } v; v.f = x;
    unsigned int r = v.i + 0x7fffu + ((v.i >> 16) & 1u);   // RNE
    return (unsigned short)(r >> 16);
}
// elu(x)+1: for x<=0, elu = exp(x)-1, so elu+1 = exp(x) exactly.
__device__ __forceinline__ float elu1(float x) {
    return x > 0.f ? x + 1.f : __expf(x);
}

#define ASYNC_COPY16(gptr, lptr) \
    __builtin_amdgcn_global_load_lds((const __attribute__((address_space(1))) void*)(gptr), \
                                     (__attribute__((address_space(3))) void*)(lptr), 16, 0, 0)

// ---------------------------------------------------------------------------
// bf16 MFMA GEMM: C[M,N] = A[M,K] @ W[K,N], W pre-transposed as Wt[N][K].
// 128x128 tile, BK=64 (two 32-col LDS panels). Used for the QKV projection.
// ---------------------------------------------------------------------------
__global__ __launch_bounds__(256) void gemm_bf16_kernel(
    const ushort_t* __restrict__ A0, int lda0,
    const ushort_t* __restrict__ Wt, int ldw,
    ushort_t* __restrict__ C, int ldc, int Kd)
{
    __shared__ ushort_t As[128 * 64];   // 16 KB
    __shared__ ushort_t Bs[128 * 64];   // 16 KB

    int tid = threadIdx.x;
    int m0 = blockIdx.y * 128;
    int n0 = blockIdx.x * 128;
    int lane = tid & 63, w = tid >> 6;
    int wrow = w >> 1, wcol = w & 1;
    int quad = lane >> 4, l16 = lane & 15;

    f32x4 acc[4][4];
    #pragma unroll
    for (int i = 0; i < 4; i++)
        #pragma unroll
        for (int j = 0; j < 4; j++) acc[i][j] = (f32x4){0.f, 0.f, 0.f, 0.f};

    for (int kb = 0; kb < Kd; kb += 64) {
        #pragma unroll
        for (int q = 0; q < 4; q++) {
            int s = q * 256 + tid;
            int kk = s >> 9, p = s & 511;
            int row = p >> 2, c4 = p & 3;
            ASYNC_COPY16(A0 + (size_t)(m0 + row) * lda0 + kb + kk * 32 + c4 * 8,
                         (char*)As + s * 16);
        }
        #pragma unroll
        for (int q = 0; q < 4; q++) {
            int s = q * 256 + tid;
            int kk = s >> 9, p = s & 511;
            int row = p >> 2, c4 = p & 3;
            ASYNC_COPY16(Wt + (size_t)(n0 + row) * ldw + kb + kk * 32 + c4 * 8,
                         (char*)Bs + s * 16);
        }
        __syncthreads();

        #pragma unroll
        for (int kk = 0; kk < 2; kk++) {
            short8 af[4], bf[4];
            #pragma unroll
            for (int mt = 0; mt < 4; mt++)
                af[mt] = *(const short8*)&As[kk * 4096 + (wrow * 64 + mt * 16 + l16) * 32 + quad * 8];
            #pragma unroll
            for (int nt = 0; nt < 4; nt++)
                bf[nt] = *(const short8*)&Bs[kk * 4096 + (wcol * 64 + nt * 16 + l16) * 32 + quad * 8];
            #pragma unroll
            for (int mt = 0; mt < 4; mt++)
                #pragma unroll
                for (int nt = 0; nt < 4; nt++)
                    acc[mt][nt] = __builtin_amdgcn_mfma_f32_16x16x32_bf16(
                        af[mt], bf[nt], acc[mt][nt], 0, 0, 0);
        }
        __syncthreads();
    }

    #pragma unroll
    for (int mt = 0; mt < 4; mt++) {
        int row = m0 + wrow * 64 + mt * 16 + quad * 4;
        #pragma unroll
        for (int nt = 0; nt < 4; nt++) {
            int col = n0 + wcol * 64 + nt * 16 + l16;
            #pragma unroll
            for (int r = 0; r < 4; r++)
                C[(size_t)(row + r) * ldc + col] = f2b(acc[mt][nt][r]);
        }
    }
}

// ---------------------------------------------------------------------------
// GEMM + fused LayerNorm (the Wm -> ln1 path). 32 rows x 256 cols per block,
// BK=64 two-panel LDS layout. OutBf = bf16(LN(A@Wt)).
// ---------------------------------------------------------------------------
__global__ __launch_bounds__(256) void gemm_ln_kernel(
    const ushort_t* __restrict__ A, int lda,
    const ushort_t* __restrict__ Wt, int ldw, int Kd,
    const float* __restrict__ g, const float* __restrict__ bp,
    ushort_t* __restrict__ OutBf)
{
    __shared__ ushort_t As[32 * 64];    // 4 KB, panels of 32x32
    __shared__ ushort_t Bs[256 * 64];   // 32 KB, panels of 256x32
    __shared__ float rsum[4][32];
    __shared__ float rsq[4][32];

    int tid = threadIdx.x;
    int m0 = blockIdx.x * 32;
    int lane = tid & 63, w = tid >> 6;
    int quad = lane >> 4, l16 = lane & 15;

    f32x4 acc[2][4];
    #pragma unroll
    for (int i = 0; i < 2; i++)
        #pragma unroll
        for (int j = 0; j < 4; j++) acc[i][j] = (f32x4){0.f, 0.f, 0.f, 0.f};

    for (int kb = 0; kb < Kd; kb += 64) {
        {
            int s = tid;
            int kk = s >> 7, p = s & 127;
            int row = p >> 2, c4 = p & 3;
            ASYNC_COPY16(A + (size_t)(m0 + row) * lda + kb + kk * 32 + c4 * 8,
                         (char*)As + s * 16);
        }
        #pragma unroll
        for (int q = 0; q < 8; q++) {
            int s = q * 256 + tid;
            int kk = s >> 10, p = s & 1023;
            int row = p >> 2, c4 = p & 3;
            ASYNC_COPY16(Wt + (size_t)(row) * ldw + kb + kk * 32 + c4 * 8,
                         (char*)Bs + s * 16);
        }
        __syncthreads();

        #pragma unroll
        for (int kk = 0; kk < 2; kk++) {
            short8 af[2], bf[4];
            #pragma unroll
            for (int mt = 0; mt < 2; mt++)
                af[mt] = *(const short8*)&As[kk * 1024 + (mt * 16 + l16) * 32 + quad * 8];
            #pragma unroll
            for (int nt = 0; nt < 4; nt++)
                bf[nt] = *(const short8*)&Bs[kk * 8192 + (w * 64 + nt * 16 + l16) * 32 + quad * 8];
            #pragma unroll
            for (int mt = 0; mt < 2; mt++)
                #pragma unroll
                for (int nt = 0; nt < 4; nt++)
                    acc[mt][nt] = __builtin_amdgcn_mfma_f32_16x16x32_bf16(
                        af[mt], bf[nt], acc[mt][nt], 0, 0, 0);
        }
        __syncthreads();
    }

    #pragma unroll
    for (int mt = 0; mt < 2; mt++)
        #pragma unroll
        for (int r = 0; r < 4; r++) {
            float s = 0.f, q = 0.f;
            #pragma unroll
            for (int nt = 0; nt < 4; nt++) {
                float v = acc[mt][nt][r];
                s += v; q += v * v;
            }
            #pragma unroll
            for (int off = 1; off < 16; off <<= 1) {
                s += __shfl_xor(s, off, 64);
                q += __shfl_xor(q, off, 64);
            }
            if (l16 == 0) {
                rsum[w][mt * 16 + quad * 4 + r] = s;
                rsq[w][mt * 16 + quad * 4 + r]  = q;
            }
        }
    __syncthreads();

    #pragma unroll
    for (int mt = 0; mt < 2; mt++) {
        #pragma unroll
        for (int r = 0; r < 4; r++) {
            int rl = mt * 16 + quad * 4 + r;
            float s = rsum[0][rl] + rsum[1][rl] + rsum[2][rl] + rsum[3][rl];
            float q = rsq[0][rl] + rsq[1][rl] + rsq[2][rl] + rsq[3][rl];
            float m = s * (1.f / 256.f);
            float var = q * (1.f / 256.f) - m * m;
            float rs = rsqrtf(var + 1e-5f);
            size_t row = (size_t)(m0 + rl);
            #pragma unroll
            for (int nt = 0; nt < 4; nt++) {
                int col = w * 64 + nt * 16 + l16;
                float y = (acc[mt][nt][r] - m) * rs * g[col] + bp[col];
                OutBf[row * 256 + col] = f2b(y);
            }
        }
    }
}

// ---------------------------------------------------------------------------
// Fused MLP tail: per 32-row block,
//   stage1: T = tanh([Xb|L1] @ W1t)   (32x512, kept in XOR-swizzled LDS)
//   stage2: M2 = T @ W2t ; xn = Xin + LN(M2); Xout = xn; XbfOut = bf16(xn)
// Eliminates the T round-trip and one dispatch per layer.
// LDS: Tt 32 KB + staging buf 20 KB (As 4K + Bs 16K, reused by stage2/epilogue).
// ---------------------------------------------------------------------------
__global__ __launch_bounds__(256) void mlp_fused_kernel(
    const ushort_t* __restrict__ Xb, const ushort_t* __restrict__ L1,
    const ushort_t* __restrict__ W1t, const ushort_t* __restrict__ W2t,
    const float* __restrict__ g, const float* __restrict__ bp,
    ushort_t* __restrict__ XbfOut, const float* __restrict__ Xin,
    float* __restrict__ Xout)
{
    __shared__ ushort_t Tt[32 * 512];   // 32 KB, XOR-swizzled by (col>>3)^(row&7)
    __shared__ char buf[20480];         // stage1: As 4K + Bs 16K ; stage2: Bs2 16K ; epi: stats

    ushort_t* As  = (ushort_t*)buf;
    ushort_t* Bs  = (ushort_t*)(buf + 4096);
    ushort_t* Bs2 = (ushort_t*)buf;
    float* rsum = (float*)buf;          // [4][32] (dead staging region by epilogue)
    float* rsq  = (float*)(buf + 512);

    int tid = threadIdx.x;
    int m0 = blockIdx.x * 32;
    int lane = tid & 63, w = tid >> 6;
    int quad = lane >> 4, l16 = lane & 15;

    // ---------- stage 1: 4 N-passes of 128 cols ----------
    for (int np = 0; np < 4; np++) {
        f32x4 acc[2][2];
        #pragma unroll
        for (int i = 0; i < 2; i++)
            #pragma unroll
            for (int j = 0; j < 2; j++) acc[i][j] = (f32x4){0.f, 0.f, 0.f, 0.f};

        for (int kb = 0; kb < 512; kb += 64) {
            const ushort_t* Ab = (kb < 256) ? Xb : L1;
            int kc = (kb < 256) ? kb : kb - 256;
            {
                int s = tid;
                int kk = s >> 7, p = s & 127;
                ASYNC_COPY16(Ab + (size_t)(m0 + (p >> 2)) * 256 + kc + kk * 32 + (p & 3) * 8,
                             (char*)As + s * 16);
            }
            #pragma unroll
            for (int q = 0; q < 4; q++) {
                int s = q * 256 + tid;
                int kk = s >> 9, p = s & 511;
                ASYNC_COPY16(W1t + (size_t)(np * 128 + (p >> 2)) * 512 + kb + kk * 32 + (p & 3) * 8,
                             (char*)Bs + s * 16);
            }
            __syncthreads();

            #pragma unroll
            for (int kk = 0; kk < 2; kk++) {
                short8 af[2], bfr[2];
                #pragma unroll
                for (int mt = 0; mt < 2; mt++)
                    af[mt] = *(const short8*)&As[kk * 1024 + (mt * 16 + l16) * 32 + quad * 8];
                #pragma unroll
                for (int nt = 0; nt < 2; nt++)
                    bfr[nt] = *(const short8*)&Bs[kk * 4096 + (w * 32 + nt * 16 + l16) * 32 + quad * 8];
                #pragma unroll
                for (int mt = 0; mt < 2; mt++)
                    #pragma unroll
                    for (int nt = 0; nt < 2; nt++)
                        acc[mt][nt] = __builtin_amdgcn_mfma_f32_16x16x32_bf16(
                            af[mt], bfr[nt], acc[mt][nt], 0, 0, 0);
            }
            __syncthreads();
        }

        // write tanh(acc) into Tt (swizzled)
        #pragma unroll
        for (int mt = 0; mt < 2; mt++)
            #pragma unroll
            for (int nt = 0; nt < 2; nt++)
                #pragma unroll
                for (int r = 0; r < 4; r++) {
                    int trow = mt * 16 + quad * 4 + r;
                    int col = np * 128 + w * 32 + nt * 16 + l16;
                    int c8s = (col >> 3) ^ (trow & 7);
                    Tt[trow * 512 + c8s * 8 + (col & 7)] = f2b(tanhf(acc[mt][nt][r]));
                }
    }
    // Tt completeness is guaranteed by the first __syncthreads in stage 2.

    // ---------- stage 2: 2 N-passes of 128 cols, acc kept across passes ----------
    f32x4 acc2[2][2][2];
    #pragma unroll
    for (int a = 0; a < 2; a++)
        #pragma unroll
        for (int i = 0; i < 2; i++)
            #pragma unroll
            for (int j = 0; j < 2; j++) acc2[a][i][j] = (f32x4){0.f, 0.f, 0.f, 0.f};

    for (int pass = 0; pass < 2; pass++) {
        for (int kb = 0; kb < 512; kb += 64) {
            #pragma unroll
            for (int q = 0; q < 4; q++) {
                int s = q * 256 + tid;
                int kk = s >> 9, p = s & 511;
                ASYNC_COPY16(W2t + (size_t)(pass * 128 + (p >> 2)) * 512 + kb + kk * 32 + (p & 3) * 8,
                             (char*)Bs2 + s * 16);
            }
            __syncthreads();

            #pragma unroll
            for (int kk = 0; kk < 2; kk++) {
                short8 af[2], bfr[2];
                #pragma unroll
                for (int mt = 0; mt < 2; mt++) {
                    int row = mt * 16 + l16;
                    int blk = ((kb >> 3) + kk * 4 + quad) ^ (row & 7);
                    af[mt] = *(const short8*)&Tt[row * 512 + blk * 8];
                }
                #pragma unroll
                for (int nt = 0; nt < 2; nt++)
                    bfr[nt] = *(const short8*)&Bs2[kk * 4096 + (w * 32 + nt * 16 + l16) * 32 + quad * 8];
                #pragma unroll
                for (int mt = 0; mt < 2; mt++)
                    #pragma unroll
                    for (int nt = 0; nt < 2; nt++)
                        acc2[pass][mt][nt] = __builtin_amdgcn_mfma_f32_16x16x32_bf16(
                            af[mt], bfr[nt], acc2[pass][mt][nt], 0, 0, 0);
            }
            __syncthreads();
        }
    }

    // ---------- epilogue: LN + residual ----------
    #pragma unroll
    for (int mt = 0; mt < 2; mt++)
        #pragma unroll
        for (int r = 0; r < 4; r++) {
            float s = 0.f, q = 0.f;
            #pragma unroll
            for (int pass = 0; pass < 2; pass++)
                #pragma unroll
                for (int nt = 0; nt < 2; nt++) {
                    float v = acc2[pass][mt][nt][r];
                    s += v; q += v * v;
                }
            #pragma unroll
            for (int off = 1; off < 16; off <<= 1) {
                s += __shfl_xor(s, off, 64);
                q += __shfl_xor(q, off, 64);
            }
            if (l16 == 0) {
                rsum[w * 32 + mt * 16 + quad * 4 + r] = s;
                rsq[w * 32 + mt * 16 + quad * 4 + r]  = q;
            }
        }
    __syncthreads();

    #pragma unroll
    for (int mt = 0; mt < 2; mt++) {
        #pragma unroll
        for (int r = 0; r < 4; r++) {
            int rl = mt * 16 + quad * 4 + r;
            float s = rsum[rl] + rsum[32 + rl] + rsum[64 + rl] + rsum[96 + rl];
            float q = rsq[rl] + rsq[32 + rl] + rsq[64 + rl] + rsq[96 + rl];
            float m = s * (1.f / 256.f);
            float var = q * (1.f / 256.f) - m * m;
            float rs = rsqrtf(var + 1e-5f);
            size_t row = (size_t)(m0 + rl);
            #pragma unroll
            for (int pass = 0; pass < 2; pass++)
                #pragma unroll
                for (int nt = 0; nt < 2; nt++) {
                    int col = pass * 128 + w * 32 + nt * 16 + l16;
                    float y = (acc2[pass][mt][nt][r] - m) * rs * g[col] + bp[col];
                    float xn = Xin[row * 256 + col] + y;
                    Xout[row * 256 + col] = xn;
                    XbfOut[row * 256 + col] = f2b(xn);
                }
        }
    }
}

// ---------------------------------------------------------------------------
// Weight prep: fp32 [K][N] -> bf16 transposed [N][K]; q/k/v fused into [768][256].
// ---------------------------------------------------------------------------
__global__ __launch_bounds__(256) void wprep_kernel(
    const float* __restrict__ Wq, const float* __restrict__ Wk,
    const float* __restrict__ Wv, const float* __restrict__ Wm,
    const float* __restrict__ W1, const float* __restrict__ W2,
    ushort_t* __restrict__ Wqkvt, ushort_t* __restrict__ Wmt,
    ushort_t* __restrict__ W1t, ushort_t* __restrict__ W2t)
{
    int t = blockIdx.x;
    int layer = t / 640, r = t % 640;
    const float* src; ushort_t* dst;
    int ldsrc, lddst, tn, tk;
    if (r < 192) {
        int grp = r / 64, rr = r % 64; tn = rr / 8; tk = rr % 8;
        src = (grp == 0 ? Wq : grp == 1 ? Wk : Wv) + (size_t)layer * 65536;
        ldsrc = 256;
        dst = Wqkvt + (size_t)layer * 196608 + (size_t)grp * 65536;
        lddst = 256;
    } else if (r < 256) {
        int rr = r - 192; tn = rr / 8; tk = rr % 8;
        src = Wm + (size_t)layer * 65536; ldsrc = 256;
        dst = Wmt + (size_t)layer * 65536; lddst = 256;
    } else if (r < 512) {
        int rr = r - 256; tn = rr / 16; tk = rr % 16;
        src = W1 + (size_t)layer * 262144; ldsrc = 512;
        dst = W1t + (size_t)layer * 262144; lddst = 512;
    } else {
        int rr = r - 512; tn = rr / 16; tk = rr % 16;
        src = W2 + (size_t)layer * 131072; ldsrc = 256;
        dst = W2t + (size_t)layer * 131072; lddst = 512;
    }
    int n0 = tn * 32, k0 = tk * 32;
    __shared__ float tileS[32][33];
    int j = threadIdx.x & 31, i0 = threadIdx.x >> 5;
    #pragma unroll
    for (int p = 0; p < 4; p++) {
        int i = i0 + p * 8;
        tileS[i][j] = src[(size_t)(k0 + i) * ldsrc + n0 + j];
    }
    __syncthreads();
    #pragma unroll
    for (int p = 0; p < 4; p++) {
        int i = i0 + p * 8;
        dst[(size_t)(n0 + i) * lddst + k0 + j] = f2b(tileS[j][i]);
    }
}

// init: X fp32 master + Xbf bf16 mirror from feat0/feat1
__global__ __launch_bounds__(256) void init_kernel(
    const float* __restrict__ f0, const float* __restrict__ f1,
    float* __restrict__ X, ushort_t* __restrict__ Xbf)
{
    int idx = blockIdx.x * 256 + threadIdx.x;      // per float4; 1,048,576 total
    size_t e = (size_t)idx * 4;
    float4 v = (e < 2097152) ? *(const float4*)&f0[e] : *(const float4*)&f1[e - 2097152];
    *(float4*)&X[e] = v;
    ushort4_t u = { f2b(v.x), f2b(v.y), f2b(v.z), f2b(v.w) };
    *(ushort4_t*)&Xbf[e] = u;
}

// ---------------------------------------------------------------------------
// Self-attention KV[g,32,32] + Ksum[g,32] over S=4096, bf16 in (QKV fused, ld=768).
// ---------------------------------------------------------------------------
__global__ __launch_bounds__(256) void kv_reduce_kernel(
    const ushort_t* __restrict__ QKV,
    const int* __restrict__ mask0, const int* __restrict__ mask1,
    float* __restrict__ KV, float* __restrict__ Ksum)
{
    int g = blockIdx.y;
    int t = g >> 4, b = (g >> 3) & 1, h = g & 7;
    const int* mask = t ? mask1 : mask0;
    int rowbase = t * 8192 + b * 4096;
    int s_begin = blockIdx.x * 256;

    __shared__ float sK[32][32];
    __shared__ float sV[32][32];

    int tid = threadIdx.x;
    int e  = tid & 31;
    int dq = tid >> 5;              // 0..7 ; this thread owns d = dq*4..dq*4+3

    float acc[4] = {0.f, 0.f, 0.f, 0.f};
    float ks[4]  = {0.f, 0.f, 0.f, 0.f};

    for (int s0 = s_begin; s0 < s_begin + 256; s0 += 32) {
        #pragma unroll
        for (int q = 0; q < 2; q++) {
            int idx = tid + q * 256;
            int rl = idx >> 4;
            int part = idx & 15;
            int s = s0 + rl;
            size_t row = (size_t)(rowbase + s);
            float m = mask[b * 4096 + s] ? 1.f : 0.f;
            if (part < 8) {
                ushort4_t u = *(const ushort4_t*)&QKV[row * 768 + 256 + h * 32 + part * 4];
                float4 f = { elu1(b2f(u.x)) * m, elu1(b2f(u.y)) * m,
                             elu1(b2f(u.z)) * m, elu1(b2f(u.w)) * m };
                *(float4*)&sK[rl][part * 4] = f;
            } else {
                ushort4_t u = *(const ushort4_t*)&QKV[row * 768 + 512 + h * 32 + (part - 8) * 4];
                float4 f = { b2f(u.x) * m, b2f(u.y) * m, b2f(u.z) * m, b2f(u.w) * m };
                *(float4*)&sV[rl][(part - 8) * 4] = f;
            }
        }
        __syncthreads();

        #pragma unroll
        for (int s = 0; s < 32; s++) {
            float4 kq = *(const float4*)&sK[s][dq * 4];
            float vv = sV[s][e];
            acc[0] += kq.x * vv;
            acc[1] += kq.y * vv;
            acc[2] += kq.z * vv;
            acc[3] += kq.w * vv;
            ks[0] += kq.x; ks[1] += kq.y; ks[2] += kq.z; ks[3] += kq.w;
        }
        __syncthreads();
    }

    #pragma unroll
    for (int j = 0; j < 4; j++)
        atomicAdd(&KV[(size_t)g * 1024 + (dq * 4 + j) * 32 + e], acc[j]);
    if (e == 0) {
        #pragma unroll
        for (int j = 0; j < 4; j++)
            atomicAdd(&Ksum[g * 32 + dq * 4 + j], ks[j]);
    }
}

__global__ __launch_bounds__(256) void attn_apply_kernel(
    const ushort_t* __restrict__ QKV, const float* __restrict__ KV,
    const float* __restrict__ Ksum, ushort_t* __restrict__ MSG)
{
    int row = blockIdx.x;
    int t = row >> 13, bb = (row >> 12) & 1;
    int gb = (t * 2 + bb) * 8;
    int c = threadIdx.x, h = c >> 5, e = c & 31;
    int g = gb + h;

    __shared__ float sQ[256];
    float qf = elu1(b2f(QKV[(size_t)row * 768 + c]));
    sQ[c] = qf;
    __syncthreads();

    float p = qf * Ksum[g * 32 + e];
    #pragma unroll
    for (int off = 16; off; off >>= 1) p += __shfl_xor(p, off, 32);
    float Z = 1.f / (p + 1e-6f);

    float acc = 0.f;
    #pragma unroll
    for (int d = 0; d < 32; d++)
        acc += sQ[h * 32 + d] * KV[(size_t)g * 1024 + d * 32 + e];

    MSG[(size_t)row * 256 + c] = f2b(acc * Z);
}

// ---------------------------------------------------------------------------
// Gram table: for every bilinear anchor cell (65x65 per image, edges clamped)
// the 10 pairwise dot products of the 4 corner feature rows.
// ---------------------------------------------------------------------------
__global__ __launch_bounds__(256) void gram_kernel(
    const ushort_t* __restrict__ Xbf, float* __restrict__ Gm)
{
    int a = blockIdx.x * 4 + (threadIdx.x >> 6);
    int lane = threadIdx.x & 63;
    int img = a / 4225;
    int rr = a - img * 4225;
    int ay = rr / 65, ax = rr - ay * 65;
    int xa = ax > 0 ? ax - 1 : 0;
    int xb = ax < 64 ? ax : 63;
    if (ax == 0) xb = 0;
    int ya = ay > 0 ? ay - 1 : 0;
    int yb = ay < 64 ? ay : 63;
    if (ay == 0) yb = 0;

    size_t rbase = (size_t)img * 4096;
    size_t r0 = (rbase + ya * 64 + xa) * 256;
    size_t r1 = (rbase + ya * 64 + xb) * 256;
    size_t r2 = (rbase + yb * 64 + xa) * 256;
    size_t r3 = (rbase + yb * 64 + xb) * 256;

    int c4 = lane * 4;
    ushort4_t u0 = *(const ushort4_t*)&Xbf[r0 + c4];
    ushort4_t u1 = *(const ushort4_t*)&Xbf[r1 + c4];
    ushort4_t u2 = *(const ushort4_t*)&Xbf[r2 + c4];
    ushort4_t u3 = *(const ushort4_t*)&Xbf[r3 + c4];

    float p[10] = {0,0,0,0,0,0,0,0,0,0};
    #pragma unroll
    for (int j = 0; j < 4; j++) {
        float f0 = b2f(u0[j]), f1 = b2f(u1[j]), f2 = b2f(u2[j]), f3 = b2f(u3[j]);
        p[0] += f0 * f0; p[1] += f0 * f1; p[2] += f0 * f2; p[3] += f0 * f3;
        p[4] += f1 * f1; p[5] += f1 * f2; p[6] += f1 * f3;
        p[7] += f2 * f2; p[8] += f2 * f3; p[9] += f3 * f3;
    }
    #pragma unroll
    for (int k = 0; k < 10; k++)
        #pragma unroll
        for (int off = 32; off; off >>= 1) p[k] += __shfl_xor(p[k], off, 64);

    if (lane == 0) {
        #pragma unroll
        for (int k = 0; k < 10; k++) Gm[(size_t)a * 10 + k] = p[k];
    }
}

// ---------------------------------------------------------------------------
// Fused cross attention (S=9): ONE WAVE per query row, 8 ch/lane per half-wave
// (both halves cover all 256 ch). Samples interleaved across halves (5/4),
// combined at the end via shfl_xor(...,32). Mask-skip per sample.
// ---------------------------------------------------------------------------
__global__ __launch_bounds__(256) void cross_fused_kernel(
    const ushort_t* __restrict__ QKV, const float* __restrict__ Gm,
    const float* __restrict__ kp0, const float* __restrict__ kp1,
    const int* __restrict__ maskc0, const int* __restrict__ maskc1,
    ushort_t* __restrict__ MSG)
{
    int wv = threadIdx.x >> 6;
    int lane = threadIdx.x & 63;
    int half = lane >> 5;
    int l32 = lane & 31;
    int row = blockIdx.x * 4 + wv;

    int t = row >> 13;
    int bl = row & 8191;               // b*4096 + l
    int ts = 1 - t;                    // source image
    const float* kp = ts ? kp1 : kp0;
    const int* mask = (t == 0) ? maskc1 : maskc0;
    int img = ts * 2 + (bl >> 12);
    size_t rb = (size_t)img * 4096;    // source row base
    const float* Gimg = Gm + (size_t)img * 42250;

    int c8 = l32 * 8;                  // this lane's 8 channels

    ushort8_t qu = *(const ushort8_t*)&QKV[(size_t)row * 768 + c8];
    float qf[8];
    #pragma unroll
    for (int j = 0; j < 8; j++) qf[j] = elu1(b2f(qu[j]));

    float zsum = 0.f;
    float acc[8] = {0,0,0,0,0,0,0,0};

    for (int s9 = half; s9 < 9; s9 += 2) {
        int r = bl * 9 + s9;
        bool mk = mask[r] != 0;
        if (mk) {
            float xx = kp[(size_t)r * 2 + 0];
            float yy = kp[(size_t)r * 2 + 1];
            float px = (xx - 3.5f) * (63.f / 507.5f);
            float py = (yy - 3.5f) * (63.f / 507.5f);
            float fx = floorf(px), fy = floorf(py);
            float wx = px - fx, wy = py - fy;
            int ix = (int)fx, iy = (int)fy;            // -1..63
            int xa = ix > 0 ? ix : 0;
            int xb = ix + 1 > 0 ? (ix + 1 < 63 ? ix + 1 : 63) : 0;
            int ya = iy > 0 ? iy : 0;
            int yb = iy + 1 > 0 ? (iy + 1 < 63 ? iy + 1 : 63) : 0;

            float w0 = (1.f - wy) * (1.f - wx);
            float w1 = (1.f - wy) * wx;
            float w2 = wy * (1.f - wx);
            float w3 = wy * wx;

            const float* G = &Gimg[(size_t)((iy + 1) * 65 + (ix + 1)) * 10];
            float g00 = G[0], g01 = G[1], g02 = G[2], g03 = G[3], g11 = G[4];
            float g12 = G[5], g13 = G[6], g22 = G[7], g23 = G[8], g33 = G[9];
            float ss = w0 * w0 * g00 + w1 * w1 * g11 + w2 * w2 * g22 + w3 * w3 * g33
                     + 2.f * (w0 * w1 * g01 + w0 * w2 * g02 + w0 * w3 * g03
                            + w1 * w2 * g12 + w1 * w3 * g13 + w2 * w3 * g23);
            float inv = 1.f / (sqrtf(ss) + 1e-8f);
            float u0 = w0 * inv, u1 = w1 * inv, u2 = w2 * inv, u3 = w3 * inv;

            size_t s00 = (rb + ya * 64 + xa) * 768;
            size_t s01 = (rb + ya * 64 + xb) * 768;
            size_t s10 = (rb + yb * 64 + xa) * 768;
            size_t s11 = (rb + yb * 64 + xb) * 768;

            ushort8_t k00 = *(const ushort8_t*)&QKV[s00 + 256 + c8];
            ushort8_t k01 = *(const ushort8_t*)&QKV[s01 + 256 + c8];
            ushort8_t k10 = *(const ushort8_t*)&QKV[s10 + 256 + c8];
            ushort8_t k11 = *(const ushort8_t*)&QKV[s11 + 256 + c8];
            ushort8_t v00 = *(const ushort8_t*)&QKV[s00 + 512 + c8];
            ushort8_t v01 = *(const ushort8_t*)&QKV[s01 + 512 + c8];
            ushort8_t v10 = *(const ushort8_t*)&QKV[s10 + 512 + c8];
            ushort8_t v11 = *(const ushort8_t*)&QKV[s11 + 512 + c8];

            float vc[8];
            float p = 0.f;
            #pragma unroll
            for (int j = 0; j < 8; j++) {
                float kc = u0 * b2f(k00[j]) + u1 * b2f(k01[j])
                         + u2 * b2f(k10[j]) + u3 * b2f(k11[j]);
                vc[j] = u0 * b2f(v00[j]) + u1 * b2f(v01[j])
                      + u2 * b2f(v10[j]) + u3 * b2f(v11[j]);
                p += qf[j] * elu1(kc);
            }
            // head = 32 ch = 4 lanes (group aligned): reduce over 4 lanes
            p += __shfl_xor(p, 1, 64);
            p += __shfl_xor(p, 2, 64);

            zsum += p;
            #pragma unroll
            for (int j = 0; j < 8; j++) acc[j] += p * vc[j];
        }
    }

    // combine the two halves (same channels, disjoint samples)
    zsum += __shfl_xor(zsum, 32, 64);
    #pragma unroll
    for (int j = 0; j < 8; j++) acc[j] += __shfl_xor(acc[j], 32, 64);

    if (half == 0) {
        float Z = 1.f / (zsum + 1e-6f);
        ushort8_t o;
        #pragma unroll
        for (int j = 0; j < 8; j++) o[j] = f2b(acc[j] * Z);
        *(ushort8_t*)&MSG[(size_t)row * 256 + c8] = o;
    }
}

// ---------------------------------------------------------------------------

extern "C" void kernel_launch(void* const* d_in, const int* in_sizes, int n_in,
                              void* d_out, int out_size, void* d_ws, size_t ws_size,
                              hipStream_t stream)
{
    const float* feat0 = (const float*)d_in[0];
    const float* feat1 = (const float*)d_in[1];
    const float* kp0 = (const float*)d_in[2];
    const float* kp1 = (const float*)d_in[3];
    const int* ms0 = (const int*)d_in[4];
    const int* ms1 = (const int*)d_in[5];
    const int* mc0 = (const int*)d_in[6];
    const int* mc1 = (const int*)d_in[7];
    const float* Wq = (const float*)d_in[8];
    const float* Wk = (const float*)d_in[9];
    const float* Wv = (const float*)d_in[10];
    const float* Wm = (const float*)d_in[11];
    const float* W1 = (const float*)d_in[12];
    const float* W2 = (const float*)d_in[13];
    const float* g1 = (const float*)d_in[14];
    const float* b1 = (const float*)d_in[15];
    const float* g2 = (const float*)d_in[16];
    const float* b2 = (const float*)d_in[17];

    // workspace carve (bytes; all offsets 256B-aligned). ~55 MB total.
    char* p = (char*)d_ws;
    float*    X     = (float*)p;            p += 16777216;   // 16384x256 fp32
    ushort_t* Xbf   = (ushort_t*)p;         p += 8388608;    // bf16 mirror
    ushort_t* QKV   = (ushort_t*)p;         p += 25165824;   // 16384x768 bf16
    ushort_t* MSG   = (ushort_t*)p;         p += 8388608;    // 16384x256 bf16
    ushort_t* L1bf  = (ushort_t*)p;         p += 8388608;    // 16384x256 bf16
    float*    KVb   = (float*)p;            p += 131072;     // 32x1024
    float*    KSb   = (float*)p;            p += 4096;       // 32x32
    float*    Gm    = (float*)p;            p += 679936;     // 4x65x65x10 fp32 Gram
    ushort_t* Wqkvt = (ushort_t*)p;         p += 1572864;    // 4x768x256 bf16
    ushort_t* Wmt   = (ushort_t*)p;         p += 524288;     // 4x256x256
    ushort_t* W1t   = (ushort_t*)p;         p += 2097152;    // 4x512x512
    ushort_t* W2t   = (ushort_t*)p;         p += 1048576;    // 4x256x512

    init_kernel<<<4096, 256, 0, stream>>>(feat0, feat1, X, Xbf);
    wprep_kernel<<<2560, 256, 0, stream>>>(Wq, Wk, Wv, Wm, W1, W2, Wqkvt, Wmt, W1t, W2t);

    for (int i = 0; i < 4; i++) {
        const ushort_t* Wqkvt_l = Wqkvt + (size_t)i * 196608;
        const ushort_t* Wmt_l   = Wmt   + (size_t)i * 65536;
        const ushort_t* W1t_l   = W1t   + (size_t)i * 262144;
        const ushort_t* W2t_l   = W2t   + (size_t)i * 131072;
        const float* g1_l = g1 + (size_t)i * 256;
        const float* b1_l = b1 + (size_t)i * 256;
        const float* g2_l = g2 + (size_t)i * 256;
        const float* b2_l = b2 + (size_t)i * 256;
        bool is_self = (i == 0 || i == 2);

        // QKV = Xbf @ [Wq|Wk|Wv]
        gemm_bf16_kernel<<<dim3(6, 128), 256, 0, stream>>>(
            Xbf, 256, Wqkvt_l, 256, QKV, 768, 256);

        if (is_self) {
            hipMemsetAsync(KVb, 0, 33792 * 4, stream);
            kv_reduce_kernel<<<dim3(16, 32), 256, 0, stream>>>(QKV, ms0, ms1, KVb, KSb);
            attn_apply_kernel<<<NROWS, 256, 0, stream>>>(QKV, KVb, KSb, MSG);
        } else {
            gram_kernel<<<4225, 256, 0, stream>>>(Xbf, Gm);
            cross_fused_kernel<<<NROWS / 4, 256, 0, stream>>>(QKV, Gm, kp0, kp1, mc0, mc1, MSG);
        }

        // L1 = ln1(MSG @ Wm)  (fused)
        gemm_ln_kernel<<<NROWS / 32, 256, 0, stream>>>(
            MSG, 256, Wmt_l, 256, 256, g1_l, b1_l, L1bf);

        // T = tanh([Xbf|L1] @ W1) ; X += ln2(T @ W2) ; Xbf = bf16(X)  (one kernel)
        float* Xout = (i == 3) ? (float*)d_out : X;
        mlp_fused_kernel<<<NROWS / 32, 256, 0, stream>>>(
            Xbf, L1bf, W1t_l, W2t_l, g2_l, b2_l, Xbf, X, Xout);
    }
}